// Round 12
// baseline (122.936 us; speedup 1.0000x reference)
//
#include <hip/hip_runtime.h>
#include <hip/hip_bf16.h>
#include <math.h>

#define EPSN 1e-12f
typedef unsigned short ushort_t;

typedef float f32x4 __attribute__((ext_vector_type(4)));
typedef short s16x8 __attribute__((ext_vector_type(8)));
typedef unsigned short u16x8 __attribute__((ext_vector_type(8)));
typedef unsigned short u16x4 __attribute__((ext_vector_type(4)));

__device__ __forceinline__ void gload_lds16(const void* g, void* l) {
  __builtin_amdgcn_global_load_lds((const __attribute__((address_space(1))) void*)g,
                                   (__attribute__((address_space(3))) void*)l, 16, 0, 0);
}

// ---------------- K0: per-token sum of squares -> 8 partials ----------------
__global__ void k0_ssq(const float* __restrict__ x, float* __restrict__ ssq8) {
  int b8 = blockIdx.x >> 3;
  int cc = blockIdx.x & 7;
  int t = threadIdx.x;
  int s4 = (t & 15) * 4;
  int cg = t >> 4;
  const float* xp = x + (size_t)b8 * 65536 + (size_t)cc * 128 * 64;
  float4 a = {0.f, 0.f, 0.f, 0.f};
#pragma unroll
  for (int j = 0; j < 8; ++j) {
    int c = cg + j * 16;
    float4 v = *(const float4*)(xp + (size_t)c * 64 + s4);
    a.x = fmaf(v.x, v.x, a.x);
    a.y = fmaf(v.y, v.y, a.y);
    a.z = fmaf(v.z, v.z, a.z);
    a.w = fmaf(v.w, v.w, a.w);
  }
  __shared__ float red[16][68];
  *(float4*)&red[cg][s4] = a;
  __syncthreads();
  if (t < 64) {
    float s = 0.f;
#pragma unroll
    for (int g = 0; g < 16; ++g) s += red[g][t];
    ssq8[cc * 4096 + b8 * 64 + t] = s;
  }
}

// ---------------- K1: transpose + scale -> xnb bf16 [tm][c] ----------------
__global__ void k1_transpose(const float* __restrict__ x, const float* __restrict__ ssq8,
                             __hip_bfloat16* __restrict__ xnb) {
  int ct = blockIdx.x;
  int b8 = blockIdx.y;
  int t = threadIdx.x;
  __shared__ float tile[64][65];
  __shared__ float ivs[64];
  if (t < 64) {
    float s = 0.f;
#pragma unroll
    for (int cc = 0; cc < 8; ++cc) s += ssq8[cc * 4096 + b8 * 64 + t];
    ivs[t] = rsqrtf(fmaxf(s, 1e-24f));
  }
  int s = t & 63, cq = t >> 6;
  const float* xp = x + (size_t)b8 * 65536 + (size_t)ct * 64 * 64;
#pragma unroll
  for (int r = 0; r < 16; ++r) {
    int cl = cq * 16 + r;
    tile[cl][s] = xp[cl * 64 + s];
  }
  __syncthreads();
  int cl = t & 63, sq = t >> 6;
#pragma unroll
  for (int r = 0; r < 16; ++r) {
    int smm = sq * 16 + r;
    int tm = b8 * 64 + smm;
    xnb[(size_t)tm * 1024 + ct * 64 + cl] = __float2bfloat16(tile[cl][smm] * ivs[smm]);
  }
}

// ---------------- kpack2: stackedA rows 0-2047 (=Wib) + pad rows 3200-3327 + Wgkx
//                  (+gate, zero pad) + bWg + WibT ----------------
__global__ void kpack2(const float* __restrict__ Wi, const float* __restrict__ Wgk,
                       const float* __restrict__ W_g, const float* __restrict__ b_inp,
                       const float* __restrict__ b_g, __hip_bfloat16* __restrict__ oWi,
                       __hip_bfloat16* __restrict__ oWx, ushort_t* __restrict__ oWibT,
                       float* __restrict__ bWg) {
  int bid = blockIdx.x;
  int t = threadIdx.x;
  if (bid < 2048) {
    int i = (bid * 256 + t) * 4;
    float4 v = *(const float4*)(Wi + i);
    oWi[i + 0] = __float2bfloat16(v.x);
    oWi[i + 1] = __float2bfloat16(v.y);
    oWi[i + 2] = __float2bfloat16(v.z);
    oWi[i + 3] = __float2bfloat16(v.w);
  } else if (bid < 4096) {
    int i = ((bid - 2048) * 256 + t) * 4;
    float4 v = *(const float4*)(Wgk + i);
    oWx[i + 0] = __float2bfloat16(v.x);
    oWx[i + 1] = __float2bfloat16(v.y);
    oWx[i + 2] = __float2bfloat16(v.z);
    oWx[i + 3] = __float2bfloat16(v.w);
  } else if (bid < 4112) {
    int i = (bid - 4096) * 1024 + t * 4;  // 16 blocks: 8 gate rows
    float4 v = *(const float4*)(W_g + i);
    __hip_bfloat16* o = oWx + 1024 * 2048 + i;
    o[0] = __float2bfloat16(v.x);
    o[1] = __float2bfloat16(v.y);
    o[2] = __float2bfloat16(v.z);
    o[3] = __float2bfloat16(v.w);
  } else if (bid < 4352) {
    int i = (bid - 4112) * 1024 + t * 4;  // 240 blocks: 120 zero rows of Wgkx
    ushort_t* o = (ushort_t*)(oWx + 1032 * 2048) + i;
    *(u16x4*)o = (u16x4){0, 0, 0, 0};
  } else if (bid < 4360) {
    int j = bid - 4352;  // 0..7
    const float* row = W_g + (size_t)j * 2048;
    float s = 0.f;
    for (int c = t; c < 2048; c += 256) s = fmaf(b_inp[c], row[c], s);
    __shared__ float red[256];
    red[t] = s;
    __syncthreads();
    for (int o = 128; o > 0; o >>= 1) {
      if (t < o) red[t] += red[t + o];
      __syncthreads();
    }
    if (t == 0) bWg[j] = red[0] + b_g[j];
  } else if (bid < 4872) {
    // WibT[1024 c][2048 c'] = cast-transpose of W_inp[2048 c'][1024 c]; 512 tiles 64x64
    int tt = bid - 4360;
    int cp0 = (tt >> 4) * 64;  // c' base
    int c0 = (tt & 15) * 64;   // c base
    __shared__ ushort_t tile[64][72];
    int r = t >> 2, cs = (t & 3) * 16;
    const float* src = Wi + (size_t)(cp0 + r) * 1024 + c0 + cs;
#pragma unroll
    for (int j = 0; j < 16; j += 4) {
      float4 v = *(const float4*)(src + j);
      __hip_bfloat16 h0 = __float2bfloat16(v.x), h1 = __float2bfloat16(v.y);
      __hip_bfloat16 h2 = __float2bfloat16(v.z), h3 = __float2bfloat16(v.w);
      tile[r][cs + j + 0] = *(ushort_t*)&h0;
      tile[r][cs + j + 1] = *(ushort_t*)&h1;
      tile[r][cs + j + 2] = *(ushort_t*)&h2;
      tile[r][cs + j + 3] = *(ushort_t*)&h3;
    }
    __syncthreads();
    int c = t >> 2, ms = (t & 3) * 16;
    u16x8 o0, o1;
#pragma unroll
    for (int j = 0; j < 8; ++j) o0[j] = tile[ms + j][c];
#pragma unroll
    for (int j = 0; j < 8; ++j) o1[j] = tile[ms + 8 + j][c];
    ushort_t* dst = oWibT + (size_t)(c0 + c) * 2048 + cp0 + ms;
    *(u16x8*)dst = o0;
    *(u16x8*)(dst + 8) = o1;
  } else {
    // zero pad rows 3200-3327 of stackedA (128 rows): 128 blocks x 1024 elems
    int i = (bid - 4872) * 1024 + t * 4;
    ushort_t* o = (ushort_t*)oWi + (size_t)3200 * 1024 + i;
    *(u16x4*)o = (u16x4){0, 0, 0, 0};
  }
}

// ---------------- GEMM0 split-K: Wc4[s][1152][1024] = Wgkx[:,s*512:(s+1)*512] @ WibT^T ------
__launch_bounds__(512, 4)
__global__ void gemm0_splitk(const ushort_t* __restrict__ A, const ushort_t* __restrict__ B,
                             float* __restrict__ Cf) {
  const int Kstride = 2048, N = 1024;
  __shared__ alignas(16) ushort_t SH[32768];
  const int tid = threadIdx.x;
  const int m0 = blockIdx.y * 128, n0 = blockIdx.x * 128;
  const int s = blockIdx.z;
  const int koff = s * 512;
  const int w = tid >> 6, l = tid & 63;
  const int wr = w >> 2, wc = w & 3;
  const int srow = w * 8 + (l >> 3);
  const int ksw = ((l & 7) ^ (l >> 3)) * 8;
  const ushort_t* Ag0 = A + (size_t)(m0 + srow) * Kstride + ksw + koff;
  const ushort_t* Ag1 = A + (size_t)(m0 + 64 + srow) * Kstride + ksw + koff;
  const ushort_t* Bg0 = B + (size_t)(n0 + srow) * Kstride + ksw + koff;
  const ushort_t* Bg1 = B + (size_t)(n0 + 64 + srow) * Kstride + ksw + koff;
  const int l0 = w * 512;
  const int l1 = 4096 + w * 512;

  f32x4 acc[4][2];
#pragma unroll
  for (int i = 0; i < 4; ++i)
#pragma unroll
    for (int j = 0; j < 2; ++j) acc[i][j] = (f32x4){0.f, 0.f, 0.f, 0.f};

  const int sw = l & 7, qq = l >> 4;

#define ASH(buf) (SH + (buf)*8192)
#define BSH(buf) (SH + 16384 + (buf)*8192)
#define STAGE(buf, k0)                               \
  {                                                  \
    gload_lds16(Ag0 + (k0), ASH(buf) + l0);          \
    gload_lds16(Ag1 + (k0), ASH(buf) + l1);          \
    gload_lds16(Bg0 + (k0), BSH(buf) + l0);          \
    gload_lds16(Bg1 + (k0), BSH(buf) + l1);          \
  }
#define COMPUTE(buf)                                                                     \
  {                                                                                      \
    s16x8 af[4][2], bf[2][2];                                                            \
    _Pragma("unroll") for (int kk = 0; kk < 2; ++kk) {                                   \
      int slot = (((kk << 2) + qq) ^ sw) * 8;                                            \
      _Pragma("unroll") for (int mi = 0; mi < 4; ++mi)                                   \
          af[mi][kk] = *(const s16x8*)&ASH(buf)[(wr * 64 + mi * 16 + (l & 15)) * 64 +    \
                                               slot];                                   \
      _Pragma("unroll") for (int ni = 0; ni < 2; ++ni)                                   \
          bf[ni][kk] = *(const s16x8*)&BSH(buf)[(wc * 32 + ni * 16 + (l & 15)) * 64 +    \
                                               slot];                                   \
    }                                                                                    \
    _Pragma("unroll") for (int kk = 0; kk < 2; ++kk)                                     \
        _Pragma("unroll") for (int mi = 0; mi < 4; ++mi)                                 \
            _Pragma("unroll") for (int ni = 0; ni < 2; ++ni)                             \
                acc[mi][ni] = __builtin_amdgcn_mfma_f32_16x16x32_bf16(af[mi][kk],        \
                                                                     bf[ni][kk],        \
                                                                     acc[mi][ni], 0, 0, 0); \
  }

  STAGE(0, 0);
  int buf = 0;
  for (int t = 0; t < 7; ++t) {
    STAGE(buf ^ 1, (t + 1) << 6);
    asm volatile("s_waitcnt vmcnt(4)" ::: "memory");
    __builtin_amdgcn_s_barrier();
    asm volatile("" ::: "memory");
    COMPUTE(buf);
    asm volatile("" ::: "memory");
    __builtin_amdgcn_s_barrier();
    buf ^= 1;
  }
  asm volatile("s_waitcnt vmcnt(0)" ::: "memory");
  __builtin_amdgcn_s_barrier();
  asm volatile("" ::: "memory");
  COMPUTE(buf);
#undef STAGE
#undef COMPUTE
#undef ASH
#undef BSH

  float* Co = Cf + (size_t)s * 1152 * 1024;
#pragma unroll
  for (int mi = 0; mi < 4; ++mi) {
    int row = m0 + wr * 64 + mi * 16 + (l >> 4) * 4;
#pragma unroll
    for (int ni = 0; ni < 2; ++ni) {
      int col = n0 + wc * 32 + ni * 16 + (l & 15);
#pragma unroll
      for (int r = 0; r < 4; ++r)
        Co[(size_t)(row + r) * N + col] = acc[mi][ni][r];
    }
  }
}

// ---------------- kpackC: sum 4 split-K partials -> bf16 into stackedA rows 2048+ ----------
__global__ void kpackC(const float* __restrict__ Wc4, ushort_t* __restrict__ dst) {
  int i = (blockIdx.x * 256 + threadIdx.x) * 4;
  float4 a = *(const float4*)(Wc4 + i);
  float4 b = *(const float4*)(Wc4 + 1179648 + i);
  float4 c = *(const float4*)(Wc4 + 2359296 + i);
  float4 d = *(const float4*)(Wc4 + 3538944 + i);
  float4 sv = {a.x + b.x + c.x + d.x, a.y + b.y + c.y + d.y,
               a.z + b.z + c.z + d.z, a.w + b.w + c.w + d.w};
  u16x4 o;
  __hip_bfloat16 h0 = __float2bfloat16(sv.x), h1 = __float2bfloat16(sv.y);
  __hip_bfloat16 h2 = __float2bfloat16(sv.z), h3 = __float2bfloat16(sv.w);
  o[0] = *(ushort_t*)&h0; o[1] = *(ushort_t*)&h1;
  o[2] = *(ushort_t*)&h2; o[3] = *(ushort_t*)&h3;
  *(u16x4*)(dst + i) = o;
}

// ---------------- big stacked GEMM, 256x256 tile, BK=64, 8-PHASE counted-vmcnt schedule ----
// C[3328,4096] = stackedA[3328,1024] @ xnb[4096,1024]^T. 8 waves (2Mx4N), per-wave 128x64.
// LDS 128KB: A[2dbuf][2half][128r][64k] | B[...], halves are CONSUMPTION-ORDERED:
//   A-half h = global rows {m0+h*64..+63} u {m0+128+h*64..+63}  (read in phases mh==h)
//   B-half h = global rows {n0 + wc*64 + h*32..} for all wc      (read in phases nh==h)
// Per phase: 12 ds_read_b128 (quadrant) + 1 half-tile stage (2 gload_lds) + bar +
// setprio(1) 16 MFMA setprio(0) + bar. vmcnt(4) at phases 4,8 only (counted, never 0).
// Race-free by construction: every stage targets a region last read >=1 barrier earlier;
// every read is covered by a vmcnt(4)+barrier at least one phase-pair ahead.
__launch_bounds__(512, 2)
__global__ void gemm256_8ph(const ushort_t* __restrict__ A, const ushort_t* __restrict__ B,
                            ushort_t* __restrict__ C, int K, int N) {
  __shared__ alignas(16) ushort_t SH[65536];  // 128 KB
  const int tid = threadIdx.x;
  const int m0 = blockIdx.y * 256, n0 = blockIdx.x * 256;
  const int w = tid >> 6, l = tid & 63;
  const int wr = w >> 2, wc = w & 3;  // 2x4 wave grid; per-wave 128m x 64n
  const int r16 = l & 15, qq = l >> 4, sw = l & 7;
  // staging lane geometry
  const int s = tid >> 3;             // 0..63 (LDS row within a 64-row load group)
  const int s_hi = s >> 5, s_lo = s & 31;
  const int ksw = ((tid & 7) ^ (s & 7)) * 8;  // inverse-swizzled source k-offset
  const int NT = K >> 6;

  const ushort_t* pA0 = A + (size_t)(m0 + s) * K + ksw;          // load0: rows m0..+127 block
  const ushort_t* pA1 = A + (size_t)(m0 + 128 + s) * K + ksw;    // load1
  const ushort_t* pB0 = B + (size_t)(n0 + s_hi * 64 + s_lo) * K + ksw;
  const ushort_t* pB1 = B + (size_t)(n0 + 128 + s_hi * 64 + s_lo) * K + ksw;
  ushort_t* dA = SH + tid * 8;
  ushort_t* dB = SH + 32768 + tid * 8;

  f32x4 acc[8][4];
#pragma unroll
  for (int i = 0; i < 8; ++i)
#pragma unroll
    for (int j = 0; j < 4; ++j) acc[i][j] = (f32x4){0.f, 0.f, 0.f, 0.f};

// stage one A half-tile (kt, half h): 128 rows x 64k, consumption-ordered rows
#define SA(kt, h)                                                                        \
  {                                                                                      \
    gload_lds16(pA0 + (size_t)(h) * (K << 6) + ((kt) << 6),                              \
                dA + (((kt)&1) << 14) + ((h) << 13));                                    \
    gload_lds16(pA1 + (size_t)(h) * (K << 6) + ((kt) << 6),                              \
                dA + (((kt)&1) << 14) + ((h) << 13) + 4096);                             \
  }
#define SB(kt, h)                                                                        \
  {                                                                                      \
    gload_lds16(pB0 + (size_t)(h) * (K << 5) + ((kt) << 6),                              \
                dB + (((kt)&1) << 14) + ((h) << 13));                                    \
    gload_lds16(pB1 + (size_t)(h) * (K << 5) + ((kt) << 6),                              \
                dB + (((kt)&1) << 14) + ((h) << 13) + 4096);                             \
  }
#define VMC4 asm volatile("s_waitcnt vmcnt(4)" ::: "memory")

// one phase: quadrant (mh,nh) of dbuf d; STG = stage op; VM = optional vmcnt
#define PHASE(d, mh, nh, STG, VM)                                                        \
  {                                                                                      \
    s16x8 af[2][4], bf[2][2];                                                            \
    _Pragma("unroll") for (int kk = 0; kk < 2; ++kk) {                                   \
      int slot = (((kk << 2) + qq) ^ sw) * 8;                                            \
      _Pragma("unroll") for (int ni2 = 0; ni2 < 2; ++ni2)                                \
          bf[kk][ni2] = *(const s16x8*)&SH[32768 + ((d) << 14) + ((nh) << 13) +          \
                                           (wc * 32 + ni2 * 16 + r16) * 64 + slot];      \
      _Pragma("unroll") for (int mi2 = 0; mi2 < 4; ++mi2)                                \
          af[kk][mi2] = *(const s16x8*)&SH[((d) << 14) + ((mh) << 13) +                  \
                                           (wr * 64 + mi2 * 16 + r16) * 64 + slot];      \
    }                                                                                    \
    STG;                                                                                 \
    asm volatile("" ::: "memory");                                                       \
    __builtin_amdgcn_s_barrier();                                                        \
    asm volatile("" ::: "memory");                                                       \
    __builtin_amdgcn_s_setprio(1);                                                       \
    _Pragma("unroll") for (int kk = 0; kk < 2; ++kk)                                     \
        _Pragma("unroll") for (int mi2 = 0; mi2 < 4; ++mi2)                              \
            _Pragma("unroll") for (int ni2 = 0; ni2 < 2; ++ni2)                          \
                acc[(mh)*4 + mi2][(nh)*2 + ni2] = __builtin_amdgcn_mfma_f32_16x16x32_bf16( \
                    af[kk][mi2], bf[kk][ni2], acc[(mh)*4 + mi2][(nh)*2 + ni2], 0, 0, 0); \
    __builtin_amdgcn_s_setprio(0);                                                       \
    VM;                                                                                  \
    asm volatile("" ::: "memory");                                                       \
    __builtin_amdgcn_s_barrier();                                                        \
    asm volatile("" ::: "memory");                                                       \
  }

  // prologue: kt0 complete + kt1.{A0,B0}; vmcnt(4) -> kt0's 4 halves landed
  SA(0, 0); SB(0, 0); SA(0, 1); SB(0, 1); SA(1, 0); SB(1, 0);
  VMC4;
  __builtin_amdgcn_s_barrier();
  asm volatile("" ::: "memory");

#pragma unroll 1
  for (int I = 0; I < (NT >> 1); ++I) {
    const int kt = 2 * I;
    const int k1 = kt + 1, k2 = kt + 2, k3 = kt + 3;
    // phases 1-4: compute kt (dbuf0)
    PHASE(0, 0, 0, SA(k1, 1), );                       // dbuf1.A1 free since prev p8
    PHASE(0, 0, 1, SB(k1, 1), );                       // dbuf1.B1 free since prev p8
    PHASE(0, 1, 0, if (k2 < NT) SA(k2, 0), );          // dbuf0.A0 free after p2
    PHASE(0, 1, 1, if (k2 < NT) SB(k2, 0), VMC4);      // dbuf0.B0 free after p3
    // phases 5-8: compute kt+1 (dbuf1); kt+1 fully landed by p4's vmcnt(4)
    PHASE(1, 0, 0, if (k2 < NT) SA(k2, 1), );          // dbuf0.A1 free after p4
    PHASE(1, 0, 1, if (k2 < NT) SB(k2, 1), );          // dbuf0.B1 free after p4
    PHASE(1, 1, 0, if (k3 < NT) SA(k3, 0), );          // dbuf1.A0 free after p6
    PHASE(1, 1, 1, if (k3 < NT) SB(k3, 0), VMC4);      // dbuf1.B0 free after p7
  }
#undef PHASE
#undef SA
#undef SB
#undef VMC4

#pragma unroll
  for (int mi = 0; mi < 8; ++mi) {
    int row = m0 + wr * 128 + mi * 16 + (l >> 4) * 4;
#pragma unroll
    for (int ni = 0; ni < 4; ++ni) {
      int col = n0 + wc * 64 + ni * 16 + r16;
#pragma unroll
      for (int r = 0; r < 4; ++r) {
        __hip_bfloat16 hb = __float2bfloat16(acc[mi][ni][r]);
        C[(size_t)(row + r) * N + col] = *(ushort_t*)&hb;
      }
    }
  }
}

// ---------------- K5: row softmax over tokens + gate sigmoid, one wave per (q,b) ----------------
__launch_bounds__(256)
__global__ void k5_softmax(const ushort_t* __restrict__ logitsTb, const float* __restrict__ bWg,
                           float* __restrict__ colsumW, ushort_t* __restrict__ wbT) {
  int wv = (blockIdx.x << 2) + (threadIdx.x >> 6);
  int q = wv >> 3, b = wv & 7;
  int l = threadIdx.x & 63;
  int g = q >> 7;
  size_t base = (size_t)q * 4096 + b * 512 + l * 8;
  u16x8 v8 = *(const u16x8*)(logitsTb + base);
  float vs[8];
#pragma unroll
  for (int i = 0; i < 8; ++i) vs[i] = __uint_as_float(((unsigned)v8[i]) << 16);
  float M = vs[0];
#pragma unroll
  for (int i = 1; i < 8; ++i) M = fmaxf(M, vs[i]);
#pragma unroll
  for (int m = 1; m < 64; m <<= 1) M = fmaxf(M, __shfl_xor(M, m, 64));
  float e[8], S = 0.f;
#pragma unroll
  for (int i = 0; i < 8; ++i) {
    e[i] = expf(vs[i] - M);
    S += e[i];
  }
#pragma unroll
  for (int m = 1; m < 64; m <<= 1) S += __shfl_xor(S, m, 64);
  float R = 1.0f / S;
  u16x8 g8 = *(const u16x8*)(logitsTb + (size_t)(1024 + g) * 4096 + b * 512 + l * 8);
  float bg = bWg[g];
  float wv8[8], wsum = 0.f;
#pragma unroll
  for (int i = 0; i < 8; ++i) {
    float gl = __uint_as_float(((unsigned)g8[i]) << 16);
    float ag = 1.0f / (1.0f + expf(-(gl + bg)));
    wv8[i] = e[i] * R * ag;
    wsum += wv8[i];
  }
#pragma unroll
  for (int m = 1; m < 64; m <<= 1) wsum += __shfl_xor(wsum, m, 64);
  if (l == 0) colsumW[b * 1024 + q] = wsum;
  u16x8 o;
#pragma unroll
  for (int i = 0; i < 8; ++i) {
    __hip_bfloat16 hb = __float2bfloat16(wv8[i]);
    o[i] = *(ushort_t*)&hb;
  }
  *(u16x8*)(wbT + base) = o;
}

// ---------------- K6: VLAD einsum via MFMA, 64x64 tile, m-split 8, counted vmcnt ----------------
__launch_bounds__(256)
__global__ void k6_vlad_mfma(const ushort_t* __restrict__ wbT, const ushort_t* __restrict__ YcT,
                             float* __restrict__ vpart) {
  int kt = blockIdx.x >> 2, dt = blockIdx.x & 3;
  int ms = blockIdx.y, b = blockIdx.z;
  __shared__ alignas(16) ushort_t Ash[2][4096];
  __shared__ alignas(16) ushort_t Bsh[2][4096];
  const int tid = threadIdx.x;
  const int w = tid >> 6, l = tid & 63;
  const int wr = w >> 1, wc = w & 1;
  const int crow = l >> 3;
  const int ksw = ((l & 7) ^ crow) * 8;

  const ushort_t* Ap[2];
  const ushort_t* Bp[2];
  int loff[2];
#pragma unroll
  for (int c = 0; c < 2; ++c) {
    int chunk = w * 2 + c;
    Ap[c] = wbT + (size_t)(kt * 64 + chunk * 8 + crow) * 4096 + b * 512 + ms * 64 + ksw;
    Bp[c] = YcT + (size_t)(dt * 64 + chunk * 8 + crow) * 4096 + b * 512 + ms * 64 + ksw;
    loff[c] = chunk * 512;
  }

  f32x4 acc[2][2];
#pragma unroll
  for (int i = 0; i < 2; ++i)
#pragma unroll
    for (int j = 0; j < 2; ++j) acc[i][j] = (f32x4){0.f, 0.f, 0.f, 0.f};

  const int sw = l & 7, qq = l >> 4;

#define STAGE6(buf, g)                                                       \
  {                                                                          \
    size_t offA = (size_t)(g)*524288;                                        \
    size_t offB = (size_t)(g)*1048576;                                       \
    gload_lds16(Ap[0] + offA, &Ash[buf][loff[0]]);                           \
    gload_lds16(Ap[1] + offA, &Ash[buf][loff[1]]);                           \
    gload_lds16(Bp[0] + offB, &Bsh[buf][loff[0]]);                           \
    gload_lds16(Bp[1] + offB, &Bsh[buf][loff[1]]);                           \
  }
#define COMPUTE6(buf)                                                                    \
  {                                                                                      \
    s16x8 af[2][2], bf[2][2];                                                            \
    _Pragma("unroll") for (int kk = 0; kk < 2; ++kk) {                                   \
      int slot = (((kk << 2) + qq) ^ sw) * 8;                                            \
      _Pragma("unroll") for (int mi = 0; mi < 2; ++mi) {                                 \
        af[mi][kk] = *(const s16x8*)&Ash[buf][(wr * 32 + mi * 16 + (l & 15)) * 64 +      \
                                             slot];                                     \
        bf[mi][kk] = *(const s16x8*)&Bsh[buf][(wc * 32 + mi * 16 + (l & 15)) * 64 +      \
                                             slot];                                     \
      }                                                                                  \
    }                                                                                    \
    _Pragma("unroll") for (int kk = 0; kk < 2; ++kk)                                     \
        _Pragma("unroll") for (int mi = 0; mi < 2; ++mi)                                 \
            _Pragma("unroll") for (int ni = 0; ni < 2; ++ni)                             \
                acc[mi][ni] = __builtin_amdgcn_mfma_f32_16x16x32_bf16(af[mi][kk],        \
                                                                     bf[ni][kk],        \
                                                                     acc[mi][ni], 0, 0, 0); \
  }

  STAGE6(0, 0);
  int buf = 0;
  for (int s = 0; s < 7; ++s) {
    STAGE6(buf ^ 1, s + 1);
    asm volatile("s_waitcnt vmcnt(4)" ::: "memory");
    __builtin_amdgcn_s_barrier();
    asm volatile("" ::: "memory");
    COMPUTE6(buf);
    asm volatile("" ::: "memory");
    __builtin_amdgcn_s_barrier();
    buf ^= 1;
  }
  asm volatile("s_waitcnt vmcnt(0)" ::: "memory");
  __builtin_amdgcn_s_barrier();
  asm volatile("" ::: "memory");
  COMPUTE6(buf);
#undef STAGE6
#undef COMPUTE6

#pragma unroll
  for (int mi = 0; mi < 2; ++mi) {
    int row = kt * 64 + wr * 32 + mi * 16 + (l >> 4) * 4;
#pragma unroll
    for (int ni = 0; ni < 2; ++ni) {
      int col = dt * 64 + wc * 32 + ni * 16 + (l & 15);
#pragma unroll
      for (int r = 0; r < 4; ++r)
        vpart[((size_t)(ms * 8 + b) * 128 + row + r) * 256 + col] = acc[mi][ni][r];
    }
  }
}

// ---------------- K7: combine 8 partials + bias-part - S*centroid, intra-normalize ----------------
__global__ void k7_intranorm(const float* __restrict__ vpart, const float* __restrict__ colsumW,
                             const float* __restrict__ b_inp, const float* __restrict__ cent,
                             float* __restrict__ out, float* __restrict__ ss1) {
  int k = blockIdx.x;
  int b = blockIdx.y;
  int d = threadIdx.x;
  float S = 0.f, bp = 0.f;
#pragma unroll
  for (int g = 0; g < 8; ++g) {
    float cw = colsumW[b * 1024 + g * 128 + k];
    S += cw;
    bp = fmaf(b_inp[g * 256 + d], cw, bp);
  }
  size_t off = ((size_t)b * 128 + k) * 256 + d;
  float v = bp - S * cent[(size_t)k * 256 + d];
#pragma unroll
  for (int i = 0; i < 8; ++i) v += vpart[off + (size_t)i * 262144];
  float ss = v * v;
#pragma unroll
  for (int m = 1; m < 64; m <<= 1) ss += __shfl_xor(ss, m, 64);
  __shared__ float red[4];
  int lane = d & 63, wv = d >> 6;
  if (lane == 0) red[wv] = ss;
  __syncthreads();
  float tot = red[0] + red[1] + red[2] + red[3];
  float rinv = 1.0f / fmaxf(sqrtf(tot), EPSN);
  out[off] = v * rinv;
  if (d == 0) ss1[b * 128 + k] = tot * rinv * rinv;
}

// ---------------- K8: final global L2 norm ----------------
__global__ void k8_finalnorm(const float* __restrict__ ss1, float* __restrict__ out) {
  int b = blockIdx.x;
  int t = threadIdx.x;
  __shared__ float red[256];
  red[t] = (t < 128) ? ss1[b * 128 + t] : 0.f;
  __syncthreads();
  for (int o = 128; o > 0; o >>= 1) {
    if (t < o) red[t] += red[t + o];
    __syncthreads();
  }
  float rinv = 1.0f / fmaxf(sqrtf(red[0]), EPSN);
  float* op = out + (size_t)b * 32768;
  for (int i = t; i < 32768; i += 256) op[i] *= rinv;
}

extern "C" void kernel_launch(void* const* d_in, const int* in_sizes, int n_in,
                              void* d_out, int out_size, void* d_ws, size_t ws_size,
                              hipStream_t stream) {
  const float* x     = (const float*)d_in[0];
  const float* W_inp = (const float*)d_in[1];
  const float* b_inp = (const float*)d_in[2];
  const float* W_g   = (const float*)d_in[3];
  const float* b_g   = (const float*)d_in[4];
  const float* W_gk  = (const float*)d_in[5];
  // b_gk (d_in[6]) cancels in the token-axis softmax — unused.
  const float* cent  = (const float*)d_in[7];
  float* out = (float*)d_out;
  float* ws = (float*)d_ws;

  // workspace layout (float offsets), total 12,887,104 floats = 51.5 MB
  float* ssq8    = ws + 0;         // 32768
  float* colsumW = ws + 32768;     // 8192
  float* ss1     = ws + 40960;     // 1024
  float* bWg     = ws + 41984;     // 64
  ushort_t* xnb  = (ushort_t*)(ws + 42048);        // [4096][1024] bf16 (2097152 fl)
  ushort_t* wbT  = xnb;                            // alias (xnb dead after gemm256)
  ushort_t* stackedA = (ushort_t*)(ws + 2139200);  // [3328][1024] bf16 (1703936 fl)
  ushort_t* WibT = (ushort_t*)(ws + 3843136);      // [1024][2048] bf16 (1048576 fl)
  ushort_t* Wgkx = (ushort_t*)(ws + 4891712);      // [1152][2048] bf16 (1179648 fl)
  float* vpart   = ws + 3843136;   // 2097152 fl, aliases WibT+Wgkx (dead after GEMM0)
  float* Wc4     = ws + 6071360;   // [4][1152][1024] f32 (4718592 fl), dead after kpackC
  ushort_t* Cstacked = (ushort_t*)(ws + 6071360);  // [3328][4096] bf16 (6815744 fl), over Wc4
  ushort_t* YcT      = Cstacked;                   // rows 0-2047
  ushort_t* logitsTb = Cstacked + (size_t)2048 * 4096;  // rows 2048-3199

  k0_ssq<<<512, 256, 0, stream>>>(x, ssq8);
  k1_transpose<<<dim3(16, 64), 256, 0, stream>>>(x, ssq8, (__hip_bfloat16*)xnb);
  kpack2<<<5000, 256, 0, stream>>>(W_inp, W_gk, W_g, b_inp, b_g,
                                   (__hip_bfloat16*)stackedA, (__hip_bfloat16*)Wgkx, WibT, bWg);
  // GEMM0 split-K x4: Wc4[s] = Wgkx[:, s*512..] @ WibT[:, s*512..]^T
  gemm0_splitk<<<dim3(8, 9, 4), 512, 0, stream>>>(Wgkx, WibT, Wc4);
  // pack: stackedA rows 2048-3199 = bf16(sum_s Wc4[s])
  kpackC<<<1152, 256, 0, stream>>>(Wc4, stackedA + (size_t)2048 * 1024);
  // big stacked GEMM (256^2 tiles, 8-phase): Cstacked[3328,4096] = stackedA @ xnb^T
  gemm256_8ph<<<dim3(16, 13), 512, 0, stream>>>(stackedA, xnb, Cstacked, 1024, 4096);
  k5_softmax<<<2048, 256, 0, stream>>>(logitsTb, bWg, colsumW, wbT);
  k6_vlad_mfma<<<dim3(8, 8, 8), 256, 0, stream>>>(wbT, YcT, vpart);
  k7_intranorm<<<dim3(128, 8), 256, 0, stream>>>(vpart, colsumW, b_inp, cent, out, ss1);
  k8_finalnorm<<<8, 256, 0, stream>>>(ss1, out);
}

// Round 13
// 117.005 us; speedup vs baseline: 1.0507x; 1.0507x over previous
//
#include <hip/hip_runtime.h>
#include <hip/hip_bf16.h>
#include <math.h>

#define EPSN 1e-12f
typedef unsigned short ushort_t;

typedef float f32x4 __attribute__((ext_vector_type(4)));
typedef short s16x8 __attribute__((ext_vector_type(8)));
typedef unsigned short u16x8 __attribute__((ext_vector_type(8)));
typedef unsigned short u16x4 __attribute__((ext_vector_type(4)));

__device__ __forceinline__ void gload_lds16(const void* g, void* l) {
  __builtin_amdgcn_global_load_lds((const __attribute__((address_space(1))) void*)g,
                                   (__attribute__((address_space(3))) void*)l, 16, 0, 0);
}

// ---------------- K1: transpose + scale -> xnb bf16 [tm][c] ----------------
__global__ void k1_transpose(const float* __restrict__ x, const float* __restrict__ ssq8,
                             __hip_bfloat16* __restrict__ xnb) {
  int ct = blockIdx.x;
  int b8 = blockIdx.y;
  int t = threadIdx.x;
  __shared__ float tile[64][65];
  __shared__ float ivs[64];
  if (t < 64) {
    float s = 0.f;
#pragma unroll
    for (int cc = 0; cc < 8; ++cc) s += ssq8[cc * 4096 + b8 * 64 + t];
    ivs[t] = rsqrtf(fmaxf(s, 1e-24f));
  }
  int s = t & 63, cq = t >> 6;
  const float* xp = x + (size_t)b8 * 65536 + (size_t)ct * 64 * 64;
#pragma unroll
  for (int r = 0; r < 16; ++r) {
    int cl = cq * 16 + r;
    tile[cl][s] = xp[cl * 64 + s];
  }
  __syncthreads();
  int cl = t & 63, sq = t >> 6;
#pragma unroll
  for (int r = 0; r < 16; ++r) {
    int smm = sq * 16 + r;
    int tm = b8 * 64 + smm;
    xnb[(size_t)tm * 1024 + ct * 64 + cl] = __float2bfloat16(tile[cl][smm] * ivs[smm]);
  }
}

// ---------------- kpack2 (fused with k0): weights pack + WibT + bWg + per-token ssq ------
__global__ void kpack2(const float* __restrict__ Wi, const float* __restrict__ Wgk,
                       const float* __restrict__ W_g, const float* __restrict__ b_inp,
                       const float* __restrict__ b_g, __hip_bfloat16* __restrict__ oWi,
                       __hip_bfloat16* __restrict__ oWx, ushort_t* __restrict__ oWibT,
                       float* __restrict__ bWg, const float* __restrict__ x,
                       float* __restrict__ ssq8) {
  int bid = blockIdx.x;
  int t = threadIdx.x;
  if (bid < 2048) {
    int i = (bid * 256 + t) * 4;
    float4 v = *(const float4*)(Wi + i);
    oWi[i + 0] = __float2bfloat16(v.x);
    oWi[i + 1] = __float2bfloat16(v.y);
    oWi[i + 2] = __float2bfloat16(v.z);
    oWi[i + 3] = __float2bfloat16(v.w);
  } else if (bid < 4096) {
    int i = ((bid - 2048) * 256 + t) * 4;
    float4 v = *(const float4*)(Wgk + i);
    oWx[i + 0] = __float2bfloat16(v.x);
    oWx[i + 1] = __float2bfloat16(v.y);
    oWx[i + 2] = __float2bfloat16(v.z);
    oWx[i + 3] = __float2bfloat16(v.w);
  } else if (bid < 4112) {
    int i = (bid - 4096) * 1024 + t * 4;  // 16 blocks: 8 gate rows
    float4 v = *(const float4*)(W_g + i);
    __hip_bfloat16* o = oWx + 1024 * 2048 + i;
    o[0] = __float2bfloat16(v.x);
    o[1] = __float2bfloat16(v.y);
    o[2] = __float2bfloat16(v.z);
    o[3] = __float2bfloat16(v.w);
  } else if (bid < 4352) {
    int i = (bid - 4112) * 1024 + t * 4;  // 240 blocks: 120 zero rows of Wgkx
    ushort_t* o = (ushort_t*)(oWx + 1032 * 2048) + i;
    *(u16x4*)o = (u16x4){0, 0, 0, 0};
  } else if (bid < 4360) {
    int j = bid - 4352;  // 0..7
    const float* row = W_g + (size_t)j * 2048;
    float s = 0.f;
    for (int c = t; c < 2048; c += 256) s = fmaf(b_inp[c], row[c], s);
    __shared__ float red[256];
    red[t] = s;
    __syncthreads();
    for (int o = 128; o > 0; o >>= 1) {
      if (t < o) red[t] += red[t + o];
      __syncthreads();
    }
    if (t == 0) bWg[j] = red[0] + b_g[j];
  } else if (bid < 4872) {
    // WibT[1024 c][2048 c'] = cast-transpose of W_inp[2048 c'][1024 c]; 512 tiles 64x64
    int tt = bid - 4360;
    int cp0 = (tt >> 4) * 64;  // c' base
    int c0 = (tt & 15) * 64;   // c base
    __shared__ ushort_t tile[64][72];
    int r = t >> 2, cs = (t & 3) * 16;
    const float* src = Wi + (size_t)(cp0 + r) * 1024 + c0 + cs;
#pragma unroll
    for (int j = 0; j < 16; j += 4) {
      float4 v = *(const float4*)(src + j);
      __hip_bfloat16 h0 = __float2bfloat16(v.x), h1 = __float2bfloat16(v.y);
      __hip_bfloat16 h2 = __float2bfloat16(v.z), h3 = __float2bfloat16(v.w);
      tile[r][cs + j + 0] = *(ushort_t*)&h0;
      tile[r][cs + j + 1] = *(ushort_t*)&h1;
      tile[r][cs + j + 2] = *(ushort_t*)&h2;
      tile[r][cs + j + 3] = *(ushort_t*)&h3;
    }
    __syncthreads();
    int c = t >> 2, ms = (t & 3) * 16;
    u16x8 o0, o1;
#pragma unroll
    for (int j = 0; j < 8; ++j) o0[j] = tile[ms + j][c];
#pragma unroll
    for (int j = 0; j < 8; ++j) o1[j] = tile[ms + 8 + j][c];
    ushort_t* dst = oWibT + (size_t)(c0 + c) * 2048 + cp0 + ms;
    *(u16x8*)dst = o0;
    *(u16x8*)(dst + 8) = o1;
  } else if (bid < 5000) {
    // zero pad rows 3200-3327 of stackedA (128 rows)
    int i = (bid - 4872) * 1024 + t * 4;
    ushort_t* o = (ushort_t*)oWi + (size_t)3200 * 1024 + i;
    *(u16x4*)o = (u16x4){0, 0, 0, 0};
  } else {
    // fused k0: per-token sum of squares partials (512 blocks)
    int kb = bid - 5000;
    int b8 = kb >> 3;
    int cc = kb & 7;
    int s4 = (t & 15) * 4;
    int cg = t >> 4;
    const float* xp = x + (size_t)b8 * 65536 + (size_t)cc * 128 * 64;
    float4 a = {0.f, 0.f, 0.f, 0.f};
#pragma unroll
    for (int j = 0; j < 8; ++j) {
      int c = cg + j * 16;
      float4 v = *(const float4*)(xp + (size_t)c * 64 + s4);
      a.x = fmaf(v.x, v.x, a.x);
      a.y = fmaf(v.y, v.y, a.y);
      a.z = fmaf(v.z, v.z, a.z);
      a.w = fmaf(v.w, v.w, a.w);
    }
    __shared__ float red0[16][68];
    *(float4*)&red0[cg][s4] = a;
    __syncthreads();
    if (t < 64) {
      float s = 0.f;
#pragma unroll
      for (int g = 0; g < 16; ++g) s += red0[g][t];
      ssq8[cc * 4096 + b8 * 64 + t] = s;
    }
  }
}

// ---------------- GEMM0 split-K: Wc4[s][1152][1024] = Wgkx[:,s*512:(s+1)*512] @ WibT^T ------
__launch_bounds__(512, 4)
__global__ void gemm0_splitk(const ushort_t* __restrict__ A, const ushort_t* __restrict__ B,
                             float* __restrict__ Cf) {
  const int Kstride = 2048, N = 1024;
  __shared__ alignas(16) ushort_t SH[32768];
  const int tid = threadIdx.x;
  const int m0 = blockIdx.y * 128, n0 = blockIdx.x * 128;
  const int s = blockIdx.z;
  const int koff = s * 512;
  const int w = tid >> 6, l = tid & 63;
  const int wr = w >> 2, wc = w & 3;
  const int srow = w * 8 + (l >> 3);
  const int ksw = ((l & 7) ^ (l >> 3)) * 8;
  const ushort_t* Ag0 = A + (size_t)(m0 + srow) * Kstride + ksw + koff;
  const ushort_t* Ag1 = A + (size_t)(m0 + 64 + srow) * Kstride + ksw + koff;
  const ushort_t* Bg0 = B + (size_t)(n0 + srow) * Kstride + ksw + koff;
  const ushort_t* Bg1 = B + (size_t)(n0 + 64 + srow) * Kstride + ksw + koff;
  const int l0 = w * 512;
  const int l1 = 4096 + w * 512;

  f32x4 acc[4][2];
#pragma unroll
  for (int i = 0; i < 4; ++i)
#pragma unroll
    for (int j = 0; j < 2; ++j) acc[i][j] = (f32x4){0.f, 0.f, 0.f, 0.f};

  const int sw = l & 7, qq = l >> 4;

#define ASH(buf) (SH + (buf)*8192)
#define BSH(buf) (SH + 16384 + (buf)*8192)
#define STAGE(buf, k0)                               \
  {                                                  \
    gload_lds16(Ag0 + (k0), ASH(buf) + l0);          \
    gload_lds16(Ag1 + (k0), ASH(buf) + l1);          \
    gload_lds16(Bg0 + (k0), BSH(buf) + l0);          \
    gload_lds16(Bg1 + (k0), BSH(buf) + l1);          \
  }
#define COMPUTE(buf)                                                                     \
  {                                                                                      \
    s16x8 af[4][2], bf[2][2];                                                            \
    _Pragma("unroll") for (int kk = 0; kk < 2; ++kk) {                                   \
      int slot = (((kk << 2) + qq) ^ sw) * 8;                                            \
      _Pragma("unroll") for (int mi = 0; mi < 4; ++mi)                                   \
          af[mi][kk] = *(const s16x8*)&ASH(buf)[(wr * 64 + mi * 16 + (l & 15)) * 64 +    \
                                               slot];                                   \
      _Pragma("unroll") for (int ni = 0; ni < 2; ++ni)                                   \
          bf[ni][kk] = *(const s16x8*)&BSH(buf)[(wc * 32 + ni * 16 + (l & 15)) * 64 +    \
                                               slot];                                   \
    }                                                                                    \
    _Pragma("unroll") for (int kk = 0; kk < 2; ++kk)                                     \
        _Pragma("unroll") for (int mi = 0; mi < 4; ++mi)                                 \
            _Pragma("unroll") for (int ni = 0; ni < 2; ++ni)                             \
                acc[mi][ni] = __builtin_amdgcn_mfma_f32_16x16x32_bf16(af[mi][kk],        \
                                                                     bf[ni][kk],        \
                                                                     acc[mi][ni], 0, 0, 0); \
  }

  STAGE(0, 0);
  int buf = 0;
  for (int t = 0; t < 7; ++t) {
    STAGE(buf ^ 1, (t + 1) << 6);
    asm volatile("s_waitcnt vmcnt(4)" ::: "memory");
    __builtin_amdgcn_s_barrier();
    asm volatile("" ::: "memory");
    COMPUTE(buf);
    asm volatile("" ::: "memory");
    __builtin_amdgcn_s_barrier();
    buf ^= 1;
  }
  asm volatile("s_waitcnt vmcnt(0)" ::: "memory");
  __builtin_amdgcn_s_barrier();
  asm volatile("" ::: "memory");
  COMPUTE(buf);
#undef STAGE
#undef COMPUTE
#undef ASH
#undef BSH

  float* Co = Cf + (size_t)s * 1152 * 1024;
#pragma unroll
  for (int mi = 0; mi < 4; ++mi) {
    int row = m0 + wr * 64 + mi * 16 + (l >> 4) * 4;
#pragma unroll
    for (int ni = 0; ni < 2; ++ni) {
      int col = n0 + wc * 32 + ni * 16 + (l & 15);
#pragma unroll
      for (int r = 0; r < 4; ++r)
        Co[(size_t)(row + r) * N + col] = acc[mi][ni][r];
    }
  }
}

// ---------------- kpackC: sum 4 split-K partials -> bf16 into stackedA rows 2048+ ----------
__global__ void kpackC(const float* __restrict__ Wc4, ushort_t* __restrict__ dst) {
  int i = (blockIdx.x * 256 + threadIdx.x) * 4;
  float4 a = *(const float4*)(Wc4 + i);
  float4 b = *(const float4*)(Wc4 + 1179648 + i);
  float4 c = *(const float4*)(Wc4 + 2359296 + i);
  float4 d = *(const float4*)(Wc4 + 3538944 + i);
  float4 sv = {a.x + b.x + c.x + d.x, a.y + b.y + c.y + d.y,
               a.z + b.z + c.z + d.z, a.w + b.w + c.w + d.w};
  u16x4 o;
  __hip_bfloat16 h0 = __float2bfloat16(sv.x), h1 = __float2bfloat16(sv.y);
  __hip_bfloat16 h2 = __float2bfloat16(sv.z), h3 = __float2bfloat16(sv.w);
  o[0] = *(ushort_t*)&h0; o[1] = *(ushort_t*)&h1;
  o[2] = *(ushort_t*)&h2; o[3] = *(ushort_t*)&h3;
  *(u16x4*)(dst + i) = o;
}

// ---------------- big stacked GEMM, 256x256 tile, BK=64, 8-phase, A-frag register reuse ----
// C[3328,4096] = stackedA[3328,1024] @ xnb[4096,1024]^T. 8 waves (2Mx4N), per-wave 128x64.
// Phase-PAIR structure: per (dbuf, mh) read af ONCE (8 ds_read) + bf(nh=0) (4), MFMA,
// then only bf(nh=1) (4), MFMA -> 32 ds_read/K-tile (was 48). Staging schedule, vmcnt
// placement, and race invariants identical to the verified round-12 kernel.
__launch_bounds__(512, 2)
__global__ void gemm256_8ph(const ushort_t* __restrict__ A, const ushort_t* __restrict__ B,
                            ushort_t* __restrict__ C, int K, int N) {
  __shared__ alignas(16) ushort_t SH[65536];  // 128 KB
  const int tid = threadIdx.x;
  const int m0 = blockIdx.y * 256, n0 = blockIdx.x * 256;
  const int w = tid >> 6, l = tid & 63;
  const int wr = w >> 2, wc = w & 3;  // 2x4 wave grid; per-wave 128m x 64n
  const int r16 = l & 15, qq = l >> 4, sw = l & 7;
  const int s = tid >> 3;
  const int s_hi = s >> 5, s_lo = s & 31;
  const int ksw = ((tid & 7) ^ (s & 7)) * 8;
  const int NT = K >> 6;

  const ushort_t* pA0 = A + (size_t)(m0 + s) * K + ksw;
  const ushort_t* pA1 = A + (size_t)(m0 + 128 + s) * K + ksw;
  const ushort_t* pB0 = B + (size_t)(n0 + s_hi * 64 + s_lo) * K + ksw;
  const ushort_t* pB1 = B + (size_t)(n0 + 128 + s_hi * 64 + s_lo) * K + ksw;
  ushort_t* dA = SH + tid * 8;
  ushort_t* dB = SH + 32768 + tid * 8;

  f32x4 acc[8][4];
#pragma unroll
  for (int i = 0; i < 8; ++i)
#pragma unroll
    for (int j = 0; j < 4; ++j) acc[i][j] = (f32x4){0.f, 0.f, 0.f, 0.f};

#define SA(kt, h)                                                                        \
  {                                                                                      \
    gload_lds16(pA0 + (size_t)(h) * (K << 6) + ((kt) << 6),                              \
                dA + (((kt)&1) << 14) + ((h) << 13));                                    \
    gload_lds16(pA1 + (size_t)(h) * (K << 6) + ((kt) << 6),                              \
                dA + (((kt)&1) << 14) + ((h) << 13) + 4096);                             \
  }
#define SB(kt, h)                                                                        \
  {                                                                                      \
    gload_lds16(pB0 + (size_t)(h) * (K << 5) + ((kt) << 6),                              \
                dB + (((kt)&1) << 14) + ((h) << 13));                                    \
    gload_lds16(pB1 + (size_t)(h) * (K << 5) + ((kt) << 6),                              \
                dB + (((kt)&1) << 14) + ((h) << 13) + 4096);                             \
  }
#define VMC4 asm volatile("s_waitcnt vmcnt(4)" ::: "memory")

// phase-pair: quadrants (mh,0) and (mh,1) of dbuf d; af read once, held across both.
#define PHASEPAIR(d, mh, STG1, VM1, STG2, VM2)                                           \
  {                                                                                      \
    s16x8 af[2][4], bf[2][2];                                                            \
    _Pragma("unroll") for (int kk = 0; kk < 2; ++kk) {                                   \
      int slot = (((kk << 2) + qq) ^ sw) * 8;                                            \
      _Pragma("unroll") for (int mi2 = 0; mi2 < 4; ++mi2)                                \
          af[kk][mi2] = *(const s16x8*)&SH[((d) << 14) + ((mh) << 13) +                  \
                                           (wr * 64 + mi2 * 16 + r16) * 64 + slot];      \
      _Pragma("unroll") for (int ni2 = 0; ni2 < 2; ++ni2)                                \
          bf[kk][ni2] = *(const s16x8*)&SH[32768 + ((d) << 14) +                         \
                                           (wc * 32 + ni2 * 16 + r16) * 64 + slot];      \
    }                                                                                    \
    STG1;                                                                                \
    asm volatile("" ::: "memory");                                                       \
    __builtin_amdgcn_s_barrier();                                                        \
    asm volatile("" ::: "memory");                                                       \
    __builtin_amdgcn_s_setprio(1);                                                       \
    _Pragma("unroll") for (int kk = 0; kk < 2; ++kk)                                     \
        _Pragma("unroll") for (int mi2 = 0; mi2 < 4; ++mi2)                              \
            _Pragma("unroll") for (int ni2 = 0; ni2 < 2; ++ni2)                          \
                acc[(mh)*4 + mi2][ni2] = __builtin_amdgcn_mfma_f32_16x16x32_bf16(        \
                    af[kk][mi2], bf[kk][ni2], acc[(mh)*4 + mi2][ni2], 0, 0, 0);          \
    __builtin_amdgcn_s_setprio(0);                                                       \
    VM1;                                                                                 \
    asm volatile("" ::: "memory");                                                       \
    __builtin_amdgcn_s_barrier();                                                        \
    asm volatile("" ::: "memory");                                                       \
    _Pragma("unroll") for (int kk = 0; kk < 2; ++kk) {                                   \
      int slot = (((kk << 2) + qq) ^ sw) * 8;                                            \
      _Pragma("unroll") for (int ni2 = 0; ni2 < 2; ++ni2)                                \
          bf[kk][ni2] = *(const s16x8*)&SH[32768 + ((d) << 14) + 8192 +                  \
                                           (wc * 32 + ni2 * 16 + r16) * 64 + slot];      \
    }                                                                                    \
    STG2;                                                                                \
    asm volatile("" ::: "memory");                                                       \
    __builtin_amdgcn_s_barrier();                                                        \
    asm volatile("" ::: "memory");                                                       \
    __builtin_amdgcn_s_setprio(1);                                                       \
    _Pragma("unroll") for (int kk = 0; kk < 2; ++kk)                                     \
        _Pragma("unroll") for (int mi2 = 0; mi2 < 4; ++mi2)                              \
            _Pragma("unroll") for (int ni2 = 0; ni2 < 2; ++ni2)                          \
                acc[(mh)*4 + mi2][2 + ni2] = __builtin_amdgcn_mfma_f32_16x16x32_bf16(    \
                    af[kk][mi2], bf[kk][ni2], acc[(mh)*4 + mi2][2 + ni2], 0, 0, 0);      \
    __builtin_amdgcn_s_setprio(0);                                                       \
    VM2;                                                                                 \
    asm volatile("" ::: "memory");                                                       \
    __builtin_amdgcn_s_barrier();                                                        \
    asm volatile("" ::: "memory");                                                       \
  }

  // prologue: kt0 complete + kt1.{A0,B0}; vmcnt(4) -> kt0's 4 halves landed
  SA(0, 0); SB(0, 0); SA(0, 1); SB(0, 1); SA(1, 0); SB(1, 0);
  VMC4;
  __builtin_amdgcn_s_barrier();
  asm volatile("" ::: "memory");

#pragma unroll 1
  for (int I = 0; I < (NT >> 1); ++I) {
    const int kt = 2 * I;
    const int k1 = kt + 1, k2 = kt + 2, k3 = kt + 3;
    // pair1 = phases 1,2 (dbuf0, mh=0); pair2 = phases 3,4 (dbuf0, mh=1)
    PHASEPAIR(0, 0, SA(k1, 1), , SB(k1, 1), );
    PHASEPAIR(0, 1, if (k2 < NT) SA(k2, 0), , if (k2 < NT) SB(k2, 0), VMC4);
    // pair3 = phases 5,6 (dbuf1, mh=0); pair4 = phases 7,8 (dbuf1, mh=1)
    PHASEPAIR(1, 0, if (k2 < NT) SA(k2, 1), , if (k2 < NT) SB(k2, 1), );
    PHASEPAIR(1, 1, if (k3 < NT) SA(k3, 0), , if (k3 < NT) SB(k3, 0), VMC4);
  }
#undef PHASEPAIR
#undef SA
#undef SB
#undef VMC4

#pragma unroll
  for (int mi = 0; mi < 8; ++mi) {
    int row = m0 + wr * 128 + mi * 16 + (l >> 4) * 4;
#pragma unroll
    for (int ni = 0; ni < 4; ++ni) {
      int col = n0 + wc * 64 + ni * 16 + r16;
#pragma unroll
      for (int r = 0; r < 4; ++r) {
        __hip_bfloat16 hb = __float2bfloat16(acc[mi][ni][r]);
        C[(size_t)(row + r) * N + col] = *(ushort_t*)&hb;
      }
    }
  }
}

// ---------------- K5: row softmax over tokens + gate sigmoid, one wave per (q,b) ----------------
__launch_bounds__(256)
__global__ void k5_softmax(const ushort_t* __restrict__ logitsTb, const float* __restrict__ bWg,
                           float* __restrict__ colsumW, ushort_t* __restrict__ wbT) {
  int wv = (blockIdx.x << 2) + (threadIdx.x >> 6);
  int q = wv >> 3, b = wv & 7;
  int l = threadIdx.x & 63;
  int g = q >> 7;
  size_t base = (size_t)q * 4096 + b * 512 + l * 8;
  u16x8 v8 = *(const u16x8*)(logitsTb + base);
  float vs[8];
#pragma unroll
  for (int i = 0; i < 8; ++i) vs[i] = __uint_as_float(((unsigned)v8[i]) << 16);
  float M = vs[0];
#pragma unroll
  for (int i = 1; i < 8; ++i) M = fmaxf(M, vs[i]);
#pragma unroll
  for (int m = 1; m < 64; m <<= 1) M = fmaxf(M, __shfl_xor(M, m, 64));
  float e[8], S = 0.f;
#pragma unroll
  for (int i = 0; i < 8; ++i) {
    e[i] = expf(vs[i] - M);
    S += e[i];
  }
#pragma unroll
  for (int m = 1; m < 64; m <<= 1) S += __shfl_xor(S, m, 64);
  float R = 1.0f / S;
  u16x8 g8 = *(const u16x8*)(logitsTb + (size_t)(1024 + g) * 4096 + b * 512 + l * 8);
  float bg = bWg[g];
  float wv8[8], wsum = 0.f;
#pragma unroll
  for (int i = 0; i < 8; ++i) {
    float gl = __uint_as_float(((unsigned)g8[i]) << 16);
    float ag = 1.0f / (1.0f + expf(-(gl + bg)));
    wv8[i] = e[i] * R * ag;
    wsum += wv8[i];
  }
#pragma unroll
  for (int m = 1; m < 64; m <<= 1) wsum += __shfl_xor(wsum, m, 64);
  if (l == 0) colsumW[b * 1024 + q] = wsum;
  u16x8 o;
#pragma unroll
  for (int i = 0; i < 8; ++i) {
    __hip_bfloat16 hb = __float2bfloat16(wv8[i]);
    o[i] = *(ushort_t*)&hb;
  }
  *(u16x8*)(wbT + base) = o;
}

// ---------------- K6: VLAD einsum via MFMA, 64x64 tile, m-split 8, counted vmcnt ----------------
__launch_bounds__(256)
__global__ void k6_vlad_mfma(const ushort_t* __restrict__ wbT, const ushort_t* __restrict__ YcT,
                             float* __restrict__ vpart) {
  int kt = blockIdx.x >> 2, dt = blockIdx.x & 3;
  int ms = blockIdx.y, b = blockIdx.z;
  __shared__ alignas(16) ushort_t Ash[2][4096];
  __shared__ alignas(16) ushort_t Bsh[2][4096];
  const int tid = threadIdx.x;
  const int w = tid >> 6, l = tid & 63;
  const int wr = w >> 1, wc = w & 1;
  const int crow = l >> 3;
  const int ksw = ((l & 7) ^ crow) * 8;

  const ushort_t* Ap[2];
  const ushort_t* Bp[2];
  int loff[2];
#pragma unroll
  for (int c = 0; c < 2; ++c) {
    int chunk = w * 2 + c;
    Ap[c] = wbT + (size_t)(kt * 64 + chunk * 8 + crow) * 4096 + b * 512 + ms * 64 + ksw;
    Bp[c] = YcT + (size_t)(dt * 64 + chunk * 8 + crow) * 4096 + b * 512 + ms * 64 + ksw;
    loff[c] = chunk * 512;
  }

  f32x4 acc[2][2];
#pragma unroll
  for (int i = 0; i < 2; ++i)
#pragma unroll
    for (int j = 0; j < 2; ++j) acc[i][j] = (f32x4){0.f, 0.f, 0.f, 0.f};

  const int sw = l & 7, qq = l >> 4;

#define STAGE6(buf, g)                                                       \
  {                                                                          \
    size_t offA = (size_t)(g)*524288;                                        \
    size_t offB = (size_t)(g)*1048576;                                       \
    gload_lds16(Ap[0] + offA, &Ash[buf][loff[0]]);                           \
    gload_lds16(Ap[1] + offA, &Ash[buf][loff[1]]);                           \
    gload_lds16(Bp[0] + offB, &Bsh[buf][loff[0]]);                           \
    gload_lds16(Bp[1] + offB, &Bsh[buf][loff[1]]);                           \
  }
#define COMPUTE6(buf)                                                                    \
  {                                                                                      \
    s16x8 af[2][2], bf[2][2];                                                            \
    _Pragma("unroll") for (int kk = 0; kk < 2; ++kk) {                                   \
      int slot = (((kk << 2) + qq) ^ sw) * 8;                                            \
      _Pragma("unroll") for (int mi = 0; mi < 2; ++mi) {                                 \
        af[mi][kk] = *(const s16x8*)&Ash[buf][(wr * 32 + mi * 16 + (l & 15)) * 64 +      \
                                             slot];                                     \
        bf[mi][kk] = *(const s16x8*)&Bsh[buf][(wc * 32 + mi * 16 + (l & 15)) * 64 +      \
                                             slot];                                     \
      }                                                                                  \
    }                                                                                    \
    _Pragma("unroll") for (int kk = 0; kk < 2; ++kk)                                     \
        _Pragma("unroll") for (int mi = 0; mi < 2; ++mi)                                 \
            _Pragma("unroll") for (int ni = 0; ni < 2; ++ni)                             \
                acc[mi][ni] = __builtin_amdgcn_mfma_f32_16x16x32_bf16(af[mi][kk],        \
                                                                     bf[ni][kk],        \
                                                                     acc[mi][ni], 0, 0, 0); \
  }

  STAGE6(0, 0);
  int buf = 0;
  for (int s = 0; s < 7; ++s) {
    STAGE6(buf ^ 1, s + 1);
    asm volatile("s_waitcnt vmcnt(4)" ::: "memory");
    __builtin_amdgcn_s_barrier();
    asm volatile("" ::: "memory");
    COMPUTE6(buf);
    asm volatile("" ::: "memory");
    __builtin_amdgcn_s_barrier();
    buf ^= 1;
  }
  asm volatile("s_waitcnt vmcnt(0)" ::: "memory");
  __builtin_amdgcn_s_barrier();
  asm volatile("" ::: "memory");
  COMPUTE6(buf);
#undef STAGE6
#undef COMPUTE6

#pragma unroll
  for (int mi = 0; mi < 2; ++mi) {
    int row = kt * 64 + wr * 32 + mi * 16 + (l >> 4) * 4;
#pragma unroll
    for (int ni = 0; ni < 2; ++ni) {
      int col = dt * 64 + wc * 32 + ni * 16 + (l & 15);
#pragma unroll
      for (int r = 0; r < 4; ++r)
        vpart[((size_t)(ms * 8 + b) * 128 + row + r) * 256 + col] = acc[mi][ni][r];
    }
  }
}

// ---------------- K7: combine 8 partials + bias-part - S*centroid, intra-normalize ----------------
__global__ void k7_intranorm(const float* __restrict__ vpart, const float* __restrict__ colsumW,
                             const float* __restrict__ b_inp, const float* __restrict__ cent,
                             float* __restrict__ out, float* __restrict__ ss1) {
  int k = blockIdx.x;
  int b = blockIdx.y;
  int d = threadIdx.x;
  float S = 0.f, bp = 0.f;
#pragma unroll
  for (int g = 0; g < 8; ++g) {
    float cw = colsumW[b * 1024 + g * 128 + k];
    S += cw;
    bp = fmaf(b_inp[g * 256 + d], cw, bp);
  }
  size_t off = ((size_t)b * 128 + k) * 256 + d;
  float v = bp - S * cent[(size_t)k * 256 + d];
#pragma unroll
  for (int i = 0; i < 8; ++i) v += vpart[off + (size_t)i * 262144];
  float ss = v * v;
#pragma unroll
  for (int m = 1; m < 64; m <<= 1) ss += __shfl_xor(ss, m, 64);
  __shared__ float red[4];
  int lane = d & 63, wv = d >> 6;
  if (lane == 0) red[wv] = ss;
  __syncthreads();
  float tot = red[0] + red[1] + red[2] + red[3];
  float rinv = 1.0f / fmaxf(sqrtf(tot), EPSN);
  out[off] = v * rinv;
  if (d == 0) ss1[b * 128 + k] = tot * rinv * rinv;
}

// ---------------- K8: final global L2 norm ----------------
__global__ void k8_finalnorm(const float* __restrict__ ss1, float* __restrict__ out) {
  int b = blockIdx.x;
  int t = threadIdx.x;
  __shared__ float red[256];
  red[t] = (t < 128) ? ss1[b * 128 + t] : 0.f;
  __syncthreads();
  for (int o = 128; o > 0; o >>= 1) {
    if (t < o) red[t] += red[t + o];
    __syncthreads();
  }
  float rinv = 1.0f / fmaxf(sqrtf(red[0]), EPSN);
  float* op = out + (size_t)b * 32768;
  for (int i = t; i < 32768; i += 256) op[i] *= rinv;
}

extern "C" void kernel_launch(void* const* d_in, const int* in_sizes, int n_in,
                              void* d_out, int out_size, void* d_ws, size_t ws_size,
                              hipStream_t stream) {
  const float* x     = (const float*)d_in[0];
  const float* W_inp = (const float*)d_in[1];
  const float* b_inp = (const float*)d_in[2];
  const float* W_g   = (const float*)d_in[3];
  const float* b_g   = (const float*)d_in[4];
  const float* W_gk  = (const float*)d_in[5];
  // b_gk (d_in[6]) cancels in the token-axis softmax — unused.
  const float* cent  = (const float*)d_in[7];
  float* out = (float*)d_out;
  float* ws = (float*)d_ws;

  // workspace layout (float offsets), total 12,887,104 floats = 51.5 MB
  float* ssq8    = ws + 0;         // 32768
  float* colsumW = ws + 32768;     // 8192
  float* ss1     = ws + 40960;     // 1024
  float* bWg     = ws + 41984;     // 64
  ushort_t* xnb  = (ushort_t*)(ws + 42048);        // [4096][1024] bf16 (2097152 fl)
  ushort_t* wbT  = xnb;                            // alias (xnb dead after gemm256)
  ushort_t* stackedA = (ushort_t*)(ws + 2139200);  // [3328][1024] bf16 (1703936 fl)
  ushort_t* WibT = (ushort_t*)(ws + 3843136);      // [1024][2048] bf16 (1048576 fl)
  ushort_t* Wgkx = (ushort_t*)(ws + 4891712);      // [1152][2048] bf16 (1179648 fl)
  float* vpart   = ws + 3843136;   // 2097152 fl, aliases WibT+Wgkx (dead after GEMM0)
  float* Wc4     = ws + 6071360;   // [4][1152][1024] f32 (4718592 fl), dead after kpackC
  ushort_t* Cstacked = (ushort_t*)(ws + 6071360);  // [3328][4096] bf16 (6815744 fl), over Wc4
  ushort_t* YcT      = Cstacked;                   // rows 0-2047
  ushort_t* logitsTb = Cstacked + (size_t)2048 * 4096;  // rows 2048-3199

  // fused prep: weights pack + WibT + bWg + k0 ssq partials
  kpack2<<<5512, 256, 0, stream>>>(W_inp, W_gk, W_g, b_inp, b_g,
                                   (__hip_bfloat16*)stackedA, (__hip_bfloat16*)Wgkx, WibT, bWg,
                                   x, ssq8);
  k1_transpose<<<dim3(16, 64), 256, 0, stream>>>(x, ssq8, (__hip_bfloat16*)xnb);
  // GEMM0 split-K x4: Wc4[s] = Wgkx[:, s*512..] @ WibT[:, s*512..]^T
  gemm0_splitk<<<dim3(8, 9, 4), 512, 0, stream>>>(Wgkx, WibT, Wc4);
  // pack: stackedA rows 2048-3199 = bf16(sum_s Wc4[s])
  kpackC<<<1152, 256, 0, stream>>>(Wc4, stackedA + (size_t)2048 * 1024);
  // big stacked GEMM (256^2 tiles, 8-phase, A-frag reuse): Cstacked = stackedA @ xnb^T
  gemm256_8ph<<<dim3(16, 13), 512, 0, stream>>>(stackedA, xnb, Cstacked, 1024, 4096);
  k5_softmax<<<2048, 256, 0, stream>>>(logitsTb, bWg, colsumW, wbT);
  k6_vlad_mfma<<<dim3(8, 8, 8), 256, 0, stream>>>(wbT, YcT, vpart);
  k7_intranorm<<<dim3(128, 8), 256, 0, stream>>>(vpart, colsumW, b_inp, cent, out, ss1);
  k8_finalnorm<<<8, 256, 0, stream>>>(ss1, out);
}

// Round 14
// 115.191 us; speedup vs baseline: 1.0672x; 1.0157x over previous
//
#include <hip/hip_runtime.h>
#include <hip/hip_bf16.h>
#include <math.h>

#define EPSN 1e-12f
typedef unsigned short ushort_t;

typedef float f32x4 __attribute__((ext_vector_type(4)));
typedef short s16x8 __attribute__((ext_vector_type(8)));
typedef unsigned short u16x8 __attribute__((ext_vector_type(8)));
typedef unsigned short u16x4 __attribute__((ext_vector_type(4)));

__device__ __forceinline__ void gload_lds16(const void* g, void* l) {
  __builtin_amdgcn_global_load_lds((const __attribute__((address_space(1))) void*)g,
                                   (__attribute__((address_space(3))) void*)l, 16, 0, 0);
}

// ---------------- kpack2 (fused with k0): weights pack + WibT + bWg + per-token ssq ------
__global__ void kpack2(const float* __restrict__ Wi, const float* __restrict__ Wgk,
                       const float* __restrict__ W_g, const float* __restrict__ b_inp,
                       const float* __restrict__ b_g, __hip_bfloat16* __restrict__ oWi,
                       __hip_bfloat16* __restrict__ oWx, ushort_t* __restrict__ oWibT,
                       float* __restrict__ bWg, const float* __restrict__ x,
                       float* __restrict__ ssq8) {
  int bid = blockIdx.x;
  int t = threadIdx.x;
  if (bid < 2048) {
    int i = (bid * 256 + t) * 4;
    float4 v = *(const float4*)(Wi + i);
    oWi[i + 0] = __float2bfloat16(v.x);
    oWi[i + 1] = __float2bfloat16(v.y);
    oWi[i + 2] = __float2bfloat16(v.z);
    oWi[i + 3] = __float2bfloat16(v.w);
  } else if (bid < 4096) {
    int i = ((bid - 2048) * 256 + t) * 4;
    float4 v = *(const float4*)(Wgk + i);
    oWx[i + 0] = __float2bfloat16(v.x);
    oWx[i + 1] = __float2bfloat16(v.y);
    oWx[i + 2] = __float2bfloat16(v.z);
    oWx[i + 3] = __float2bfloat16(v.w);
  } else if (bid < 4112) {
    int i = (bid - 4096) * 1024 + t * 4;  // 16 blocks: 8 gate rows
    float4 v = *(const float4*)(W_g + i);
    __hip_bfloat16* o = oWx + 1024 * 2048 + i;
    o[0] = __float2bfloat16(v.x);
    o[1] = __float2bfloat16(v.y);
    o[2] = __float2bfloat16(v.z);
    o[3] = __float2bfloat16(v.w);
  } else if (bid < 4352) {
    int i = (bid - 4112) * 1024 + t * 4;  // 240 blocks: 120 zero rows of Wgkx
    ushort_t* o = (ushort_t*)(oWx + 1032 * 2048) + i;
    *(u16x4*)o = (u16x4){0, 0, 0, 0};
  } else if (bid < 4360) {
    int j = bid - 4352;  // 0..7
    const float* row = W_g + (size_t)j * 2048;
    float s = 0.f;
    for (int c = t; c < 2048; c += 256) s = fmaf(b_inp[c], row[c], s);
    __shared__ float red[256];
    red[t] = s;
    __syncthreads();
    for (int o = 128; o > 0; o >>= 1) {
      if (t < o) red[t] += red[t + o];
      __syncthreads();
    }
    if (t == 0) bWg[j] = red[0] + b_g[j];
  } else if (bid < 4872) {
    // WibT[1024 c][2048 c'] = cast-transpose of W_inp; 512 tiles 64x64
    int tt = bid - 4360;
    int cp0 = (tt >> 4) * 64;
    int c0 = (tt & 15) * 64;
    __shared__ ushort_t tile[64][72];
    int r = t >> 2, cs = (t & 3) * 16;
    const float* src = Wi + (size_t)(cp0 + r) * 1024 + c0 + cs;
#pragma unroll
    for (int j = 0; j < 16; j += 4) {
      float4 v = *(const float4*)(src + j);
      __hip_bfloat16 h0 = __float2bfloat16(v.x), h1 = __float2bfloat16(v.y);
      __hip_bfloat16 h2 = __float2bfloat16(v.z), h3 = __float2bfloat16(v.w);
      tile[r][cs + j + 0] = *(ushort_t*)&h0;
      tile[r][cs + j + 1] = *(ushort_t*)&h1;
      tile[r][cs + j + 2] = *(ushort_t*)&h2;
      tile[r][cs + j + 3] = *(ushort_t*)&h3;
    }
    __syncthreads();
    int c = t >> 2, ms = (t & 3) * 16;
    u16x8 o0, o1;
#pragma unroll
    for (int j = 0; j < 8; ++j) o0[j] = tile[ms + j][c];
#pragma unroll
    for (int j = 0; j < 8; ++j) o1[j] = tile[ms + 8 + j][c];
    ushort_t* dst = oWibT + (size_t)(c0 + c) * 2048 + cp0 + ms;
    *(u16x8*)dst = o0;
    *(u16x8*)(dst + 8) = o1;
  } else if (bid < 5000) {
    // zero pad rows 3200-3327 of stackedA
    int i = (bid - 4872) * 1024 + t * 4;
    ushort_t* o = (ushort_t*)oWi + (size_t)3200 * 1024 + i;
    *(u16x4*)o = (u16x4){0, 0, 0, 0};
  } else {
    // fused k0: per-token sum of squares partials (512 blocks)
    int kb = bid - 5000;
    int b8 = kb >> 3;
    int cc = kb & 7;
    int s4 = (t & 15) * 4;
    int cg = t >> 4;
    const float* xp = x + (size_t)b8 * 65536 + (size_t)cc * 128 * 64;
    float4 a = {0.f, 0.f, 0.f, 0.f};
#pragma unroll
    for (int j = 0; j < 8; ++j) {
      int c = cg + j * 16;
      float4 v = *(const float4*)(xp + (size_t)c * 64 + s4);
      a.x = fmaf(v.x, v.x, a.x);
      a.y = fmaf(v.y, v.y, a.y);
      a.z = fmaf(v.z, v.z, a.z);
      a.w = fmaf(v.w, v.w, a.w);
    }
    __shared__ float red0[16][68];
    *(float4*)&red0[cg][s4] = a;
    __syncthreads();
    if (t < 64) {
      float s = 0.f;
#pragma unroll
      for (int g = 0; g < 16; ++g) s += red0[g][t];
      ssq8[cc * 4096 + b8 * 64 + t] = s;
    }
  }
}

// ---------------- fused: GEMM0 split-K (blocks 0-287) + k1 transpose (blocks 288-799) ----
// gemm0: Wc4[s][1152][1024] = Wgkx[:,s*512:(s+1)*512] @ WibT[...]^T, 128^2 tile, 8 waves.
// k1: two 64x64 transpose+scale tiles per 512-thread block (half-block split).
__launch_bounds__(512, 4)
__global__ void g0k1(const ushort_t* __restrict__ A, const ushort_t* __restrict__ B,
                     float* __restrict__ Cf, const float* __restrict__ x,
                     const float* __restrict__ ssq8, __hip_bfloat16* __restrict__ xnb) {
  __shared__ alignas(16) unsigned char SHRAW[65536];
  const int bid = blockIdx.x;
  const int tid = threadIdx.x;
  if (bid >= 288) {
    // ---- k1 path: tile_id = (bid-288)*2 + (tid>>8)
    int ht = tid >> 8, t = tid & 255;
    int tile_id = (bid - 288) * 2 + ht;
    int ct = tile_id & 15, b8 = tile_id >> 4;
    float* tbuf = (float*)(SHRAW + ht * 20480);  // [64][65]
    float* ivs = tbuf + 64 * 65;
    if (t < 64) {
      float s = 0.f;
#pragma unroll
      for (int cc = 0; cc < 8; ++cc) s += ssq8[cc * 4096 + b8 * 64 + t];
      ivs[t] = rsqrtf(fmaxf(s, 1e-24f));
    }
    int s = t & 63, cq = t >> 6;
    const float* xp = x + (size_t)b8 * 65536 + (size_t)ct * 64 * 64;
#pragma unroll
    for (int r = 0; r < 16; ++r) {
      int cl = cq * 16 + r;
      tbuf[cl * 65 + s] = xp[cl * 64 + s];
    }
    __syncthreads();
    int cl = t & 63, sq = t >> 6;
#pragma unroll
    for (int r = 0; r < 16; ++r) {
      int smm = sq * 16 + r;
      int tm = b8 * 64 + smm;
      xnb[(size_t)tm * 1024 + ct * 64 + cl] = __float2bfloat16(tbuf[cl * 65 + smm] * ivs[smm]);
    }
    return;
  }
  // ---- gemm0 path
  ushort_t* SH = (ushort_t*)SHRAW;  // 32768 ushorts
  const int Kstride = 2048, N = 1024;
  const int nx = bid & 7, ny = (bid >> 3) % 9, sK = bid / 72;
  const int m0 = ny * 128, n0 = nx * 128;
  const int koff = sK * 512;
  const int w = tid >> 6, l = tid & 63;
  const int wr = w >> 2, wc = w & 3;
  const int srow = w * 8 + (l >> 3);
  const int ksw = ((l & 7) ^ (l >> 3)) * 8;
  const ushort_t* Ag0 = A + (size_t)(m0 + srow) * Kstride + ksw + koff;
  const ushort_t* Ag1 = A + (size_t)(m0 + 64 + srow) * Kstride + ksw + koff;
  const ushort_t* Bg0 = B + (size_t)(n0 + srow) * Kstride + ksw + koff;
  const ushort_t* Bg1 = B + (size_t)(n0 + 64 + srow) * Kstride + ksw + koff;
  const int l0 = w * 512;
  const int l1 = 4096 + w * 512;

  f32x4 acc[4][2];
#pragma unroll
  for (int i = 0; i < 4; ++i)
#pragma unroll
    for (int j = 0; j < 2; ++j) acc[i][j] = (f32x4){0.f, 0.f, 0.f, 0.f};

  const int sw = l & 7, qq = l >> 4;

#define ASH(buf) (SH + (buf)*8192)
#define BSH(buf) (SH + 16384 + (buf)*8192)
#define STAGE(buf, k0)                               \
  {                                                  \
    gload_lds16(Ag0 + (k0), ASH(buf) + l0);          \
    gload_lds16(Ag1 + (k0), ASH(buf) + l1);          \
    gload_lds16(Bg0 + (k0), BSH(buf) + l0);          \
    gload_lds16(Bg1 + (k0), BSH(buf) + l1);          \
  }
#define COMPUTE(buf)                                                                     \
  {                                                                                      \
    s16x8 af[4][2], bf[2][2];                                                            \
    _Pragma("unroll") for (int kk = 0; kk < 2; ++kk) {                                   \
      int slot = (((kk << 2) + qq) ^ sw) * 8;                                            \
      _Pragma("unroll") for (int mi = 0; mi < 4; ++mi)                                   \
          af[mi][kk] = *(const s16x8*)&ASH(buf)[(wr * 64 + mi * 16 + (l & 15)) * 64 +    \
                                               slot];                                   \
      _Pragma("unroll") for (int ni = 0; ni < 2; ++ni)                                   \
          bf[ni][kk] = *(const s16x8*)&BSH(buf)[(wc * 32 + ni * 16 + (l & 15)) * 64 +    \
                                               slot];                                   \
    }                                                                                    \
    _Pragma("unroll") for (int kk = 0; kk < 2; ++kk)                                     \
        _Pragma("unroll") for (int mi = 0; mi < 4; ++mi)                                 \
            _Pragma("unroll") for (int ni = 0; ni < 2; ++ni)                             \
                acc[mi][ni] = __builtin_amdgcn_mfma_f32_16x16x32_bf16(af[mi][kk],        \
                                                                     bf[ni][kk],        \
                                                                     acc[mi][ni], 0, 0, 0); \
  }

  STAGE(0, 0);
  int buf = 0;
  for (int t2 = 0; t2 < 7; ++t2) {
    STAGE(buf ^ 1, (t2 + 1) << 6);
    asm volatile("s_waitcnt vmcnt(4)" ::: "memory");
    __builtin_amdgcn_s_barrier();
    asm volatile("" ::: "memory");
    COMPUTE(buf);
    asm volatile("" ::: "memory");
    __builtin_amdgcn_s_barrier();
    buf ^= 1;
  }
  asm volatile("s_waitcnt vmcnt(0)" ::: "memory");
  __builtin_amdgcn_s_barrier();
  asm volatile("" ::: "memory");
  COMPUTE(buf);
#undef STAGE
#undef COMPUTE
#undef ASH
#undef BSH

  float* Co = Cf + (size_t)sK * 1152 * 1024;
#pragma unroll
  for (int mi = 0; mi < 4; ++mi) {
    int row = m0 + wr * 64 + mi * 16 + (l >> 4) * 4;
#pragma unroll
    for (int ni = 0; ni < 2; ++ni) {
      int col = n0 + wc * 32 + ni * 16 + (l & 15);
#pragma unroll
      for (int r = 0; r < 4; ++r)
        Co[(size_t)(row + r) * N + col] = acc[mi][ni][r];
    }
  }
}

// ---------------- kpackC: sum 4 split-K partials -> bf16 into stackedA rows 2048+ ----------
__global__ void kpackC(const float* __restrict__ Wc4, ushort_t* __restrict__ dst) {
  int i = (blockIdx.x * 256 + threadIdx.x) * 4;
  float4 a = *(const float4*)(Wc4 + i);
  float4 b = *(const float4*)(Wc4 + 1179648 + i);
  float4 c = *(const float4*)(Wc4 + 2359296 + i);
  float4 d = *(const float4*)(Wc4 + 3538944 + i);
  float4 sv = {a.x + b.x + c.x + d.x, a.y + b.y + c.y + d.y,
               a.z + b.z + c.z + d.z, a.w + b.w + c.w + d.w};
  u16x4 o;
  __hip_bfloat16 h0 = __float2bfloat16(sv.x), h1 = __float2bfloat16(sv.y);
  __hip_bfloat16 h2 = __float2bfloat16(sv.z), h3 = __float2bfloat16(sv.w);
  o[0] = *(ushort_t*)&h0; o[1] = *(ushort_t*)&h1;
  o[2] = *(ushort_t*)&h2; o[3] = *(ushort_t*)&h3;
  *(u16x4*)(dst + i) = o;
}

// ---------------- big stacked GEMM, 256x256 tile, 8-phase, A-reuse, coalesced epilogue ----
__launch_bounds__(512, 2)
__global__ void gemm256_8ph(const ushort_t* __restrict__ A, const ushort_t* __restrict__ B,
                            ushort_t* __restrict__ C, int K, int N) {
  __shared__ alignas(16) ushort_t SH[65536];  // 128 KB
  const int tid = threadIdx.x;
  const int m0 = blockIdx.y * 256, n0 = blockIdx.x * 256;
  const int w = tid >> 6, l = tid & 63;
  const int wr = w >> 2, wc = w & 3;  // 2x4 wave grid; per-wave 128m x 64n
  const int r16 = l & 15, qq = l >> 4, sw = l & 7;
  const int s = tid >> 3;
  const int s_hi = s >> 5, s_lo = s & 31;
  const int ksw = ((tid & 7) ^ (s & 7)) * 8;
  const int NT = K >> 6;

  const ushort_t* pA0 = A + (size_t)(m0 + s) * K + ksw;
  const ushort_t* pA1 = A + (size_t)(m0 + 128 + s) * K + ksw;
  const ushort_t* pB0 = B + (size_t)(n0 + s_hi * 64 + s_lo) * K + ksw;
  const ushort_t* pB1 = B + (size_t)(n0 + 128 + s_hi * 64 + s_lo) * K + ksw;
  ushort_t* dA = SH + tid * 8;
  ushort_t* dB = SH + 32768 + tid * 8;

  f32x4 acc[8][4];
#pragma unroll
  for (int i = 0; i < 8; ++i)
#pragma unroll
    for (int j = 0; j < 4; ++j) acc[i][j] = (f32x4){0.f, 0.f, 0.f, 0.f};

#define SA(kt, h)                                                                        \
  {                                                                                      \
    gload_lds16(pA0 + (size_t)(h) * (K << 6) + ((kt) << 6),                              \
                dA + (((kt)&1) << 14) + ((h) << 13));                                    \
    gload_lds16(pA1 + (size_t)(h) * (K << 6) + ((kt) << 6),                              \
                dA + (((kt)&1) << 14) + ((h) << 13) + 4096);                             \
  }
#define SB(kt, h)                                                                        \
  {                                                                                      \
    gload_lds16(pB0 + (size_t)(h) * (K << 5) + ((kt) << 6),                              \
                dB + (((kt)&1) << 14) + ((h) << 13));                                    \
    gload_lds16(pB1 + (size_t)(h) * (K << 5) + ((kt) << 6),                              \
                dB + (((kt)&1) << 14) + ((h) << 13) + 4096);                             \
  }
#define VMC4 asm volatile("s_waitcnt vmcnt(4)" ::: "memory")

#define PHASEPAIR(d, mh, STG1, VM1, STG2, VM2)                                           \
  {                                                                                      \
    s16x8 af[2][4], bf[2][2];                                                            \
    _Pragma("unroll") for (int kk = 0; kk < 2; ++kk) {                                   \
      int slot = (((kk << 2) + qq) ^ sw) * 8;                                            \
      _Pragma("unroll") for (int mi2 = 0; mi2 < 4; ++mi2)                                \
          af[kk][mi2] = *(const s16x8*)&SH[((d) << 14) + ((mh) << 13) +                  \
                                           (wr * 64 + mi2 * 16 + r16) * 64 + slot];      \
      _Pragma("unroll") for (int ni2 = 0; ni2 < 2; ++ni2)                                \
          bf[kk][ni2] = *(const s16x8*)&SH[32768 + ((d) << 14) +                         \
                                           (wc * 32 + ni2 * 16 + r16) * 64 + slot];      \
    }                                                                                    \
    STG1;                                                                                \
    asm volatile("" ::: "memory");                                                       \
    __builtin_amdgcn_s_barrier();                                                        \
    asm volatile("" ::: "memory");                                                       \
    __builtin_amdgcn_s_setprio(1);                                                       \
    _Pragma("unroll") for (int kk = 0; kk < 2; ++kk)                                     \
        _Pragma("unroll") for (int mi2 = 0; mi2 < 4; ++mi2)                              \
            _Pragma("unroll") for (int ni2 = 0; ni2 < 2; ++ni2)                          \
                acc[(mh)*4 + mi2][ni2] = __builtin_amdgcn_mfma_f32_16x16x32_bf16(        \
                    af[kk][mi2], bf[kk][ni2], acc[(mh)*4 + mi2][ni2], 0, 0, 0);          \
    __builtin_amdgcn_s_setprio(0);                                                       \
    VM1;                                                                                 \
    asm volatile("" ::: "memory");                                                       \
    __builtin_amdgcn_s_barrier();                                                        \
    asm volatile("" ::: "memory");                                                       \
    _Pragma("unroll") for (int kk = 0; kk < 2; ++kk) {                                   \
      int slot = (((kk << 2) + qq) ^ sw) * 8;                                            \
      _Pragma("unroll") for (int ni2 = 0; ni2 < 2; ++ni2)                                \
          bf[kk][ni2] = *(const s16x8*)&SH[32768 + ((d) << 14) + 8192 +                  \
                                           (wc * 32 + ni2 * 16 + r16) * 64 + slot];      \
    }                                                                                    \
    STG2;                                                                                \
    asm volatile("" ::: "memory");                                                       \
    __builtin_amdgcn_s_barrier();                                                        \
    asm volatile("" ::: "memory");                                                       \
    __builtin_amdgcn_s_setprio(1);                                                       \
    _Pragma("unroll") for (int kk = 0; kk < 2; ++kk)                                     \
        _Pragma("unroll") for (int mi2 = 0; mi2 < 4; ++mi2)                              \
            _Pragma("unroll") for (int ni2 = 0; ni2 < 2; ++ni2)                          \
                acc[(mh)*4 + mi2][2 + ni2] = __builtin_amdgcn_mfma_f32_16x16x32_bf16(    \
                    af[kk][mi2], bf[kk][ni2], acc[(mh)*4 + mi2][2 + ni2], 0, 0, 0);      \
    __builtin_amdgcn_s_setprio(0);                                                       \
    VM2;                                                                                 \
    asm volatile("" ::: "memory");                                                       \
    __builtin_amdgcn_s_barrier();                                                        \
    asm volatile("" ::: "memory");                                                       \
  }

  SA(0, 0); SB(0, 0); SA(0, 1); SB(0, 1); SA(1, 0); SB(1, 0);
  VMC4;
  __builtin_amdgcn_s_barrier();
  asm volatile("" ::: "memory");

#pragma unroll 1
  for (int I = 0; I < (NT >> 1); ++I) {
    const int kt = 2 * I;
    const int k1 = kt + 1, k2 = kt + 2, k3 = kt + 3;
    PHASEPAIR(0, 0, SA(k1, 1), , SB(k1, 1), );
    PHASEPAIR(0, 1, if (k2 < NT) SA(k2, 0), , if (k2 < NT) SB(k2, 0), VMC4);
    PHASEPAIR(1, 0, if (k2 < NT) SA(k2, 1), , if (k2 < NT) SB(k2, 1), );
    PHASEPAIR(1, 1, if (k3 < NT) SA(k3, 0), , if (k3 < NT) SB(k3, 0), VMC4);
  }
#undef PHASEPAIR
#undef SA
#undef SB
#undef VMC4

  // -------- coalesced epilogue: per-wave LDS bounce, u16x8 stores --------
  ushort_t* eb = SH + w * 2048;  // 4KB region per wave; need 16*68=1088 elems
  const int erow = (l >> 4) * 4;
  const int rrow = l >> 2, rc = (l & 3) * 16;
#pragma unroll
  for (int mi = 0; mi < 8; ++mi) {
    asm volatile("s_waitcnt lgkmcnt(0)" ::: "memory");  // prior reads done before overwrite
#pragma unroll
    for (int ni = 0; ni < 4; ++ni)
#pragma unroll
      for (int r = 0; r < 4; ++r) {
        __hip_bfloat16 hb = __float2bfloat16(acc[mi][ni][r]);
        eb[(erow + r) * 68 + ni * 16 + r16] = *(ushort_t*)&hb;
      }
    asm volatile("s_waitcnt lgkmcnt(0)" ::: "memory");  // writes visible to wave's lanes
    u16x8 v0 = *(const u16x8*)&eb[rrow * 68 + rc];
    u16x8 v1 = *(const u16x8*)&eb[rrow * 68 + rc + 8];
    size_t gbase = (size_t)(m0 + wr * 128 + mi * 16 + rrow) * N + n0 + wc * 64 + rc;
    *(u16x8*)&C[gbase] = v0;
    *(u16x8*)&C[gbase + 8] = v1;
  }
}

// ---------------- K5: row softmax over tokens + gate sigmoid, one wave per (q,b) ----------------
__launch_bounds__(256)
__global__ void k5_softmax(const ushort_t* __restrict__ logitsTb, const float* __restrict__ bWg,
                           float* __restrict__ colsumW, ushort_t* __restrict__ wbT) {
  int wv = (blockIdx.x << 2) + (threadIdx.x >> 6);
  int q = wv >> 3, b = wv & 7;
  int l = threadIdx.x & 63;
  int g = q >> 7;
  size_t base = (size_t)q * 4096 + b * 512 + l * 8;
  u16x8 v8 = *(const u16x8*)(logitsTb + base);
  float vs[8];
#pragma unroll
  for (int i = 0; i < 8; ++i) vs[i] = __uint_as_float(((unsigned)v8[i]) << 16);
  float M = vs[0];
#pragma unroll
  for (int i = 1; i < 8; ++i) M = fmaxf(M, vs[i]);
#pragma unroll
  for (int m = 1; m < 64; m <<= 1) M = fmaxf(M, __shfl_xor(M, m, 64));
  float e[8], S = 0.f;
#pragma unroll
  for (int i = 0; i < 8; ++i) {
    e[i] = expf(vs[i] - M);
    S += e[i];
  }
#pragma unroll
  for (int m = 1; m < 64; m <<= 1) S += __shfl_xor(S, m, 64);
  float R = 1.0f / S;
  u16x8 g8 = *(const u16x8*)(logitsTb + (size_t)(1024 + g) * 4096 + b * 512 + l * 8);
  float bg = bWg[g];
  float wv8[8], wsum = 0.f;
#pragma unroll
  for (int i = 0; i < 8; ++i) {
    float gl = __uint_as_float(((unsigned)g8[i]) << 16);
    float ag = 1.0f / (1.0f + expf(-(gl + bg)));
    wv8[i] = e[i] * R * ag;
    wsum += wv8[i];
  }
#pragma unroll
  for (int m = 1; m < 64; m <<= 1) wsum += __shfl_xor(wsum, m, 64);
  if (l == 0) colsumW[b * 1024 + q] = wsum;
  u16x8 o;
#pragma unroll
  for (int i = 0; i < 8; ++i) {
    __hip_bfloat16 hb = __float2bfloat16(wv8[i]);
    o[i] = *(ushort_t*)&hb;
  }
  *(u16x8*)(wbT + base) = o;
}

// ---------------- K6: VLAD einsum via MFMA, 64x64 tile, m-split 8, counted vmcnt ----------------
__launch_bounds__(256)
__global__ void k6_vlad_mfma(const ushort_t* __restrict__ wbT, const ushort_t* __restrict__ YcT,
                             float* __restrict__ vpart) {
  int kt = blockIdx.x >> 2, dt = blockIdx.x & 3;
  int ms = blockIdx.y, b = blockIdx.z;
  __shared__ alignas(16) ushort_t Ash[2][4096];
  __shared__ alignas(16) ushort_t Bsh[2][4096];
  const int tid = threadIdx.x;
  const int w = tid >> 6, l = tid & 63;
  const int wr = w >> 1, wc = w & 1;
  const int crow = l >> 3;
  const int ksw = ((l & 7) ^ crow) * 8;

  const ushort_t* Ap[2];
  const ushort_t* Bp[2];
  int loff[2];
#pragma unroll
  for (int c = 0; c < 2; ++c) {
    int chunk = w * 2 + c;
    Ap[c] = wbT + (size_t)(kt * 64 + chunk * 8 + crow) * 4096 + b * 512 + ms * 64 + ksw;
    Bp[c] = YcT + (size_t)(dt * 64 + chunk * 8 + crow) * 4096 + b * 512 + ms * 64 + ksw;
    loff[c] = chunk * 512;
  }

  f32x4 acc[2][2];
#pragma unroll
  for (int i = 0; i < 2; ++i)
#pragma unroll
    for (int j = 0; j < 2; ++j) acc[i][j] = (f32x4){0.f, 0.f, 0.f, 0.f};

  const int sw = l & 7, qq = l >> 4;

#define STAGE6(buf, g)                                                       \
  {                                                                          \
    size_t offA = (size_t)(g)*524288;                                        \
    size_t offB = (size_t)(g)*1048576;                                       \
    gload_lds16(Ap[0] + offA, &Ash[buf][loff[0]]);                           \
    gload_lds16(Ap[1] + offA, &Ash[buf][loff[1]]);                           \
    gload_lds16(Bp[0] + offB, &Bsh[buf][loff[0]]);                           \
    gload_lds16(Bp[1] + offB, &Bsh[buf][loff[1]]);                           \
  }
#define COMPUTE6(buf)                                                                    \
  {                                                                                      \
    s16x8 af[2][2], bf[2][2];                                                            \
    _Pragma("unroll") for (int kk = 0; kk < 2; ++kk) {                                   \
      int slot = (((kk << 2) + qq) ^ sw) * 8;                                            \
      _Pragma("unroll") for (int mi = 0; mi < 2; ++mi) {                                 \
        af[mi][kk] = *(const s16x8*)&Ash[buf][(wr * 32 + mi * 16 + (l & 15)) * 64 +      \
                                             slot];                                     \
        bf[mi][kk] = *(const s16x8*)&Bsh[buf][(wc * 32 + mi * 16 + (l & 15)) * 64 +      \
                                             slot];                                     \
      }                                                                                  \
    }                                                                                    \
    _Pragma("unroll") for (int kk = 0; kk < 2; ++kk)                                     \
        _Pragma("unroll") for (int mi = 0; mi < 2; ++mi)                                 \
            _Pragma("unroll") for (int ni = 0; ni < 2; ++ni)                             \
                acc[mi][ni] = __builtin_amdgcn_mfma_f32_16x16x32_bf16(af[mi][kk],        \
                                                                     bf[ni][kk],        \
                                                                     acc[mi][ni], 0, 0, 0); \
  }

  STAGE6(0, 0);
  int buf = 0;
  for (int s = 0; s < 7; ++s) {
    STAGE6(buf ^ 1, s + 1);
    asm volatile("s_waitcnt vmcnt(4)" ::: "memory");
    __builtin_amdgcn_s_barrier();
    asm volatile("" ::: "memory");
    COMPUTE6(buf);
    asm volatile("" ::: "memory");
    __builtin_amdgcn_s_barrier();
    buf ^= 1;
  }
  asm volatile("s_waitcnt vmcnt(0)" ::: "memory");
  __builtin_amdgcn_s_barrier();
  asm volatile("" ::: "memory");
  COMPUTE6(buf);
#undef STAGE6
#undef COMPUTE6

#pragma unroll
  for (int mi = 0; mi < 2; ++mi) {
    int row = kt * 64 + wr * 32 + mi * 16 + (l >> 4) * 4;
#pragma unroll
    for (int ni = 0; ni < 2; ++ni) {
      int col = dt * 64 + wc * 32 + ni * 16 + (l & 15);
#pragma unroll
      for (int r = 0; r < 4; ++r)
        vpart[((size_t)(ms * 8 + b) * 128 + row + r) * 256 + col] = acc[mi][ni][r];
    }
  }
}

// ---------------- K7: combine 8 partials + bias-part - S*centroid, intra-normalize ----------------
__global__ void k7_intranorm(const float* __restrict__ vpart, const float* __restrict__ colsumW,
                             const float* __restrict__ b_inp, const float* __restrict__ cent,
                             float* __restrict__ out, float* __restrict__ ss1) {
  int k = blockIdx.x;
  int b = blockIdx.y;
  int d = threadIdx.x;
  float S = 0.f, bp = 0.f;
#pragma unroll
  for (int g = 0; g < 8; ++g) {
    float cw = colsumW[b * 1024 + g * 128 + k];
    S += cw;
    bp = fmaf(b_inp[g * 256 + d], cw, bp);
  }
  size_t off = ((size_t)b * 128 + k) * 256 + d;
  float v = bp - S * cent[(size_t)k * 256 + d];
#pragma unroll
  for (int i = 0; i < 8; ++i) v += vpart[off + (size_t)i * 262144];
  float ss = v * v;
#pragma unroll
  for (int m = 1; m < 64; m <<= 1) ss += __shfl_xor(ss, m, 64);
  __shared__ float red[4];
  int lane = d & 63, wv = d >> 6;
  if (lane == 0) red[wv] = ss;
  __syncthreads();
  float tot = red[0] + red[1] + red[2] + red[3];
  float rinv = 1.0f / fmaxf(sqrtf(tot), EPSN);
  out[off] = v * rinv;
  if (d == 0) ss1[b * 128 + k] = tot * rinv * rinv;
}

// ---------------- K8: final global L2 norm ----------------
__global__ void k8_finalnorm(const float* __restrict__ ss1, float* __restrict__ out) {
  int b = blockIdx.x;
  int t = threadIdx.x;
  __shared__ float red[256];
  red[t] = (t < 128) ? ss1[b * 128 + t] : 0.f;
  __syncthreads();
  for (int o = 128; o > 0; o >>= 1) {
    if (t < o) red[t] += red[t + o];
    __syncthreads();
  }
  float rinv = 1.0f / fmaxf(sqrtf(red[0]), EPSN);
  float* op = out + (size_t)b * 32768;
  for (int i = t; i < 32768; i += 256) op[i] *= rinv;
}

extern "C" void kernel_launch(void* const* d_in, const int* in_sizes, int n_in,
                              void* d_out, int out_size, void* d_ws, size_t ws_size,
                              hipStream_t stream) {
  const float* x     = (const float*)d_in[0];
  const float* W_inp = (const float*)d_in[1];
  const float* b_inp = (const float*)d_in[2];
  const float* W_g   = (const float*)d_in[3];
  const float* b_g   = (const float*)d_in[4];
  const float* W_gk  = (const float*)d_in[5];
  // b_gk (d_in[6]) cancels in the token-axis softmax — unused.
  const float* cent  = (const float*)d_in[7];
  float* out = (float*)d_out;
  float* ws = (float*)d_ws;

  // workspace layout (float offsets), total 12,887,104 floats = 51.5 MB
  float* ssq8    = ws + 0;         // 32768
  float* colsumW = ws + 32768;     // 8192
  float* ss1     = ws + 40960;     // 1024
  float* bWg     = ws + 41984;     // 64
  ushort_t* xnb  = (ushort_t*)(ws + 42048);        // [4096][1024] bf16 (2097152 fl)
  ushort_t* wbT  = xnb;                            // alias (xnb dead after gemm256)
  ushort_t* stackedA = (ushort_t*)(ws + 2139200);  // [3328][1024] bf16 (1703936 fl)
  ushort_t* WibT = (ushort_t*)(ws + 3843136);      // [1024][2048] bf16 (1048576 fl)
  ushort_t* Wgkx = (ushort_t*)(ws + 4891712);      // [1152][2048] bf16 (1179648 fl)
  float* vpart   = ws + 3843136;   // 2097152 fl, aliases WibT+Wgkx (dead after gemm0)
  float* Wc4     = ws + 6071360;   // [4][1152][1024] f32 (4718592 fl), dead after kpackC
  ushort_t* Cstacked = (ushort_t*)(ws + 6071360);  // [3328][4096] bf16 (6815744 fl), over Wc4
  ushort_t* YcT      = Cstacked;                   // rows 0-2047
  ushort_t* logitsTb = Cstacked + (size_t)2048 * 4096;  // rows 2048-3199

  // fused prep: weights pack + WibT + bWg + k0 ssq partials
  kpack2<<<5512, 256, 0, stream>>>(W_inp, W_gk, W_g, b_inp, b_g,
                                   (__hip_bfloat16*)stackedA, (__hip_bfloat16*)Wgkx, WibT, bWg,
                                   x, ssq8);
  // fused: gemm0 split-K x4 (blocks 0-287) || k1 transpose (blocks 288-799)
  g0k1<<<800, 512, 0, stream>>>(Wgkx, WibT, Wc4, x, ssq8, (__hip_bfloat16*)xnb);
  // pack: stackedA rows 2048-3199 = bf16(sum_s Wc4[s])
  kpackC<<<1152, 256, 0, stream>>>(Wc4, stackedA + (size_t)2048 * 1024);
  // big stacked GEMM (256^2 tiles, 8-phase, A-reuse, coalesced C): Cstacked = stackedA @ xnb^T
  gemm256_8ph<<<dim3(16, 13), 512, 0, stream>>>(stackedA, xnb, Cstacked, 1024, 4096);
  k5_softmax<<<2048, 256, 0, stream>>>(logitsTb, bWg, colsumW, wbT);
  k6_vlad_mfma<<<dim3(8, 8, 8), 256, 0, stream>>>(wbT, YcT, vpart);
  k7_intranorm<<<dim3(128, 8), 256, 0, stream>>>(vpart, colsumW, b_inp, cent, out, ss1);
  k8_finalnorm<<<8, 256, 0, stream>>>(ss1, out);
}

// Round 15
// 111.617 us; speedup vs baseline: 1.1014x; 1.0320x over previous
//
#include <hip/hip_runtime.h>
#include <hip/hip_bf16.h>
#include <math.h>

#define EPSN 1e-12f
typedef unsigned short ushort_t;

typedef float f32x4 __attribute__((ext_vector_type(4)));
typedef short s16x8 __attribute__((ext_vector_type(8)));
typedef unsigned short u16x8 __attribute__((ext_vector_type(8)));
typedef unsigned short u16x4 __attribute__((ext_vector_type(4)));

__device__ __forceinline__ void gload_lds16(const void* g, void* l) {
  __builtin_amdgcn_global_load_lds((const __attribute__((address_space(1))) void*)g,
                                   (__attribute__((address_space(3))) void*)l, 16, 0, 0);
}

__device__ __forceinline__ float bf2f(ushort_t u) {
  return __uint_as_float(((unsigned)u) << 16);
}

// ---------------- kpack2: Wgkx pack + gate/zero rows + bWg + {Wib row-major AND WibT}
//                  dual-write + stackedA pad + k0 ssq partials ----------------
__global__ void kpack2(const float* __restrict__ Wi, const float* __restrict__ Wgk,
                       const float* __restrict__ W_g, const float* __restrict__ b_inp,
                       const float* __restrict__ b_g, __hip_bfloat16* __restrict__ oWi,
                       __hip_bfloat16* __restrict__ oWx, ushort_t* __restrict__ oWibT,
                       float* __restrict__ bWg, const float* __restrict__ x,
                       float* __restrict__ ssq8) {
  int bid = blockIdx.x;
  int t = threadIdx.x;
  if (bid < 2048) {
    int i = (bid * 256 + t) * 4;
    float4 v = *(const float4*)(Wgk + i);
    oWx[i + 0] = __float2bfloat16(v.x);
    oWx[i + 1] = __float2bfloat16(v.y);
    oWx[i + 2] = __float2bfloat16(v.z);
    oWx[i + 3] = __float2bfloat16(v.w);
  } else if (bid < 2064) {
    int i = (bid - 2048) * 1024 + t * 4;  // 16 blocks: 8 gate rows
    float4 v = *(const float4*)(W_g + i);
    __hip_bfloat16* o = oWx + 1024 * 2048 + i;
    o[0] = __float2bfloat16(v.x);
    o[1] = __float2bfloat16(v.y);
    o[2] = __float2bfloat16(v.z);
    o[3] = __float2bfloat16(v.w);
  } else if (bid < 2304) {
    int i = (bid - 2064) * 1024 + t * 4;  // 240 blocks: 120 zero rows of Wgkx
    ushort_t* o = (ushort_t*)(oWx + 1032 * 2048) + i;
    *(u16x4*)o = (u16x4){0, 0, 0, 0};
  } else if (bid < 2312) {
    int j = bid - 2304;  // 0..7
    const float* row = W_g + (size_t)j * 2048;
    float s = 0.f;
    for (int c = t; c < 2048; c += 256) s = fmaf(b_inp[c], row[c], s);
    __shared__ float red[256];
    red[t] = s;
    __syncthreads();
    for (int o = 128; o > 0; o >>= 1) {
      if (t < o) red[t] += red[t + o];
      __syncthreads();
    }
    if (t == 0) bWg[j] = red[0] + b_g[j];
  } else if (bid < 2824) {
    // dual: Wib (row-major bf16) + WibT (transposed); 512 tiles 64x64, W_inp read ONCE
    int tt = bid - 2312;
    int cp0 = (tt >> 4) * 64;  // c' base (W_inp row)
    int c0 = (tt & 15) * 64;   // c base  (W_inp col)
    __shared__ ushort_t tile[64][72];
    int r = t >> 2, cs = (t & 3) * 16;
    const float* src = Wi + (size_t)(cp0 + r) * 1024 + c0 + cs;
#pragma unroll
    for (int j = 0; j < 16; j += 4) {
      float4 v = *(const float4*)(src + j);
      __hip_bfloat16 h0 = __float2bfloat16(v.x), h1 = __float2bfloat16(v.y);
      __hip_bfloat16 h2 = __float2bfloat16(v.z), h3 = __float2bfloat16(v.w);
      tile[r][cs + j + 0] = *(ushort_t*)&h0;
      tile[r][cs + j + 1] = *(ushort_t*)&h1;
      tile[r][cs + j + 2] = *(ushort_t*)&h2;
      tile[r][cs + j + 3] = *(ushort_t*)&h3;
    }
    // row-major write (own LDS writes, same thread)
    {
      u16x8 w0 = *(const u16x8*)&tile[r][cs];
      u16x8 w1 = *(const u16x8*)&tile[r][cs + 8];
      ushort_t* dst = (ushort_t*)oWi + (size_t)(cp0 + r) * 1024 + c0 + cs;
      *(u16x8*)dst = w0;
      *(u16x8*)(dst + 8) = w1;
    }
    __syncthreads();
    int c = t >> 2, ms = (t & 3) * 16;
    u16x8 o0, o1;
#pragma unroll
    for (int j = 0; j < 8; ++j) o0[j] = tile[ms + j][c];
#pragma unroll
    for (int j = 0; j < 8; ++j) o1[j] = tile[ms + 8 + j][c];
    ushort_t* dst = oWibT + (size_t)(c0 + c) * 2048 + cp0 + ms;
    *(u16x8*)dst = o0;
    *(u16x8*)(dst + 8) = o1;
  } else if (bid < 2952) {
    // zero pad rows 3200-3327 of stackedA
    int i = (bid - 2824) * 1024 + t * 4;
    ushort_t* o = (ushort_t*)oWi + (size_t)3200 * 1024 + i;
    *(u16x4*)o = (u16x4){0, 0, 0, 0};
  } else {
    // fused k0: per-token sum of squares partials (512 blocks)
    int kb = bid - 2952;
    int b8 = kb >> 3;
    int cc = kb & 7;
    int s4 = (t & 15) * 4;
    int cg = t >> 4;
    const float* xp = x + (size_t)b8 * 65536 + (size_t)cc * 128 * 64;
    float4 a = {0.f, 0.f, 0.f, 0.f};
#pragma unroll
    for (int j = 0; j < 8; ++j) {
      int c = cg + j * 16;
      float4 v = *(const float4*)(xp + (size_t)c * 64 + s4);
      a.x = fmaf(v.x, v.x, a.x);
      a.y = fmaf(v.y, v.y, a.y);
      a.z = fmaf(v.z, v.z, a.z);
      a.w = fmaf(v.w, v.w, a.w);
    }
    __shared__ float red0[16][68];
    *(float4*)&red0[cg][s4] = a;
    __syncthreads();
    if (t < 64) {
      float s = 0.f;
#pragma unroll
      for (int g = 0; g < 16; ++g) s += red0[g][t];
      ssq8[cc * 4096 + b8 * 64 + t] = s;
    }
  }
}

// ---------------- fused: GEMM0 split-K (blocks 0-287, bf16 partials) + k1 (288-799) ----
__launch_bounds__(512, 4)
__global__ void g0k1(const ushort_t* __restrict__ A, const ushort_t* __restrict__ B,
                     ushort_t* __restrict__ Cb, const float* __restrict__ x,
                     const float* __restrict__ ssq8, __hip_bfloat16* __restrict__ xnb) {
  __shared__ alignas(16) unsigned char SHRAW[65536];
  const int bid = blockIdx.x;
  const int tid = threadIdx.x;
  if (bid >= 288) {
    int ht = tid >> 8, t = tid & 255;
    int tile_id = (bid - 288) * 2 + ht;
    int ct = tile_id & 15, b8 = tile_id >> 4;
    float* tbuf = (float*)(SHRAW + ht * 20480);  // [64][65]
    float* ivs = tbuf + 64 * 65;
    if (t < 64) {
      float s = 0.f;
#pragma unroll
      for (int cc = 0; cc < 8; ++cc) s += ssq8[cc * 4096 + b8 * 64 + t];
      ivs[t] = rsqrtf(fmaxf(s, 1e-24f));
    }
    int s = t & 63, cq = t >> 6;
    const float* xp = x + (size_t)b8 * 65536 + (size_t)ct * 64 * 64;
#pragma unroll
    for (int r = 0; r < 16; ++r) {
      int cl = cq * 16 + r;
      tbuf[cl * 65 + s] = xp[cl * 64 + s];
    }
    __syncthreads();
    int cl = t & 63, sq = t >> 6;
#pragma unroll
    for (int r = 0; r < 16; ++r) {
      int smm = sq * 16 + r;
      int tm = b8 * 64 + smm;
      xnb[(size_t)tm * 1024 + ct * 64 + cl] = __float2bfloat16(tbuf[cl * 65 + smm] * ivs[smm]);
    }
    return;
  }
  ushort_t* SH = (ushort_t*)SHRAW;
  const int Kstride = 2048, N = 1024;
  const int nx = bid & 7, ny = (bid >> 3) % 9, sK = bid / 72;
  const int m0 = ny * 128, n0 = nx * 128;
  const int koff = sK * 512;
  const int w = tid >> 6, l = tid & 63;
  const int wr = w >> 2, wc = w & 3;
  const int srow = w * 8 + (l >> 3);
  const int ksw = ((l & 7) ^ (l >> 3)) * 8;
  const ushort_t* Ag0 = A + (size_t)(m0 + srow) * Kstride + ksw + koff;
  const ushort_t* Ag1 = A + (size_t)(m0 + 64 + srow) * Kstride + ksw + koff;
  const ushort_t* Bg0 = B + (size_t)(n0 + srow) * Kstride + ksw + koff;
  const ushort_t* Bg1 = B + (size_t)(n0 + 64 + srow) * Kstride + ksw + koff;
  const int l0 = w * 512;
  const int l1 = 4096 + w * 512;

  f32x4 acc[4][2];
#pragma unroll
  for (int i = 0; i < 4; ++i)
#pragma unroll
    for (int j = 0; j < 2; ++j) acc[i][j] = (f32x4){0.f, 0.f, 0.f, 0.f};

  const int sw = l & 7, qq = l >> 4;

#define ASH(buf) (SH + (buf)*8192)
#define BSH(buf) (SH + 16384 + (buf)*8192)
#define STAGE(buf, k0)                               \
  {                                                  \
    gload_lds16(Ag0 + (k0), ASH(buf) + l0);          \
    gload_lds16(Ag1 + (k0), ASH(buf) + l1);          \
    gload_lds16(Bg0 + (k0), BSH(buf) + l0);          \
    gload_lds16(Bg1 + (k0), BSH(buf) + l1);          \
  }
#define COMPUTE(buf)                                                                     \
  {                                                                                      \
    s16x8 af[4][2], bf[2][2];                                                            \
    _Pragma("unroll") for (int kk = 0; kk < 2; ++kk) {                                   \
      int slot = (((kk << 2) + qq) ^ sw) * 8;                                            \
      _Pragma("unroll") for (int mi = 0; mi < 4; ++mi)                                   \
          af[mi][kk] = *(const s16x8*)&ASH(buf)[(wr * 64 + mi * 16 + (l & 15)) * 64 +    \
                                               slot];                                   \
      _Pragma("unroll") for (int ni = 0; ni < 2; ++ni)                                   \
          bf[ni][kk] = *(const s16x8*)&BSH(buf)[(wc * 32 + ni * 16 + (l & 15)) * 64 +    \
                                               slot];                                   \
    }                                                                                    \
    _Pragma("unroll") for (int kk = 0; kk < 2; ++kk)                                     \
        _Pragma("unroll") for (int mi = 0; mi < 4; ++mi)                                 \
            _Pragma("unroll") for (int ni = 0; ni < 2; ++ni)                             \
                acc[mi][ni] = __builtin_amdgcn_mfma_f32_16x16x32_bf16(af[mi][kk],        \
                                                                     bf[ni][kk],        \
                                                                     acc[mi][ni], 0, 0, 0); \
  }

  STAGE(0, 0);
  int buf = 0;
  for (int t2 = 0; t2 < 7; ++t2) {
    STAGE(buf ^ 1, (t2 + 1) << 6);
    asm volatile("s_waitcnt vmcnt(4)" ::: "memory");
    __builtin_amdgcn_s_barrier();
    asm volatile("" ::: "memory");
    COMPUTE(buf);
    asm volatile("" ::: "memory");
    __builtin_amdgcn_s_barrier();
    buf ^= 1;
  }
  asm volatile("s_waitcnt vmcnt(0)" ::: "memory");
  __builtin_amdgcn_s_barrier();
  asm volatile("" ::: "memory");
  COMPUTE(buf);
#undef STAGE
#undef COMPUTE
#undef ASH
#undef BSH

  ushort_t* Co = Cb + (size_t)sK * 1152 * 1024;
#pragma unroll
  for (int mi = 0; mi < 4; ++mi) {
    int row = m0 + wr * 64 + mi * 16 + (l >> 4) * 4;
#pragma unroll
    for (int ni = 0; ni < 2; ++ni) {
      int col = n0 + wc * 32 + ni * 16 + (l & 15);
#pragma unroll
      for (int r = 0; r < 4; ++r) {
        __hip_bfloat16 hb = __float2bfloat16(acc[mi][ni][r]);
        Co[(size_t)(row + r) * N + col] = *(ushort_t*)&hb;
      }
    }
  }
}

// ---------------- kpackC: sum 4 bf16 split-K partials -> bf16 stackedA rows 2048+ ----------
__global__ void kpackC(const ushort_t* __restrict__ Wc4b, ushort_t* __restrict__ dst) {
  int i = (blockIdx.x * 256 + threadIdx.x) * 8;
  u16x8 p0 = *(const u16x8*)(Wc4b + i);
  u16x8 p1 = *(const u16x8*)(Wc4b + 1179648 + i);
  u16x8 p2 = *(const u16x8*)(Wc4b + 2359296 + i);
  u16x8 p3 = *(const u16x8*)(Wc4b + 3538944 + i);
  u16x8 o;
#pragma unroll
  for (int j = 0; j < 8; ++j) {
    float s = bf2f(p0[j]) + bf2f(p1[j]) + bf2f(p2[j]) + bf2f(p3[j]);
    __hip_bfloat16 hb = __float2bfloat16(s);
    o[j] = *(ushort_t*)&hb;
  }
  *(u16x8*)(dst + i) = o;
}

// ---------------- big stacked GEMM, 256x256 tile, 8-phase, A-reuse, coalesced epilogue ----
__launch_bounds__(512, 2)
__global__ void gemm256_8ph(const ushort_t* __restrict__ A, const ushort_t* __restrict__ B,
                            ushort_t* __restrict__ C, int K, int N) {
  __shared__ alignas(16) ushort_t SH[65536];  // 128 KB
  const int tid = threadIdx.x;
  const int m0 = blockIdx.y * 256, n0 = blockIdx.x * 256;
  const int w = tid >> 6, l = tid & 63;
  const int wr = w >> 2, wc = w & 3;
  const int r16 = l & 15, qq = l >> 4, sw = l & 7;
  const int s = tid >> 3;
  const int s_hi = s >> 5, s_lo = s & 31;
  const int ksw = ((tid & 7) ^ (s & 7)) * 8;
  const int NT = K >> 6;

  const ushort_t* pA0 = A + (size_t)(m0 + s) * K + ksw;
  const ushort_t* pA1 = A + (size_t)(m0 + 128 + s) * K + ksw;
  const ushort_t* pB0 = B + (size_t)(n0 + s_hi * 64 + s_lo) * K + ksw;
  const ushort_t* pB1 = B + (size_t)(n0 + 128 + s_hi * 64 + s_lo) * K + ksw;
  ushort_t* dA = SH + tid * 8;
  ushort_t* dB = SH + 32768 + tid * 8;

  f32x4 acc[8][4];
#pragma unroll
  for (int i = 0; i < 8; ++i)
#pragma unroll
    for (int j = 0; j < 4; ++j) acc[i][j] = (f32x4){0.f, 0.f, 0.f, 0.f};

#define SA(kt, h)                                                                        \
  {                                                                                      \
    gload_lds16(pA0 + (size_t)(h) * (K << 6) + ((kt) << 6),                              \
                dA + (((kt)&1) << 14) + ((h) << 13));                                    \
    gload_lds16(pA1 + (size_t)(h) * (K << 6) + ((kt) << 6),                              \
                dA + (((kt)&1) << 14) + ((h) << 13) + 4096);                             \
  }
#define SB(kt, h)                                                                        \
  {                                                                                      \
    gload_lds16(pB0 + (size_t)(h) * (K << 5) + ((kt) << 6),                              \
                dB + (((kt)&1) << 14) + ((h) << 13));                                    \
    gload_lds16(pB1 + (size_t)(h) * (K << 5) + ((kt) << 6),                              \
                dB + (((kt)&1) << 14) + ((h) << 13) + 4096);                             \
  }
#define VMC4 asm volatile("s_waitcnt vmcnt(4)" ::: "memory")

#define PHASEPAIR(d, mh, STG1, VM1, STG2, VM2)                                           \
  {                                                                                      \
    s16x8 af[2][4], bf[2][2];                                                            \
    _Pragma("unroll") for (int kk = 0; kk < 2; ++kk) {                                   \
      int slot = (((kk << 2) + qq) ^ sw) * 8;                                            \
      _Pragma("unroll") for (int mi2 = 0; mi2 < 4; ++mi2)                                \
          af[kk][mi2] = *(const s16x8*)&SH[((d) << 14) + ((mh) << 13) +                  \
                                           (wr * 64 + mi2 * 16 + r16) * 64 + slot];      \
      _Pragma("unroll") for (int ni2 = 0; ni2 < 2; ++ni2)                                \
          bf[kk][ni2] = *(const s16x8*)&SH[32768 + ((d) << 14) +                         \
                                           (wc * 32 + ni2 * 16 + r16) * 64 + slot];      \
    }                                                                                    \
    STG1;                                                                                \
    asm volatile("" ::: "memory");                                                       \
    __builtin_amdgcn_s_barrier();                                                        \
    asm volatile("" ::: "memory");                                                       \
    __builtin_amdgcn_s_setprio(1);                                                       \
    _Pragma("unroll") for (int kk = 0; kk < 2; ++kk)                                     \
        _Pragma("unroll") for (int mi2 = 0; mi2 < 4; ++mi2)                              \
            _Pragma("unroll") for (int ni2 = 0; ni2 < 2; ++ni2)                          \
                acc[(mh)*4 + mi2][ni2] = __builtin_amdgcn_mfma_f32_16x16x32_bf16(        \
                    af[kk][mi2], bf[kk][ni2], acc[(mh)*4 + mi2][ni2], 0, 0, 0);          \
    __builtin_amdgcn_s_setprio(0);                                                       \
    VM1;                                                                                 \
    asm volatile("" ::: "memory");                                                       \
    __builtin_amdgcn_s_barrier();                                                        \
    asm volatile("" ::: "memory");                                                       \
    _Pragma("unroll") for (int kk = 0; kk < 2; ++kk) {                                   \
      int slot = (((kk << 2) + qq) ^ sw) * 8;                                            \
      _Pragma("unroll") for (int ni2 = 0; ni2 < 2; ++ni2)                                \
          bf[kk][ni2] = *(const s16x8*)&SH[32768 + ((d) << 14) + 8192 +                  \
                                           (wc * 32 + ni2 * 16 + r16) * 64 + slot];      \
    }                                                                                    \
    STG2;                                                                                \
    asm volatile("" ::: "memory");                                                       \
    __builtin_amdgcn_s_barrier();                                                        \
    asm volatile("" ::: "memory");                                                       \
    __builtin_amdgcn_s_setprio(1);                                                       \
    _Pragma("unroll") for (int kk = 0; kk < 2; ++kk)                                     \
        _Pragma("unroll") for (int mi2 = 0; mi2 < 4; ++mi2)                              \
            _Pragma("unroll") for (int ni2 = 0; ni2 < 2; ++ni2)                          \
                acc[(mh)*4 + mi2][2 + ni2] = __builtin_amdgcn_mfma_f32_16x16x32_bf16(    \
                    af[kk][mi2], bf[kk][ni2], acc[(mh)*4 + mi2][2 + ni2], 0, 0, 0);      \
    __builtin_amdgcn_s_setprio(0);                                                       \
    VM2;                                                                                 \
    asm volatile("" ::: "memory");                                                       \
    __builtin_amdgcn_s_barrier();                                                        \
    asm volatile("" ::: "memory");                                                       \
  }

  SA(0, 0); SB(0, 0); SA(0, 1); SB(0, 1); SA(1, 0); SB(1, 0);
  VMC4;
  __builtin_amdgcn_s_barrier();
  asm volatile("" ::: "memory");

#pragma unroll 1
  for (int I = 0; I < (NT >> 1); ++I) {
    const int kt = 2 * I;
    const int k1 = kt + 1, k2 = kt + 2, k3 = kt + 3;
    PHASEPAIR(0, 0, SA(k1, 1), , SB(k1, 1), );
    PHASEPAIR(0, 1, if (k2 < NT) SA(k2, 0), , if (k2 < NT) SB(k2, 0), VMC4);
    PHASEPAIR(1, 0, if (k2 < NT) SA(k2, 1), , if (k2 < NT) SB(k2, 1), );
    PHASEPAIR(1, 1, if (k3 < NT) SA(k3, 0), , if (k3 < NT) SB(k3, 0), VMC4);
  }
#undef PHASEPAIR
#undef SA
#undef SB
#undef VMC4

  // coalesced epilogue: per-wave LDS bounce, u16x8 stores
  ushort_t* eb = SH + w * 2048;
  const int erow = (l >> 4) * 4;
  const int rrow = l >> 2, rc = (l & 3) * 16;
#pragma unroll
  for (int mi = 0; mi < 8; ++mi) {
    asm volatile("s_waitcnt lgkmcnt(0)" ::: "memory");
#pragma unroll
    for (int ni = 0; ni < 4; ++ni)
#pragma unroll
      for (int r = 0; r < 4; ++r) {
        __hip_bfloat16 hb = __float2bfloat16(acc[mi][ni][r]);
        eb[(erow + r) * 68 + ni * 16 + r16] = *(ushort_t*)&hb;
      }
    asm volatile("s_waitcnt lgkmcnt(0)" ::: "memory");
    u16x8 v0 = *(const u16x8*)&eb[rrow * 68 + rc];
    u16x8 v1 = *(const u16x8*)&eb[rrow * 68 + rc + 8];
    size_t gbase = (size_t)(m0 + wr * 128 + mi * 16 + rrow) * N + n0 + wc * 64 + rc;
    *(u16x8*)&C[gbase] = v0;
    *(u16x8*)&C[gbase + 8] = v1;
  }
}

// ---------------- K5: row softmax over tokens + gate sigmoid, one wave per (q,b) ----------------
__launch_bounds__(256)
__global__ void k5_softmax(const ushort_t* __restrict__ logitsTb, const float* __restrict__ bWg,
                           float* __restrict__ colsumW, ushort_t* __restrict__ wbT) {
  int wv = (blockIdx.x << 2) + (threadIdx.x >> 6);
  int q = wv >> 3, b = wv & 7;
  int l = threadIdx.x & 63;
  int g = q >> 7;
  size_t base = (size_t)q * 4096 + b * 512 + l * 8;
  u16x8 v8 = *(const u16x8*)(logitsTb + base);
  float vs[8];
#pragma unroll
  for (int i = 0; i < 8; ++i) vs[i] = bf2f(v8[i]);
  float M = vs[0];
#pragma unroll
  for (int i = 1; i < 8; ++i) M = fmaxf(M, vs[i]);
#pragma unroll
  for (int m = 1; m < 64; m <<= 1) M = fmaxf(M, __shfl_xor(M, m, 64));
  float e[8], S = 0.f;
#pragma unroll
  for (int i = 0; i < 8; ++i) {
    e[i] = expf(vs[i] - M);
    S += e[i];
  }
#pragma unroll
  for (int m = 1; m < 64; m <<= 1) S += __shfl_xor(S, m, 64);
  float R = 1.0f / S;
  u16x8 g8 = *(const u16x8*)(logitsTb + (size_t)(1024 + g) * 4096 + b * 512 + l * 8);
  float bg = bWg[g];
  float wv8[8], wsum = 0.f;
#pragma unroll
  for (int i = 0; i < 8; ++i) {
    float gl = bf2f(g8[i]);
    float ag = 1.0f / (1.0f + expf(-(gl + bg)));
    wv8[i] = e[i] * R * ag;
    wsum += wv8[i];
  }
#pragma unroll
  for (int m = 1; m < 64; m <<= 1) wsum += __shfl_xor(wsum, m, 64);
  if (l == 0) colsumW[b * 1024 + q] = wsum;
  u16x8 o;
#pragma unroll
  for (int i = 0; i < 8; ++i) {
    __hip_bfloat16 hb = __float2bfloat16(wv8[i]);
    o[i] = *(ushort_t*)&hb;
  }
  *(u16x8*)(wbT + base) = o;
}

// ---------------- K6: VLAD einsum via MFMA, 64x64 tile, m-split 8, counted vmcnt ----------------
__launch_bounds__(256)
__global__ void k6_vlad_mfma(const ushort_t* __restrict__ wbT, const ushort_t* __restrict__ YcT,
                             float* __restrict__ vpart) {
  int kt = blockIdx.x >> 2, dt = blockIdx.x & 3;
  int ms = blockIdx.y, b = blockIdx.z;
  __shared__ alignas(16) ushort_t Ash[2][4096];
  __shared__ alignas(16) ushort_t Bsh[2][4096];
  const int tid = threadIdx.x;
  const int w = tid >> 6, l = tid & 63;
  const int wr = w >> 1, wc = w & 1;
  const int crow = l >> 3;
  const int ksw = ((l & 7) ^ crow) * 8;

  const ushort_t* Ap[2];
  const ushort_t* Bp[2];
  int loff[2];
#pragma unroll
  for (int c = 0; c < 2; ++c) {
    int chunk = w * 2 + c;
    Ap[c] = wbT + (size_t)(kt * 64 + chunk * 8 + crow) * 4096 + b * 512 + ms * 64 + ksw;
    Bp[c] = YcT + (size_t)(dt * 64 + chunk * 8 + crow) * 4096 + b * 512 + ms * 64 + ksw;
    loff[c] = chunk * 512;
  }

  f32x4 acc[2][2];
#pragma unroll
  for (int i = 0; i < 2; ++i)
#pragma unroll
    for (int j = 0; j < 2; ++j) acc[i][j] = (f32x4){0.f, 0.f, 0.f, 0.f};

  const int sw = l & 7, qq = l >> 4;

#define STAGE6(buf, g)                                                       \
  {                                                                          \
    size_t offA = (size_t)(g)*524288;                                        \
    size_t offB = (size_t)(g)*1048576;                                       \
    gload_lds16(Ap[0] + offA, &Ash[buf][loff[0]]);                           \
    gload_lds16(Ap[1] + offA, &Ash[buf][loff[1]]);                           \
    gload_lds16(Bp[0] + offB, &Bsh[buf][loff[0]]);                           \
    gload_lds16(Bp[1] + offB, &Bsh[buf][loff[1]]);                           \
  }
#define COMPUTE6(buf)                                                                    \
  {                                                                                      \
    s16x8 af[2][2], bf[2][2];                                                            \
    _Pragma("unroll") for (int kk = 0; kk < 2; ++kk) {                                   \
      int slot = (((kk << 2) + qq) ^ sw) * 8;                                            \
      _Pragma("unroll") for (int mi = 0; mi < 2; ++mi) {                                 \
        af[mi][kk] = *(const s16x8*)&Ash[buf][(wr * 32 + mi * 16 + (l & 15)) * 64 +      \
                                             slot];                                     \
        bf[mi][kk] = *(const s16x8*)&Bsh[buf][(wc * 32 + mi * 16 + (l & 15)) * 64 +      \
                                             slot];                                     \
      }                                                                                  \
    }                                                                                    \
    _Pragma("unroll") for (int kk = 0; kk < 2; ++kk)                                     \
        _Pragma("unroll") for (int mi = 0; mi < 2; ++mi)                                 \
            _Pragma("unroll") for (int ni = 0; ni < 2; ++ni)                             \
                acc[mi][ni] = __builtin_amdgcn_mfma_f32_16x16x32_bf16(af[mi][kk],        \
                                                                     bf[ni][kk],        \
                                                                     acc[mi][ni], 0, 0, 0); \
  }

  STAGE6(0, 0);
  int buf = 0;
  for (int s = 0; s < 7; ++s) {
    STAGE6(buf ^ 1, s + 1);
    asm volatile("s_waitcnt vmcnt(4)" ::: "memory");
    __builtin_amdgcn_s_barrier();
    asm volatile("" ::: "memory");
    COMPUTE6(buf);
    asm volatile("" ::: "memory");
    __builtin_amdgcn_s_barrier();
    buf ^= 1;
  }
  asm volatile("s_waitcnt vmcnt(0)" ::: "memory");
  __builtin_amdgcn_s_barrier();
  asm volatile("" ::: "memory");
  COMPUTE6(buf);
#undef STAGE6
#undef COMPUTE6

#pragma unroll
  for (int mi = 0; mi < 2; ++mi) {
    int row = kt * 64 + wr * 32 + mi * 16 + (l >> 4) * 4;
#pragma unroll
    for (int ni = 0; ni < 2; ++ni) {
      int col = dt * 64 + wc * 32 + ni * 16 + (l & 15);
#pragma unroll
      for (int r = 0; r < 4; ++r)
        vpart[((size_t)(ms * 8 + b) * 128 + row + r) * 256 + col] = acc[mi][ni][r];
    }
  }
}

// ---------------- K7: combine 8 partials + bias-part - S*centroid, intra-normalize ----------------
__global__ void k7_intranorm(const float* __restrict__ vpart, const float* __restrict__ colsumW,
                             const float* __restrict__ b_inp, const float* __restrict__ cent,
                             float* __restrict__ out, float* __restrict__ ss1) {
  int k = blockIdx.x;
  int b = blockIdx.y;
  int d = threadIdx.x;
  float S = 0.f, bp = 0.f;
#pragma unroll
  for (int g = 0; g < 8; ++g) {
    float cw = colsumW[b * 1024 + g * 128 + k];
    S += cw;
    bp = fmaf(b_inp[g * 256 + d], cw, bp);
  }
  size_t off = ((size_t)b * 128 + k) * 256 + d;
  float v = bp - S * cent[(size_t)k * 256 + d];
#pragma unroll
  for (int i = 0; i < 8; ++i) v += vpart[off + (size_t)i * 262144];
  float ss = v * v;
#pragma unroll
  for (int m = 1; m < 64; m <<= 1) ss += __shfl_xor(ss, m, 64);
  __shared__ float red[4];
  int lane = d & 63, wv = d >> 6;
  if (lane == 0) red[wv] = ss;
  __syncthreads();
  float tot = red[0] + red[1] + red[2] + red[3];
  float rinv = 1.0f / fmaxf(sqrtf(tot), EPSN);
  out[off] = v * rinv;
  if (d == 0) ss1[b * 128 + k] = tot * rinv * rinv;
}

// ---------------- K8: final global L2 norm ----------------
__global__ void k8_finalnorm(const float* __restrict__ ss1, float* __restrict__ out) {
  int b = blockIdx.x;
  int t = threadIdx.x;
  __shared__ float red[256];
  red[t] = (t < 128) ? ss1[b * 128 + t] : 0.f;
  __syncthreads();
  for (int o = 128; o > 0; o >>= 1) {
    if (t < o) red[t] += red[t + o];
    __syncthreads();
  }
  float rinv = 1.0f / fmaxf(sqrtf(red[0]), EPSN);
  float* op = out + (size_t)b * 32768;
  for (int i = t; i < 32768; i += 256) op[i] *= rinv;
}

extern "C" void kernel_launch(void* const* d_in, const int* in_sizes, int n_in,
                              void* d_out, int out_size, void* d_ws, size_t ws_size,
                              hipStream_t stream) {
  const float* x     = (const float*)d_in[0];
  const float* W_inp = (const float*)d_in[1];
  const float* b_inp = (const float*)d_in[2];
  const float* W_g   = (const float*)d_in[3];
  const float* b_g   = (const float*)d_in[4];
  const float* W_gk  = (const float*)d_in[5];
  // b_gk (d_in[6]) cancels in the token-axis softmax — unused.
  const float* cent  = (const float*)d_in[7];
  float* out = (float*)d_out;
  float* ws = (float*)d_ws;

  // workspace layout (float offsets), total 12,887,104 floats = 51.5 MB
  float* ssq8    = ws + 0;         // 32768
  float* colsumW = ws + 32768;     // 8192
  float* ss1     = ws + 40960;     // 1024
  float* bWg     = ws + 41984;     // 64
  ushort_t* xnb  = (ushort_t*)(ws + 42048);        // [4096][1024] bf16 (2097152 fl)
  ushort_t* wbT  = xnb;                            // alias (xnb dead after gemm256)
  ushort_t* stackedA = (ushort_t*)(ws + 2139200);  // [3328][1024] bf16 (1703936 fl)
  ushort_t* WibT = (ushort_t*)(ws + 3843136);      // [1024][2048] bf16 (1048576 fl)
  ushort_t* Wgkx = (ushort_t*)(ws + 4891712);      // [1152][2048] bf16 (1179648 fl)
  float* vpart   = ws + 3843136;   // 2097152 fl, aliases WibT+Wgkx (dead after gemm0)
  ushort_t* Wc4b = (ushort_t*)(ws + 6071360);      // [4][1152][1024] bf16, dead after kpackC
  ushort_t* Cstacked = (ushort_t*)(ws + 6071360);  // [3328][4096] bf16 (6815744 fl), over Wc4b
  ushort_t* YcT      = Cstacked;                   // rows 0-2047
  ushort_t* logitsTb = Cstacked + (size_t)2048 * 4096;  // rows 2048-3199

  // fused prep: Wgkx pack + gate + bWg + Wib/WibT dual + pad + k0 ssq partials
  kpack2<<<3464, 256, 0, stream>>>(W_inp, W_gk, W_g, b_inp, b_g,
                                   (__hip_bfloat16*)stackedA, (__hip_bfloat16*)Wgkx, WibT, bWg,
                                   x, ssq8);
  // fused: gemm0 split-K x4 (bf16 partials, blocks 0-287) || k1 transpose (288-799)
  g0k1<<<800, 512, 0, stream>>>(Wgkx, WibT, Wc4b, x, ssq8, (__hip_bfloat16*)xnb);
  // pack: stackedA rows 2048-3199 = bf16(sum_s Wc4b[s])
  kpackC<<<576, 256, 0, stream>>>(Wc4b, stackedA + (size_t)2048 * 1024);
  // big stacked GEMM (256^2, 8-phase, A-reuse, coalesced C): Cstacked = stackedA @ xnb^T
  gemm256_8ph<<<dim3(16, 13), 512, 0, stream>>>(stackedA, xnb, Cstacked, 1024, 4096);
  k5_softmax<<<2048, 256, 0, stream>>>(logitsTb, bWg, colsumW, wbT);
  k6_vlad_mfma<<<dim3(8, 8, 8), 256, 0, stream>>>(wbT, YcT, vpart);
  k7_intranorm<<<dim3(128, 8), 256, 0, stream>>>(vpart, colsumW, b_inp, cent, out, ss1);
  k8_finalnorm<<<8, 256, 0, stream>>>(ss1, out);
}

// Round 16
// 110.737 us; speedup vs baseline: 1.1102x; 1.0080x over previous
//
#include <hip/hip_runtime.h>
#include <hip/hip_bf16.h>
#include <math.h>

#define EPSN 1e-12f
typedef unsigned short ushort_t;

typedef float f32x4 __attribute__((ext_vector_type(4)));
typedef short s16x8 __attribute__((ext_vector_type(8)));
typedef unsigned short u16x8 __attribute__((ext_vector_type(8)));
typedef unsigned short u16x4 __attribute__((ext_vector_type(4)));

__device__ __forceinline__ void gload_lds16(const void* g, void* l) {
  __builtin_amdgcn_global_load_lds((const __attribute__((address_space(1))) void*)g,
                                   (__attribute__((address_space(3))) void*)l, 16, 0, 0);
}

__device__ __forceinline__ float bf2f(ushort_t u) {
  return __uint_as_float(((unsigned)u) << 16);
}

// ---------------- kpack2: Wgkx pack + gate/zero rows + bWg + {Wib row-major AND WibT}
//                  dual-write + stackedA pad + k0 ssq partials ----------------
__global__ void kpack2(const float* __restrict__ Wi, const float* __restrict__ Wgk,
                       const float* __restrict__ W_g, const float* __restrict__ b_inp,
                       const float* __restrict__ b_g, __hip_bfloat16* __restrict__ oWi,
                       __hip_bfloat16* __restrict__ oWx, ushort_t* __restrict__ oWibT,
                       float* __restrict__ bWg, const float* __restrict__ x,
                       float* __restrict__ ssq8) {
  int bid = blockIdx.x;
  int t = threadIdx.x;
  if (bid < 2048) {
    int i = (bid * 256 + t) * 4;
    float4 v = *(const float4*)(Wgk + i);
    oWx[i + 0] = __float2bfloat16(v.x);
    oWx[i + 1] = __float2bfloat16(v.y);
    oWx[i + 2] = __float2bfloat16(v.z);
    oWx[i + 3] = __float2bfloat16(v.w);
  } else if (bid < 2064) {
    int i = (bid - 2048) * 1024 + t * 4;  // 16 blocks: 8 gate rows
    float4 v = *(const float4*)(W_g + i);
    __hip_bfloat16* o = oWx + 1024 * 2048 + i;
    o[0] = __float2bfloat16(v.x);
    o[1] = __float2bfloat16(v.y);
    o[2] = __float2bfloat16(v.z);
    o[3] = __float2bfloat16(v.w);
  } else if (bid < 2304) {
    int i = (bid - 2064) * 1024 + t * 4;  // 240 blocks: 120 zero rows of Wgkx
    ushort_t* o = (ushort_t*)(oWx + 1032 * 2048) + i;
    *(u16x4*)o = (u16x4){0, 0, 0, 0};
  } else if (bid < 2312) {
    int j = bid - 2304;  // 0..7
    const float* row = W_g + (size_t)j * 2048;
    float s = 0.f;
    for (int c = t; c < 2048; c += 256) s = fmaf(b_inp[c], row[c], s);
    __shared__ float red[256];
    red[t] = s;
    __syncthreads();
    for (int o = 128; o > 0; o >>= 1) {
      if (t < o) red[t] += red[t + o];
      __syncthreads();
    }
    if (t == 0) bWg[j] = red[0] + b_g[j];
  } else if (bid < 2824) {
    // dual: Wib (row-major bf16) + WibT (transposed); 512 tiles 64x64, W_inp read ONCE
    int tt = bid - 2312;
    int cp0 = (tt >> 4) * 64;  // c' base (W_inp row)
    int c0 = (tt & 15) * 64;   // c base  (W_inp col)
    __shared__ ushort_t tile[64][72];
    int r = t >> 2, cs = (t & 3) * 16;
    const float* src = Wi + (size_t)(cp0 + r) * 1024 + c0 + cs;
#pragma unroll
    for (int j = 0; j < 16; j += 4) {
      float4 v = *(const float4*)(src + j);
      __hip_bfloat16 h0 = __float2bfloat16(v.x), h1 = __float2bfloat16(v.y);
      __hip_bfloat16 h2 = __float2bfloat16(v.z), h3 = __float2bfloat16(v.w);
      tile[r][cs + j + 0] = *(ushort_t*)&h0;
      tile[r][cs + j + 1] = *(ushort_t*)&h1;
      tile[r][cs + j + 2] = *(ushort_t*)&h2;
      tile[r][cs + j + 3] = *(ushort_t*)&h3;
    }
    {
      u16x8 w0 = *(const u16x8*)&tile[r][cs];
      u16x8 w1 = *(const u16x8*)&tile[r][cs + 8];
      ushort_t* dst = (ushort_t*)oWi + (size_t)(cp0 + r) * 1024 + c0 + cs;
      *(u16x8*)dst = w0;
      *(u16x8*)(dst + 8) = w1;
    }
    __syncthreads();
    int c = t >> 2, ms = (t & 3) * 16;
    u16x8 o0, o1;
#pragma unroll
    for (int j = 0; j < 8; ++j) o0[j] = tile[ms + j][c];
#pragma unroll
    for (int j = 0; j < 8; ++j) o1[j] = tile[ms + 8 + j][c];
    ushort_t* dst = oWibT + (size_t)(c0 + c) * 2048 + cp0 + ms;
    *(u16x8*)dst = o0;
    *(u16x8*)(dst + 8) = o1;
  } else if (bid < 2952) {
    // zero pad rows 3200-3327 of stackedA
    int i = (bid - 2824) * 1024 + t * 4;
    ushort_t* o = (ushort_t*)oWi + (size_t)3200 * 1024 + i;
    *(u16x4*)o = (u16x4){0, 0, 0, 0};
  } else {
    // fused k0: per-token sum of squares partials (512 blocks)
    int kb = bid - 2952;
    int b8 = kb >> 3;
    int cc = kb & 7;
    int s4 = (t & 15) * 4;
    int cg = t >> 4;
    const float* xp = x + (size_t)b8 * 65536 + (size_t)cc * 128 * 64;
    float4 a = {0.f, 0.f, 0.f, 0.f};
#pragma unroll
    for (int j = 0; j < 8; ++j) {
      int c = cg + j * 16;
      float4 v = *(const float4*)(xp + (size_t)c * 64 + s4);
      a.x = fmaf(v.x, v.x, a.x);
      a.y = fmaf(v.y, v.y, a.y);
      a.z = fmaf(v.z, v.z, a.z);
      a.w = fmaf(v.w, v.w, a.w);
    }
    __shared__ float red0[16][68];
    *(float4*)&red0[cg][s4] = a;
    __syncthreads();
    if (t < 64) {
      float s = 0.f;
#pragma unroll
      for (int g = 0; g < 16; ++g) s += red0[g][t];
      ssq8[cc * 4096 + b8 * 64 + t] = s;
    }
  }
}

// ---------------- fused: GEMM0 split-K (blocks 0-287, bf16 partials) + k1 (288-799) ----
__launch_bounds__(512, 4)
__global__ void g0k1(const ushort_t* __restrict__ A, const ushort_t* __restrict__ B,
                     ushort_t* __restrict__ Cb, const float* __restrict__ x,
                     const float* __restrict__ ssq8, __hip_bfloat16* __restrict__ xnb) {
  __shared__ alignas(16) unsigned char SHRAW[65536];
  const int bid = blockIdx.x;
  const int tid = threadIdx.x;
  if (bid >= 288) {
    int ht = tid >> 8, t = tid & 255;
    int tile_id = (bid - 288) * 2 + ht;
    int ct = tile_id & 15, b8 = tile_id >> 4;
    float* tbuf = (float*)(SHRAW + ht * 20480);  // [64][65]
    float* ivs = tbuf + 64 * 65;
    if (t < 64) {
      float s = 0.f;
#pragma unroll
      for (int cc = 0; cc < 8; ++cc) s += ssq8[cc * 4096 + b8 * 64 + t];
      ivs[t] = rsqrtf(fmaxf(s, 1e-24f));
    }
    int s = t & 63, cq = t >> 6;
    const float* xp = x + (size_t)b8 * 65536 + (size_t)ct * 64 * 64;
#pragma unroll
    for (int r = 0; r < 16; ++r) {
      int cl = cq * 16 + r;
      tbuf[cl * 65 + s] = xp[cl * 64 + s];
    }
    __syncthreads();
    int cl = t & 63, sq = t >> 6;
#pragma unroll
    for (int r = 0; r < 16; ++r) {
      int smm = sq * 16 + r;
      int tm = b8 * 64 + smm;
      xnb[(size_t)tm * 1024 + ct * 64 + cl] = __float2bfloat16(tbuf[cl * 65 + smm] * ivs[smm]);
    }
    return;
  }
  ushort_t* SH = (ushort_t*)SHRAW;
  const int Kstride = 2048, N = 1024;
  const int nx = bid & 7, ny = (bid >> 3) % 9, sK = bid / 72;
  const int m0 = ny * 128, n0 = nx * 128;
  const int koff = sK * 512;
  const int w = tid >> 6, l = tid & 63;
  const int wr = w >> 2, wc = w & 3;
  const int srow = w * 8 + (l >> 3);
  const int ksw = ((l & 7) ^ (l >> 3)) * 8;
  const ushort_t* Ag0 = A + (size_t)(m0 + srow) * Kstride + ksw + koff;
  const ushort_t* Ag1 = A + (size_t)(m0 + 64 + srow) * Kstride + ksw + koff;
  const ushort_t* Bg0 = B + (size_t)(n0 + srow) * Kstride + ksw + koff;
  const ushort_t* Bg1 = B + (size_t)(n0 + 64 + srow) * Kstride + ksw + koff;
  const int l0 = w * 512;
  const int l1 = 4096 + w * 512;

  f32x4 acc[4][2];
#pragma unroll
  for (int i = 0; i < 4; ++i)
#pragma unroll
    for (int j = 0; j < 2; ++j) acc[i][j] = (f32x4){0.f, 0.f, 0.f, 0.f};

  const int sw = l & 7, qq = l >> 4;

#define ASH(buf) (SH + (buf)*8192)
#define BSH(buf) (SH + 16384 + (buf)*8192)
#define STAGE(buf, k0)                               \
  {                                                  \
    gload_lds16(Ag0 + (k0), ASH(buf) + l0);          \
    gload_lds16(Ag1 + (k0), ASH(buf) + l1);          \
    gload_lds16(Bg0 + (k0), BSH(buf) + l0);          \
    gload_lds16(Bg1 + (k0), BSH(buf) + l1);          \
  }
#define COMPUTE(buf)                                                                     \
  {                                                                                      \
    s16x8 af[4][2], bf[2][2];                                                            \
    _Pragma("unroll") for (int kk = 0; kk < 2; ++kk) {                                   \
      int slot = (((kk << 2) + qq) ^ sw) * 8;                                            \
      _Pragma("unroll") for (int mi = 0; mi < 4; ++mi)                                   \
          af[mi][kk] = *(const s16x8*)&ASH(buf)[(wr * 64 + mi * 16 + (l & 15)) * 64 +    \
                                               slot];                                   \
      _Pragma("unroll") for (int ni = 0; ni < 2; ++ni)                                   \
          bf[ni][kk] = *(const s16x8*)&BSH(buf)[(wc * 32 + ni * 16 + (l & 15)) * 64 +    \
                                               slot];                                   \
    }                                                                                    \
    _Pragma("unroll") for (int kk = 0; kk < 2; ++kk)                                     \
        _Pragma("unroll") for (int mi = 0; mi < 4; ++mi)                                 \
            _Pragma("unroll") for (int ni = 0; ni < 2; ++ni)                             \
                acc[mi][ni] = __builtin_amdgcn_mfma_f32_16x16x32_bf16(af[mi][kk],        \
                                                                     bf[ni][kk],        \
                                                                     acc[mi][ni], 0, 0, 0); \
  }

  STAGE(0, 0);
  int buf = 0;
  for (int t2 = 0; t2 < 7; ++t2) {
    STAGE(buf ^ 1, (t2 + 1) << 6);
    asm volatile("s_waitcnt vmcnt(4)" ::: "memory");
    __builtin_amdgcn_s_barrier();
    asm volatile("" ::: "memory");
    COMPUTE(buf);
    asm volatile("" ::: "memory");
    __builtin_amdgcn_s_barrier();
    buf ^= 1;
  }
  asm volatile("s_waitcnt vmcnt(0)" ::: "memory");
  __builtin_amdgcn_s_barrier();
  asm volatile("" ::: "memory");
  COMPUTE(buf);
#undef STAGE
#undef COMPUTE
#undef ASH
#undef BSH

  ushort_t* Co = Cb + (size_t)sK * 1152 * 1024;
#pragma unroll
  for (int mi = 0; mi < 4; ++mi) {
    int row = m0 + wr * 64 + mi * 16 + (l >> 4) * 4;
#pragma unroll
    for (int ni = 0; ni < 2; ++ni) {
      int col = n0 + wc * 32 + ni * 16 + (l & 15);
#pragma unroll
      for (int r = 0; r < 4; ++r) {
        __hip_bfloat16 hb = __float2bfloat16(acc[mi][ni][r]);
        Co[(size_t)(row + r) * N + col] = *(ushort_t*)&hb;
      }
    }
  }
}

// ---------------- kpackC: sum 4 bf16 split-K partials -> bf16 stackedA rows 2048+ ----------
__global__ void kpackC(const ushort_t* __restrict__ Wc4b, ushort_t* __restrict__ dst) {
  int i = (blockIdx.x * 256 + threadIdx.x) * 8;
  u16x8 p0 = *(const u16x8*)(Wc4b + i);
  u16x8 p1 = *(const u16x8*)(Wc4b + 1179648 + i);
  u16x8 p2 = *(const u16x8*)(Wc4b + 2359296 + i);
  u16x8 p3 = *(const u16x8*)(Wc4b + 3538944 + i);
  u16x8 o;
#pragma unroll
  for (int j = 0; j < 8; ++j) {
    float s = bf2f(p0[j]) + bf2f(p1[j]) + bf2f(p2[j]) + bf2f(p3[j]);
    __hip_bfloat16 hb = __float2bfloat16(s);
    o[j] = *(ushort_t*)&hb;
  }
  *(u16x8*)(dst + i) = o;
}

// ---------------- big stacked GEMM, 256x256, 8-phase, A+B register-hold (24 ds_read/K-tile),
//                  counted vmcnt, race-audited peeled tail, coalesced epilogue ----
__launch_bounds__(512, 2)
__global__ void gemm256_8ph(const ushort_t* __restrict__ A, const ushort_t* __restrict__ B,
                            ushort_t* __restrict__ C, int K, int N) {
  __shared__ alignas(16) ushort_t SH[65536];  // 128 KB
  const int tid = threadIdx.x;
  const int m0 = blockIdx.y * 256, n0 = blockIdx.x * 256;
  const int w = tid >> 6, l = tid & 63;
  const int wr = w >> 2, wc = w & 3;  // 2x4 wave grid; per-wave 128m x 64n
  const int r16 = l & 15, qq = l >> 4, sw = l & 7;
  const int s = tid >> 3;
  const int s_hi = s >> 5, s_lo = s & 31;
  const int ksw = ((tid & 7) ^ (s & 7)) * 8;
  const int NT = K >> 6;

  const ushort_t* pA0 = A + (size_t)(m0 + s) * K + ksw;
  const ushort_t* pA1 = A + (size_t)(m0 + 128 + s) * K + ksw;
  const ushort_t* pB0 = B + (size_t)(n0 + s_hi * 64 + s_lo) * K + ksw;
  const ushort_t* pB1 = B + (size_t)(n0 + 128 + s_hi * 64 + s_lo) * K + ksw;
  ushort_t* dA = SH + tid * 8;
  ushort_t* dB = SH + 32768 + tid * 8;

  f32x4 acc[8][4];
#pragma unroll
  for (int i = 0; i < 8; ++i)
#pragma unroll
    for (int j = 0; j < 4; ++j) acc[i][j] = (f32x4){0.f, 0.f, 0.f, 0.f};

#define SA(kt, h)                                                                        \
  {                                                                                      \
    gload_lds16(pA0 + (size_t)(h) * (K << 6) + ((kt) << 6),                              \
                dA + (((kt)&1) << 14) + ((h) << 13));                                    \
    gload_lds16(pA1 + (size_t)(h) * (K << 6) + ((kt) << 6),                              \
                dA + (((kt)&1) << 14) + ((h) << 13) + 4096);                             \
  }
#define SB(kt, h)                                                                        \
  {                                                                                      \
    gload_lds16(pB0 + (size_t)(h) * (K << 5) + ((kt) << 6),                              \
                dB + (((kt)&1) << 14) + ((h) << 13));                                    \
    gload_lds16(pB1 + (size_t)(h) * (K << 5) + ((kt) << 6),                              \
                dB + (((kt)&1) << 14) + ((h) << 13) + 4096);                             \
  }
#define VMC4 asm volatile("s_waitcnt vmcnt(4)" ::: "memory")
#define VMC0 asm volatile("s_waitcnt vmcnt(0)" ::: "memory")
#define BAR                          \
  asm volatile("" ::: "memory");     \
  __builtin_amdgcn_s_barrier();      \
  asm volatile("" ::: "memory")

#define MFMAQ(mh, nh)                                                                    \
  __builtin_amdgcn_s_setprio(1);                                                         \
  _Pragma("unroll") for (int kk = 0; kk < 2; ++kk)                                       \
      _Pragma("unroll") for (int mi2 = 0; mi2 < 4; ++mi2)                                \
          _Pragma("unroll") for (int ni2 = 0; ni2 < 2; ++ni2)                            \
              acc[(mh)*4 + mi2][(nh)*2 + ni2] = __builtin_amdgcn_mfma_f32_16x16x32_bf16( \
                  af[kk][mi2], bf[kk][(nh)*2 + ni2], acc[(mh)*4 + mi2][(nh)*2 + ni2],    \
                  0, 0, 0);                                                              \
  __builtin_amdgcn_s_setprio(0)

// One K-tile (4 phases). af(mh=0)+ALL bf read at start; af(mh=1) re-read at phase 3.
// 24 ds_read_b128 per wave per K-tile (was 32). Stage/vmcnt schedule unchanged.
#define KTILE(d, S1, S2, S3, S4, V4)                                                     \
  {                                                                                      \
    s16x8 af[2][4], bf[2][4];                                                            \
    _Pragma("unroll") for (int kk = 0; kk < 2; ++kk) {                                   \
      int slot = (((kk << 2) + qq) ^ sw) * 8;                                            \
      _Pragma("unroll") for (int mi2 = 0; mi2 < 4; ++mi2)                                \
          af[kk][mi2] = *(const s16x8*)&SH[((d) << 14) +                                 \
                                           (wr * 64 + mi2 * 16 + r16) * 64 + slot];      \
      _Pragma("unroll") for (int nh2 = 0; nh2 < 2; ++nh2)                                \
          _Pragma("unroll") for (int ni2 = 0; ni2 < 2; ++ni2)                            \
              bf[kk][nh2 * 2 + ni2] = *(const s16x8*)&SH[32768 + ((d) << 14) +           \
                                           (nh2 << 13) +                                 \
                                           (wc * 32 + ni2 * 16 + r16) * 64 + slot];      \
    }                                                                                    \
    S1; BAR; MFMAQ(0, 0); BAR;                                                           \
    S2; BAR; MFMAQ(0, 1); BAR;                                                           \
    _Pragma("unroll") for (int kk = 0; kk < 2; ++kk) {                                   \
      int slot = (((kk << 2) + qq) ^ sw) * 8;                                            \
      _Pragma("unroll") for (int mi2 = 0; mi2 < 4; ++mi2)                                \
          af[kk][mi2] = *(const s16x8*)&SH[((d) << 14) + 8192 +                          \
                                           (wr * 64 + mi2 * 16 + r16) * 64 + slot];      \
    }                                                                                    \
    S3; BAR; MFMAQ(1, 0); BAR;                                                           \
    S4; BAR; MFMAQ(1, 1); V4; BAR;                                                       \
  }

  // prologue: kt0 complete + kt1.{A0,B0}; vmcnt(4) -> kt0's 4 halves landed
  SA(0, 0); SB(0, 0); SA(0, 1); SB(0, 1); SA(1, 0); SB(1, 0);
  VMC4;
  __builtin_amdgcn_s_barrier();
  asm volatile("" ::: "memory");

#pragma unroll 1
  for (int I = 0; I < (NT >> 1) - 1; ++I) {
    const int kt = 2 * I;
    const int k1 = kt + 1, k2 = kt + 2, k3 = kt + 3;
    KTILE(0, SA(k1, 1), SB(k1, 1), SA(k2, 0), SB(k2, 0), VMC4);
    KTILE(1, SA(k2, 1), SB(k2, 1), SA(k3, 0), SB(k3, 0), VMC4);
  }
  // peeled last K-pair (kt = NT-2): vmcnt(0) before consuming the final half-tiles
  {
    const int k1 = NT - 1;
    KTILE(0, SA(k1, 1), SB(k1, 1), , , VMC0);
    KTILE(1, , , , , );
  }
#undef KTILE
#undef MFMAQ
#undef BAR
#undef SA
#undef SB
#undef VMC4
#undef VMC0

  // coalesced epilogue: per-wave LDS bounce, u16x8 stores
  ushort_t* eb = SH + w * 2048;
  const int erow = (l >> 4) * 4;
  const int rrow = l >> 2, rc = (l & 3) * 16;
#pragma unroll
  for (int mi = 0; mi < 8; ++mi) {
    asm volatile("s_waitcnt lgkmcnt(0)" ::: "memory");
#pragma unroll
    for (int ni = 0; ni < 4; ++ni)
#pragma unroll
      for (int r = 0; r < 4; ++r) {
        __hip_bfloat16 hb = __float2bfloat16(acc[mi][ni][r]);
        eb[(erow + r) * 68 + ni * 16 + r16] = *(ushort_t*)&hb;
      }
    asm volatile("s_waitcnt lgkmcnt(0)" ::: "memory");
    u16x8 v0 = *(const u16x8*)&eb[rrow * 68 + rc];
    u16x8 v1 = *(const u16x8*)&eb[rrow * 68 + rc + 8];
    size_t gbase = (size_t)(m0 + wr * 128 + mi * 16 + rrow) * N + n0 + wc * 64 + rc;
    *(u16x8*)&C[gbase] = v0;
    *(u16x8*)&C[gbase + 8] = v1;
  }
}

// ---------------- K5: row softmax over tokens + gate sigmoid, one wave per (q,b) ----------------
__launch_bounds__(256)
__global__ void k5_softmax(const ushort_t* __restrict__ logitsTb, const float* __restrict__ bWg,
                           float* __restrict__ colsumW, ushort_t* __restrict__ wbT) {
  int wv = (blockIdx.x << 2) + (threadIdx.x >> 6);
  int q = wv >> 3, b = wv & 7;
  int l = threadIdx.x & 63;
  int g = q >> 7;
  size_t base = (size_t)q * 4096 + b * 512 + l * 8;
  u16x8 v8 = *(const u16x8*)(logitsTb + base);
  float vs[8];
#pragma unroll
  for (int i = 0; i < 8; ++i) vs[i] = bf2f(v8[i]);
  float M = vs[0];
#pragma unroll
  for (int i = 1; i < 8; ++i) M = fmaxf(M, vs[i]);
#pragma unroll
  for (int m = 1; m < 64; m <<= 1) M = fmaxf(M, __shfl_xor(M, m, 64));
  float e[8], S = 0.f;
#pragma unroll
  for (int i = 0; i < 8; ++i) {
    e[i] = expf(vs[i] - M);
    S += e[i];
  }
#pragma unroll
  for (int m = 1; m < 64; m <<= 1) S += __shfl_xor(S, m, 64);
  float R = 1.0f / S;
  u16x8 g8 = *(const u16x8*)(logitsTb + (size_t)(1024 + g) * 4096 + b * 512 + l * 8);
  float bg = bWg[g];
  float wv8[8], wsum = 0.f;
#pragma unroll
  for (int i = 0; i < 8; ++i) {
    float gl = bf2f(g8[i]);
    float ag = 1.0f / (1.0f + expf(-(gl + bg)));
    wv8[i] = e[i] * R * ag;
    wsum += wv8[i];
  }
#pragma unroll
  for (int m = 1; m < 64; m <<= 1) wsum += __shfl_xor(wsum, m, 64);
  if (l == 0) colsumW[b * 1024 + q] = wsum;
  u16x8 o;
#pragma unroll
  for (int i = 0; i < 8; ++i) {
    __hip_bfloat16 hb = __float2bfloat16(wv8[i]);
    o[i] = *(ushort_t*)&hb;
  }
  *(u16x8*)(wbT + base) = o;
}

// ---------------- K6: VLAD einsum via MFMA, 64x64 tile, m-split 8, counted vmcnt ----------------
__launch_bounds__(256)
__global__ void k6_vlad_mfma(const ushort_t* __restrict__ wbT, const ushort_t* __restrict__ YcT,
                             float* __restrict__ vpart) {
  int kt = blockIdx.x >> 2, dt = blockIdx.x & 3;
  int ms = blockIdx.y, b = blockIdx.z;
  __shared__ alignas(16) ushort_t Ash[2][4096];
  __shared__ alignas(16) ushort_t Bsh[2][4096];
  const int tid = threadIdx.x;
  const int w = tid >> 6, l = tid & 63;
  const int wr = w >> 1, wc = w & 1;
  const int crow = l >> 3;
  const int ksw = ((l & 7) ^ crow) * 8;

  const ushort_t* Ap[2];
  const ushort_t* Bp[2];
  int loff[2];
#pragma unroll
  for (int c = 0; c < 2; ++c) {
    int chunk = w * 2 + c;
    Ap[c] = wbT + (size_t)(kt * 64 + chunk * 8 + crow) * 4096 + b * 512 + ms * 64 + ksw;
    Bp[c] = YcT + (size_t)(dt * 64 + chunk * 8 + crow) * 4096 + b * 512 + ms * 64 + ksw;
    loff[c] = chunk * 512;
  }

  f32x4 acc[2][2];
#pragma unroll
  for (int i = 0; i < 2; ++i)
#pragma unroll
    for (int j = 0; j < 2; ++j) acc[i][j] = (f32x4){0.f, 0.f, 0.f, 0.f};

  const int sw = l & 7, qq = l >> 4;

#define STAGE6(buf, g)                                                       \
  {                                                                          \
    size_t offA = (size_t)(g)*524288;                                        \
    size_t offB = (size_t)(g)*1048576;                                       \
    gload_lds16(Ap[0] + offA, &Ash[buf][loff[0]]);                           \
    gload_lds16(Ap[1] + offA, &Ash[buf][loff[1]]);                           \
    gload_lds16(Bp[0] + offB, &Bsh[buf][loff[0]]);                           \
    gload_lds16(Bp[1] + offB, &Bsh[buf][loff[1]]);                           \
  }
#define COMPUTE6(buf)                                                                    \
  {                                                                                      \
    s16x8 af[2][2], bf[2][2];                                                            \
    _Pragma("unroll") for (int kk = 0; kk < 2; ++kk) {                                   \
      int slot = (((kk << 2) + qq) ^ sw) * 8;                                            \
      _Pragma("unroll") for (int mi = 0; mi < 2; ++mi) {                                 \
        af[mi][kk] = *(const s16x8*)&Ash[buf][(wr * 32 + mi * 16 + (l & 15)) * 64 +      \
                                             slot];                                     \
        bf[mi][kk] = *(const s16x8*)&Bsh[buf][(wc * 32 + mi * 16 + (l & 15)) * 64 +      \
                                             slot];                                     \
      }                                                                                  \
    }                                                                                    \
    _Pragma("unroll") for (int kk = 0; kk < 2; ++kk)                                     \
        _Pragma("unroll") for (int mi = 0; mi < 2; ++mi)                                 \
            _Pragma("unroll") for (int ni = 0; ni < 2; ++ni)                             \
                acc[mi][ni] = __builtin_amdgcn_mfma_f32_16x16x32_bf16(af[mi][kk],        \
                                                                     bf[ni][kk],        \
                                                                     acc[mi][ni], 0, 0, 0); \
  }

  STAGE6(0, 0);
  int buf = 0;
  for (int s = 0; s < 7; ++s) {
    STAGE6(buf ^ 1, s + 1);
    asm volatile("s_waitcnt vmcnt(4)" ::: "memory");
    __builtin_amdgcn_s_barrier();
    asm volatile("" ::: "memory");
    COMPUTE6(buf);
    asm volatile("" ::: "memory");
    __builtin_amdgcn_s_barrier();
    buf ^= 1;
  }
  asm volatile("s_waitcnt vmcnt(0)" ::: "memory");
  __builtin_amdgcn_s_barrier();
  asm volatile("" ::: "memory");
  COMPUTE6(buf);
#undef STAGE6
#undef COMPUTE6

#pragma unroll
  for (int mi = 0; mi < 2; ++mi) {
    int row = kt * 64 + wr * 32 + mi * 16 + (l >> 4) * 4;
#pragma unroll
    for (int ni = 0; ni < 2; ++ni) {
      int col = dt * 64 + wc * 32 + ni * 16 + (l & 15);
#pragma unroll
      for (int r = 0; r < 4; ++r)
        vpart[((size_t)(ms * 8 + b) * 128 + row + r) * 256 + col] = acc[mi][ni][r];
    }
  }
}

// ---------------- K7: combine 8 partials + bias-part - S*centroid, intra-normalize ----------------
__global__ void k7_intranorm(const float* __restrict__ vpart, const float* __restrict__ colsumW,
                             const float* __restrict__ b_inp, const float* __restrict__ cent,
                             float* __restrict__ out, float* __restrict__ ss1) {
  int k = blockIdx.x;
  int b = blockIdx.y;
  int d = threadIdx.x;
  float S = 0.f, bp = 0.f;
#pragma unroll
  for (int g = 0; g < 8; ++g) {
    float cw = colsumW[b * 1024 + g * 128 + k];
    S += cw;
    bp = fmaf(b_inp[g * 256 + d], cw, bp);
  }
  size_t off = ((size_t)b * 128 + k) * 256 + d;
  float v = bp - S * cent[(size_t)k * 256 + d];
#pragma unroll
  for (int i = 0; i < 8; ++i) v += vpart[off + (size_t)i * 262144];
  float ss = v * v;
#pragma unroll
  for (int m = 1; m < 64; m <<= 1) ss += __shfl_xor(ss, m, 64);
  __shared__ float red[4];
  int lane = d & 63, wv = d >> 6;
  if (lane == 0) red[wv] = ss;
  __syncthreads();
  float tot = red[0] + red[1] + red[2] + red[3];
  float rinv = 1.0f / fmaxf(sqrtf(tot), EPSN);
  out[off] = v * rinv;
  if (d == 0) ss1[b * 128 + k] = tot * rinv * rinv;
}

// ---------------- K8: final global L2 norm ----------------
__global__ void k8_finalnorm(const float* __restrict__ ss1, float* __restrict__ out) {
  int b = blockIdx.x;
  int t = threadIdx.x;
  __shared__ float red[256];
  red[t] = (t < 128) ? ss1[b * 128 + t] : 0.f;
  __syncthreads();
  for (int o = 128; o > 0; o >>= 1) {
    if (t < o) red[t] += red[t + o];
    __syncthreads();
  }
  float rinv = 1.0f / fmaxf(sqrtf(red[0]), EPSN);
  float* op = out + (size_t)b * 32768;
  for (int i = t; i < 32768; i += 256) op[i] *= rinv;
}

extern "C" void kernel_launch(void* const* d_in, const int* in_sizes, int n_in,
                              void* d_out, int out_size, void* d_ws, size_t ws_size,
                              hipStream_t stream) {
  const float* x     = (const float*)d_in[0];
  const float* W_inp = (const float*)d_in[1];
  const float* b_inp = (const float*)d_in[2];
  const float* W_g   = (const float*)d_in[3];
  const float* b_g   = (const float*)d_in[4];
  const float* W_gk  = (const float*)d_in[5];
  // b_gk (d_in[6]) cancels in the token-axis softmax — unused.
  const float* cent  = (const float*)d_in[7];
  float* out = (float*)d_out;
  float* ws = (float*)d_ws;

  // workspace layout (float offsets), total 12,887,104 floats = 51.5 MB
  float* ssq8    = ws + 0;         // 32768
  float* colsumW = ws + 32768;     // 8192
  float* ss1     = ws + 40960;     // 1024
  float* bWg     = ws + 41984;     // 64
  ushort_t* xnb  = (ushort_t*)(ws + 42048);        // [4096][1024] bf16 (2097152 fl)
  ushort_t* wbT  = xnb;                            // alias (xnb dead after gemm256)
  ushort_t* stackedA = (ushort_t*)(ws + 2139200);  // [3328][1024] bf16 (1703936 fl)
  ushort_t* WibT = (ushort_t*)(ws + 3843136);      // [1024][2048] bf16 (1048576 fl)
  ushort_t* Wgkx = (ushort_t*)(ws + 4891712);      // [1152][2048] bf16 (1179648 fl)
  float* vpart   = ws + 3843136;   // 2097152 fl, aliases WibT+Wgkx (dead after gemm0)
  ushort_t* Wc4b = (ushort_t*)(ws + 6071360);      // [4][1152][1024] bf16, dead after kpackC
  ushort_t* Cstacked = (ushort_t*)(ws + 6071360);  // [3328][4096] bf16 (6815744 fl), over Wc4b
  ushort_t* YcT      = Cstacked;                   // rows 0-2047
  ushort_t* logitsTb = Cstacked + (size_t)2048 * 4096;  // rows 2048-3199

  // fused prep: Wgkx pack + gate + bWg + Wib/WibT dual + pad + k0 ssq partials
  kpack2<<<3464, 256, 0, stream>>>(W_inp, W_gk, W_g, b_inp, b_g,
                                   (__hip_bfloat16*)stackedA, (__hip_bfloat16*)Wgkx, WibT, bWg,
                                   x, ssq8);
  // fused: gemm0 split-K x4 (bf16 partials, blocks 0-287) || k1 transpose (288-799)
  g0k1<<<800, 512, 0, stream>>>(Wgkx, WibT, Wc4b, x, ssq8, (__hip_bfloat16*)xnb);
  // pack: stackedA rows 2048-3199 = bf16(sum_s Wc4b[s])
  kpackC<<<576, 256, 0, stream>>>(Wc4b, stackedA + (size_t)2048 * 1024);
  // big stacked GEMM (256^2, 8-phase, A+B reg-hold, coalesced C): Cstacked = stackedA @ xnb^T
  gemm256_8ph<<<dim3(16, 13), 512, 0, stream>>>(stackedA, xnb, Cstacked, 1024, 4096);
  k5_softmax<<<2048, 256, 0, stream>>>(logitsTb, bWg, colsumW, wbT);
  k6_vlad_mfma<<<dim3(8, 8, 8), 256, 0, stream>>>(wbT, YcT, vpart);
  k7_intranorm<<<dim3(128, 8), 256, 0, stream>>>(vpart, colsumW, b_inp, cent, out, ss1);
  k8_finalnorm<<<8, 256, 0, stream>>>(ss1, out);
}

// Round 17
// 108.638 us; speedup vs baseline: 1.1316x; 1.0193x over previous
//
#include <hip/hip_runtime.h>
#include <hip/hip_bf16.h>
#include <math.h>

#define EPSN 1e-12f
typedef unsigned short ushort_t;

typedef float f32x4 __attribute__((ext_vector_type(4)));
typedef short s16x8 __attribute__((ext_vector_type(8)));
typedef unsigned short u16x8 __attribute__((ext_vector_type(8)));
typedef unsigned short u16x4 __attribute__((ext_vector_type(4)));

__device__ __forceinline__ void gload_lds16(const void* g, void* l) {
  __builtin_amdgcn_global_load_lds((const __attribute__((address_space(1))) void*)g,
                                   (__attribute__((address_space(3))) void*)l, 16, 0, 0);
}

__device__ __forceinline__ float bf2f(ushort_t u) {
  return __uint_as_float(((unsigned)u) << 16);
}

// ---------------- kpack2: Wgkx pack + gate/zero rows + bWg + {Wib row-major AND WibT}
//                  dual-write + stackedA pad + k0 ssq partials ----------------
__global__ void kpack2(const float* __restrict__ Wi, const float* __restrict__ Wgk,
                       const float* __restrict__ W_g, const float* __restrict__ b_inp,
                       const float* __restrict__ b_g, __hip_bfloat16* __restrict__ oWi,
                       __hip_bfloat16* __restrict__ oWx, ushort_t* __restrict__ oWibT,
                       float* __restrict__ bWg, const float* __restrict__ x,
                       float* __restrict__ ssq8) {
  int bid = blockIdx.x;
  int t = threadIdx.x;
  if (bid < 2048) {
    int i = (bid * 256 + t) * 4;
    float4 v = *(const float4*)(Wgk + i);
    oWx[i + 0] = __float2bfloat16(v.x);
    oWx[i + 1] = __float2bfloat16(v.y);
    oWx[i + 2] = __float2bfloat16(v.z);
    oWx[i + 3] = __float2bfloat16(v.w);
  } else if (bid < 2064) {
    int i = (bid - 2048) * 1024 + t * 4;  // 16 blocks: 8 gate rows
    float4 v = *(const float4*)(W_g + i);
    __hip_bfloat16* o = oWx + 1024 * 2048 + i;
    o[0] = __float2bfloat16(v.x);
    o[1] = __float2bfloat16(v.y);
    o[2] = __float2bfloat16(v.z);
    o[3] = __float2bfloat16(v.w);
  } else if (bid < 2304) {
    int i = (bid - 2064) * 1024 + t * 4;  // 240 blocks: 120 zero rows of Wgkx
    ushort_t* o = (ushort_t*)(oWx + 1032 * 2048) + i;
    *(u16x4*)o = (u16x4){0, 0, 0, 0};
  } else if (bid < 2312) {
    int j = bid - 2304;  // 0..7
    const float* row = W_g + (size_t)j * 2048;
    float s = 0.f;
    for (int c = t; c < 2048; c += 256) s = fmaf(b_inp[c], row[c], s);
    __shared__ float red[256];
    red[t] = s;
    __syncthreads();
    for (int o = 128; o > 0; o >>= 1) {
      if (t < o) red[t] += red[t + o];
      __syncthreads();
    }
    if (t == 0) bWg[j] = red[0] + b_g[j];
  } else if (bid < 2824) {
    // dual: Wib (row-major bf16) + WibT (transposed); 512 tiles 64x64, W_inp read ONCE
    int tt = bid - 2312;
    int cp0 = (tt >> 4) * 64;
    int c0 = (tt & 15) * 64;
    __shared__ ushort_t tile[64][72];
    int r = t >> 2, cs = (t & 3) * 16;
    const float* src = Wi + (size_t)(cp0 + r) * 1024 + c0 + cs;
#pragma unroll
    for (int j = 0; j < 16; j += 4) {
      float4 v = *(const float4*)(src + j);
      __hip_bfloat16 h0 = __float2bfloat16(v.x), h1 = __float2bfloat16(v.y);
      __hip_bfloat16 h2 = __float2bfloat16(v.z), h3 = __float2bfloat16(v.w);
      tile[r][cs + j + 0] = *(ushort_t*)&h0;
      tile[r][cs + j + 1] = *(ushort_t*)&h1;
      tile[r][cs + j + 2] = *(ushort_t*)&h2;
      tile[r][cs + j + 3] = *(ushort_t*)&h3;
    }
    {
      u16x8 w0 = *(const u16x8*)&tile[r][cs];
      u16x8 w1 = *(const u16x8*)&tile[r][cs + 8];
      ushort_t* dst = (ushort_t*)oWi + (size_t)(cp0 + r) * 1024 + c0 + cs;
      *(u16x8*)dst = w0;
      *(u16x8*)(dst + 8) = w1;
    }
    __syncthreads();
    int c = t >> 2, ms = (t & 3) * 16;
    u16x8 o0, o1;
#pragma unroll
    for (int j = 0; j < 8; ++j) o0[j] = tile[ms + j][c];
#pragma unroll
    for (int j = 0; j < 8; ++j) o1[j] = tile[ms + 8 + j][c];
    ushort_t* dst = oWibT + (size_t)(c0 + c) * 2048 + cp0 + ms;
    *(u16x8*)dst = o0;
    *(u16x8*)(dst + 8) = o1;
  } else if (bid < 2952) {
    // zero pad rows 3200-3327 of stackedA
    int i = (bid - 2824) * 1024 + t * 4;
    ushort_t* o = (ushort_t*)oWi + (size_t)3200 * 1024 + i;
    *(u16x4*)o = (u16x4){0, 0, 0, 0};
  } else {
    // fused k0: per-token sum of squares partials (512 blocks)
    int kb = bid - 2952;
    int b8 = kb >> 3;
    int cc = kb & 7;
    int s4 = (t & 15) * 4;
    int cg = t >> 4;
    const float* xp = x + (size_t)b8 * 65536 + (size_t)cc * 128 * 64;
    float4 a = {0.f, 0.f, 0.f, 0.f};
#pragma unroll
    for (int j = 0; j < 8; ++j) {
      int c = cg + j * 16;
      float4 v = *(const float4*)(xp + (size_t)c * 64 + s4);
      a.x = fmaf(v.x, v.x, a.x);
      a.y = fmaf(v.y, v.y, a.y);
      a.z = fmaf(v.z, v.z, a.z);
      a.w = fmaf(v.w, v.w, a.w);
    }
    __shared__ float red0[16][68];
    *(float4*)&red0[cg][s4] = a;
    __syncthreads();
    if (t < 64) {
      float s = 0.f;
#pragma unroll
      for (int g = 0; g < 16; ++g) s += red0[g][t];
      ssq8[cc * 4096 + b8 * 64 + t] = s;
    }
  }
}

// ---------------- fused: GEMM0 split-K (blocks 0-287, bf16 partials) + k1 (288-799) ----
__launch_bounds__(512, 4)
__global__ void g0k1(const ushort_t* __restrict__ A, const ushort_t* __restrict__ B,
                     ushort_t* __restrict__ Cb, const float* __restrict__ x,
                     const float* __restrict__ ssq8, __hip_bfloat16* __restrict__ xnb) {
  __shared__ alignas(16) unsigned char SHRAW[65536];
  const int bid = blockIdx.x;
  const int tid = threadIdx.x;
  if (bid >= 288) {
    int ht = tid >> 8, t = tid & 255;
    int tile_id = (bid - 288) * 2 + ht;
    int ct = tile_id & 15, b8 = tile_id >> 4;
    float* tbuf = (float*)(SHRAW + ht * 20480);  // [64][65]
    float* ivs = tbuf + 64 * 65;
    if (t < 64) {
      float s = 0.f;
#pragma unroll
      for (int cc = 0; cc < 8; ++cc) s += ssq8[cc * 4096 + b8 * 64 + t];
      ivs[t] = rsqrtf(fmaxf(s, 1e-24f));
    }
    int s = t & 63, cq = t >> 6;
    const float* xp = x + (size_t)b8 * 65536 + (size_t)ct * 64 * 64;
#pragma unroll
    for (int r = 0; r < 16; ++r) {
      int cl = cq * 16 + r;
      tbuf[cl * 65 + s] = xp[cl * 64 + s];
    }
    __syncthreads();
    int cl = t & 63, sq = t >> 6;
#pragma unroll
    for (int r = 0; r < 16; ++r) {
      int smm = sq * 16 + r;
      int tm = b8 * 64 + smm;
      xnb[(size_t)tm * 1024 + ct * 64 + cl] = __float2bfloat16(tbuf[cl * 65 + smm] * ivs[smm]);
    }
    return;
  }
  ushort_t* SH = (ushort_t*)SHRAW;
  const int Kstride = 2048, N = 1024;
  const int nx = bid & 7, ny = (bid >> 3) % 9, sK = bid / 72;
  const int m0 = ny * 128, n0 = nx * 128;
  const int koff = sK * 512;
  const int w = tid >> 6, l = tid & 63;
  const int wr = w >> 2, wc = w & 3;
  const int srow = w * 8 + (l >> 3);
  const int ksw = ((l & 7) ^ (l >> 3)) * 8;
  const ushort_t* Ag0 = A + (size_t)(m0 + srow) * Kstride + ksw + koff;
  const ushort_t* Ag1 = A + (size_t)(m0 + 64 + srow) * Kstride + ksw + koff;
  const ushort_t* Bg0 = B + (size_t)(n0 + srow) * Kstride + ksw + koff;
  const ushort_t* Bg1 = B + (size_t)(n0 + 64 + srow) * Kstride + ksw + koff;
  const int l0 = w * 512;
  const int l1 = 4096 + w * 512;

  f32x4 acc[4][2];
#pragma unroll
  for (int i = 0; i < 4; ++i)
#pragma unroll
    for (int j = 0; j < 2; ++j) acc[i][j] = (f32x4){0.f, 0.f, 0.f, 0.f};

  const int sw = l & 7, qq = l >> 4;

#define ASH(buf) (SH + (buf)*8192)
#define BSH(buf) (SH + 16384 + (buf)*8192)
#define STAGE(buf, k0)                               \
  {                                                  \
    gload_lds16(Ag0 + (k0), ASH(buf) + l0);          \
    gload_lds16(Ag1 + (k0), ASH(buf) + l1);          \
    gload_lds16(Bg0 + (k0), BSH(buf) + l0);          \
    gload_lds16(Bg1 + (k0), BSH(buf) + l1);          \
  }
#define COMPUTE(buf)                                                                     \
  {                                                                                      \
    s16x8 af[4][2], bf[2][2];                                                            \
    _Pragma("unroll") for (int kk = 0; kk < 2; ++kk) {                                   \
      int slot = (((kk << 2) + qq) ^ sw) * 8;                                            \
      _Pragma("unroll") for (int mi = 0; mi < 4; ++mi)                                   \
          af[mi][kk] = *(const s16x8*)&ASH(buf)[(wr * 64 + mi * 16 + (l & 15)) * 64 +    \
                                               slot];                                   \
      _Pragma("unroll") for (int ni = 0; ni < 2; ++ni)                                   \
          bf[ni][kk] = *(const s16x8*)&BSH(buf)[(wc * 32 + ni * 16 + (l & 15)) * 64 +    \
                                               slot];                                   \
    }                                                                                    \
    _Pragma("unroll") for (int kk = 0; kk < 2; ++kk)                                     \
        _Pragma("unroll") for (int mi = 0; mi < 4; ++mi)                                 \
            _Pragma("unroll") for (int ni = 0; ni < 2; ++ni)                             \
                acc[mi][ni] = __builtin_amdgcn_mfma_f32_16x16x32_bf16(af[mi][kk],        \
                                                                     bf[ni][kk],        \
                                                                     acc[mi][ni], 0, 0, 0); \
  }

  STAGE(0, 0);
  int buf = 0;
  for (int t2 = 0; t2 < 7; ++t2) {
    STAGE(buf ^ 1, (t2 + 1) << 6);
    asm volatile("s_waitcnt vmcnt(4)" ::: "memory");
    __builtin_amdgcn_s_barrier();
    asm volatile("" ::: "memory");
    COMPUTE(buf);
    asm volatile("" ::: "memory");
    __builtin_amdgcn_s_barrier();
    buf ^= 1;
  }
  asm volatile("s_waitcnt vmcnt(0)" ::: "memory");
  __builtin_amdgcn_s_barrier();
  asm volatile("" ::: "memory");
  COMPUTE(buf);
#undef STAGE
#undef COMPUTE
#undef ASH
#undef BSH

  ushort_t* Co = Cb + (size_t)sK * 1152 * 1024;
#pragma unroll
  for (int mi = 0; mi < 4; ++mi) {
    int row = m0 + wr * 64 + mi * 16 + (l >> 4) * 4;
#pragma unroll
    for (int ni = 0; ni < 2; ++ni) {
      int col = n0 + wc * 32 + ni * 16 + (l & 15);
#pragma unroll
      for (int r = 0; r < 4; ++r) {
        __hip_bfloat16 hb = __float2bfloat16(acc[mi][ni][r]);
        Co[(size_t)(row + r) * N + col] = *(ushort_t*)&hb;
      }
    }
  }
}

// ---------------- kpackC: sum 4 bf16 split-K partials -> bf16 stackedA rows 2048+ ----------
__global__ void kpackC(const ushort_t* __restrict__ Wc4b, ushort_t* __restrict__ dst) {
  int i = (blockIdx.x * 256 + threadIdx.x) * 8;
  u16x8 p0 = *(const u16x8*)(Wc4b + i);
  u16x8 p1 = *(const u16x8*)(Wc4b + 1179648 + i);
  u16x8 p2 = *(const u16x8*)(Wc4b + 2359296 + i);
  u16x8 p3 = *(const u16x8*)(Wc4b + 3538944 + i);
  u16x8 o;
#pragma unroll
  for (int j = 0; j < 8; ++j) {
    float s = bf2f(p0[j]) + bf2f(p1[j]) + bf2f(p2[j]) + bf2f(p3[j]);
    __hip_bfloat16 hb = __float2bfloat16(s);
    o[j] = *(ushort_t*)&hb;
  }
  *(u16x8*)(dst + i) = o;
}

// ---------------- big stacked GEMM, 256x256, 8-phase, A+B reg-hold, ONE barrier/phase,
//                  vmcnt(2) coverage (provably race-free), coalesced epilogue ----
__launch_bounds__(512, 2)
__global__ void gemm256_8ph(const ushort_t* __restrict__ A, const ushort_t* __restrict__ B,
                            ushort_t* __restrict__ C, int K, int N) {
  __shared__ alignas(16) ushort_t SH[65536];  // 128 KB
  const int tid = threadIdx.x;
  const int m0 = blockIdx.y * 256, n0 = blockIdx.x * 256;
  const int w = tid >> 6, l = tid & 63;
  const int wr = w >> 2, wc = w & 3;  // 2x4 wave grid; per-wave 128m x 64n
  const int r16 = l & 15, qq = l >> 4, sw = l & 7;
  const int s = tid >> 3;
  const int s_hi = s >> 5, s_lo = s & 31;
  const int ksw = ((tid & 7) ^ (s & 7)) * 8;
  const int NT = K >> 6;

  const ushort_t* pA0 = A + (size_t)(m0 + s) * K + ksw;
  const ushort_t* pA1 = A + (size_t)(m0 + 128 + s) * K + ksw;
  const ushort_t* pB0 = B + (size_t)(n0 + s_hi * 64 + s_lo) * K + ksw;
  const ushort_t* pB1 = B + (size_t)(n0 + 128 + s_hi * 64 + s_lo) * K + ksw;
  ushort_t* dA = SH + tid * 8;
  ushort_t* dB = SH + 32768 + tid * 8;

  f32x4 acc[8][4];
#pragma unroll
  for (int i = 0; i < 8; ++i)
#pragma unroll
    for (int j = 0; j < 4; ++j) acc[i][j] = (f32x4){0.f, 0.f, 0.f, 0.f};

#define SA(kt, h)                                                                        \
  {                                                                                      \
    gload_lds16(pA0 + (size_t)(h) * (K << 6) + ((kt) << 6),                              \
                dA + (((kt)&1) << 14) + ((h) << 13));                                    \
    gload_lds16(pA1 + (size_t)(h) * (K << 6) + ((kt) << 6),                              \
                dA + (((kt)&1) << 14) + ((h) << 13) + 4096);                             \
  }
#define SB(kt, h)                                                                        \
  {                                                                                      \
    gload_lds16(pB0 + (size_t)(h) * (K << 5) + ((kt) << 6),                              \
                dB + (((kt)&1) << 14) + ((h) << 13));                                    \
    gload_lds16(pB1 + (size_t)(h) * (K << 5) + ((kt) << 6),                              \
                dB + (((kt)&1) << 14) + ((h) << 13) + 4096);                             \
  }
#define VMC2 asm volatile("s_waitcnt vmcnt(2)" ::: "memory")
#define VMC0 asm volatile("s_waitcnt vmcnt(0)" ::: "memory")
#define BAR                          \
  asm volatile("" ::: "memory");     \
  __builtin_amdgcn_s_barrier();      \
  asm volatile("" ::: "memory")

#define MFMAQ(mh, nh)                                                                    \
  __builtin_amdgcn_s_setprio(1);                                                         \
  _Pragma("unroll") for (int kk = 0; kk < 2; ++kk)                                       \
      _Pragma("unroll") for (int mi2 = 0; mi2 < 4; ++mi2)                                \
          _Pragma("unroll") for (int ni2 = 0; ni2 < 2; ++ni2)                            \
              acc[(mh)*4 + mi2][(nh)*2 + ni2] = __builtin_amdgcn_mfma_f32_16x16x32_bf16( \
                  af[kk][mi2], bf[kk][(nh)*2 + ni2], acc[(mh)*4 + mi2][(nh)*2 + ni2],    \
                  0, 0, 0);                                                              \
  __builtin_amdgcn_s_setprio(0)

// One K-tile (4 phases, ONE barrier each). Reads: af(mh=0)+all bf upfront (covered by
// prior vmcnt(2)); af(mh=1) at phase 3. Stages >=2 barriers after last read of target.
#define KTILE(d, S1, S2, S3, S4, V4)                                                     \
  {                                                                                      \
    s16x8 af[2][4], bf[2][4];                                                            \
    _Pragma("unroll") for (int kk = 0; kk < 2; ++kk) {                                   \
      int slot = (((kk << 2) + qq) ^ sw) * 8;                                            \
      _Pragma("unroll") for (int mi2 = 0; mi2 < 4; ++mi2)                                \
          af[kk][mi2] = *(const s16x8*)&SH[((d) << 14) +                                 \
                                           (wr * 64 + mi2 * 16 + r16) * 64 + slot];      \
      _Pragma("unroll") for (int nh2 = 0; nh2 < 2; ++nh2)                                \
          _Pragma("unroll") for (int ni2 = 0; ni2 < 2; ++ni2)                            \
              bf[kk][nh2 * 2 + ni2] = *(const s16x8*)&SH[32768 + ((d) << 14) +           \
                                           (nh2 << 13) +                                 \
                                           (wc * 32 + ni2 * 16 + r16) * 64 + slot];      \
    }                                                                                    \
    S1; MFMAQ(0, 0); BAR;                                                                \
    S2; MFMAQ(0, 1); BAR;                                                                \
    _Pragma("unroll") for (int kk = 0; kk < 2; ++kk) {                                   \
      int slot = (((kk << 2) + qq) ^ sw) * 8;                                            \
      _Pragma("unroll") for (int mi2 = 0; mi2 < 4; ++mi2)                                \
          af[kk][mi2] = *(const s16x8*)&SH[((d) << 14) + 8192 +                          \
                                           (wr * 64 + mi2 * 16 + r16) * 64 + slot];      \
    }                                                                                    \
    S3; MFMAQ(1, 0); BAR;                                                                \
    S4; MFMAQ(1, 1); V4; BAR;                                                            \
  }

  // prologue: kt0 complete + kt1.{A0,B0}; vmcnt(2) -> kt0's 4 halves landed
  SA(0, 0); SB(0, 0); SA(0, 1); SB(0, 1); SA(1, 0); SB(1, 0);
  VMC2;
  __builtin_amdgcn_s_barrier();
  asm volatile("" ::: "memory");

#pragma unroll 1
  for (int I = 0; I < (NT >> 1) - 1; ++I) {
    const int kt = 2 * I;
    const int k1 = kt + 1, k2 = kt + 2, k3 = kt + 3;
    KTILE(0, SA(k1, 1), SB(k1, 1), SA(k2, 0), SB(k2, 0), VMC2);
    KTILE(1, SA(k2, 1), SB(k2, 1), SA(k3, 0), SB(k3, 0), VMC2);
  }
  // peeled last K-pair (kt = NT-2): vmcnt(0) before consuming the final half-tiles
  {
    const int k1 = NT - 1;
    KTILE(0, SA(k1, 1), SB(k1, 1), , , VMC0);
    KTILE(1, , , , , );
  }
#undef KTILE
#undef MFMAQ
#undef BAR
#undef SA
#undef SB
#undef VMC2
#undef VMC0

  // coalesced epilogue: per-wave LDS bounce, u16x8 stores
  ushort_t* eb = SH + w * 2048;
  const int erow = (l >> 4) * 4;
  const int rrow = l >> 2, rc = (l & 3) * 16;
#pragma unroll
  for (int mi = 0; mi < 8; ++mi) {
    asm volatile("s_waitcnt lgkmcnt(0)" ::: "memory");
#pragma unroll
    for (int ni = 0; ni < 4; ++ni)
#pragma unroll
      for (int r = 0; r < 4; ++r) {
        __hip_bfloat16 hb = __float2bfloat16(acc[mi][ni][r]);
        eb[(erow + r) * 68 + ni * 16 + r16] = *(ushort_t*)&hb;
      }
    asm volatile("s_waitcnt lgkmcnt(0)" ::: "memory");
    u16x8 v0 = *(const u16x8*)&eb[rrow * 68 + rc];
    u16x8 v1 = *(const u16x8*)&eb[rrow * 68 + rc + 8];
    size_t gbase = (size_t)(m0 + wr * 128 + mi * 16 + rrow) * N + n0 + wc * 64 + rc;
    *(u16x8*)&C[gbase] = v0;
    *(u16x8*)&C[gbase + 8] = v1;
  }
}

// ---------------- K5: row softmax over tokens + gate sigmoid, one wave per (q,b) ----------------
__launch_bounds__(256)
__global__ void k5_softmax(const ushort_t* __restrict__ logitsTb, const float* __restrict__ bWg,
                           float* __restrict__ colsumW, ushort_t* __restrict__ wbT) {
  int wv = (blockIdx.x << 2) + (threadIdx.x >> 6);
  int q = wv >> 3, b = wv & 7;
  int l = threadIdx.x & 63;
  int g = q >> 7;
  size_t base = (size_t)q * 4096 + b * 512 + l * 8;
  u16x8 v8 = *(const u16x8*)(logitsTb + base);
  float vs[8];
#pragma unroll
  for (int i = 0; i < 8; ++i) vs[i] = bf2f(v8[i]);
  float M = vs[0];
#pragma unroll
  for (int i = 1; i < 8; ++i) M = fmaxf(M, vs[i]);
#pragma unroll
  for (int m = 1; m < 64; m <<= 1) M = fmaxf(M, __shfl_xor(M, m, 64));
  float e[8], S = 0.f;
#pragma unroll
  for (int i = 0; i < 8; ++i) {
    e[i] = expf(vs[i] - M);
    S += e[i];
  }
#pragma unroll
  for (int m = 1; m < 64; m <<= 1) S += __shfl_xor(S, m, 64);
  float R = 1.0f / S;
  u16x8 g8 = *(const u16x8*)(logitsTb + (size_t)(1024 + g) * 4096 + b * 512 + l * 8);
  float bg = bWg[g];
  float wv8[8], wsum = 0.f;
#pragma unroll
  for (int i = 0; i < 8; ++i) {
    float gl = bf2f(g8[i]);
    float ag = 1.0f / (1.0f + expf(-(gl + bg)));
    wv8[i] = e[i] * R * ag;
    wsum += wv8[i];
  }
#pragma unroll
  for (int m = 1; m < 64; m <<= 1) wsum += __shfl_xor(wsum, m, 64);
  if (l == 0) colsumW[b * 1024 + q] = wsum;
  u16x8 o;
#pragma unroll
  for (int i = 0; i < 8; ++i) {
    __hip_bfloat16 hb = __float2bfloat16(wv8[i]);
    o[i] = *(ushort_t*)&hb;
  }
  *(u16x8*)(wbT + base) = o;
}

// ---------------- K6: VLAD einsum via MFMA, 64x64 tile, m-split 8, counted vmcnt ----------------
__launch_bounds__(256)
__global__ void k6_vlad_mfma(const ushort_t* __restrict__ wbT, const ushort_t* __restrict__ YcT,
                             float* __restrict__ vpart) {
  int kt = blockIdx.x >> 2, dt = blockIdx.x & 3;
  int ms = blockIdx.y, b = blockIdx.z;
  __shared__ alignas(16) ushort_t Ash[2][4096];
  __shared__ alignas(16) ushort_t Bsh[2][4096];
  const int tid = threadIdx.x;
  const int w = tid >> 6, l = tid & 63;
  const int wr = w >> 1, wc = w & 1;
  const int crow = l >> 3;
  const int ksw = ((l & 7) ^ crow) * 8;

  const ushort_t* Ap[2];
  const ushort_t* Bp[2];
  int loff[2];
#pragma unroll
  for (int c = 0; c < 2; ++c) {
    int chunk = w * 2 + c;
    Ap[c] = wbT + (size_t)(kt * 64 + chunk * 8 + crow) * 4096 + b * 512 + ms * 64 + ksw;
    Bp[c] = YcT + (size_t)(dt * 64 + chunk * 8 + crow) * 4096 + b * 512 + ms * 64 + ksw;
    loff[c] = chunk * 512;
  }

  f32x4 acc[2][2];
#pragma unroll
  for (int i = 0; i < 2; ++i)
#pragma unroll
    for (int j = 0; j < 2; ++j) acc[i][j] = (f32x4){0.f, 0.f, 0.f, 0.f};

  const int sw = l & 7, qq = l >> 4;

#define STAGE6(buf, g)                                                       \
  {                                                                          \
    size_t offA = (size_t)(g)*524288;                                        \
    size_t offB = (size_t)(g)*1048576;                                       \
    gload_lds16(Ap[0] + offA, &Ash[buf][loff[0]]);                           \
    gload_lds16(Ap[1] + offA, &Ash[buf][loff[1]]);                           \
    gload_lds16(Bp[0] + offB, &Bsh[buf][loff[0]]);                           \
    gload_lds16(Bp[1] + offB, &Bsh[buf][loff[1]]);                           \
  }
#define COMPUTE6(buf)                                                                    \
  {                                                                                      \
    s16x8 af[2][2], bf[2][2];                                                            \
    _Pragma("unroll") for (int kk = 0; kk < 2; ++kk) {                                   \
      int slot = (((kk << 2) + qq) ^ sw) * 8;                                            \
      _Pragma("unroll") for (int mi = 0; mi < 2; ++mi) {                                 \
        af[mi][kk] = *(const s16x8*)&Ash[buf][(wr * 32 + mi * 16 + (l & 15)) * 64 +      \
                                             slot];                                     \
        bf[mi][kk] = *(const s16x8*)&Bsh[buf][(wc * 32 + mi * 16 + (l & 15)) * 64 +      \
                                             slot];                                     \
      }                                                                                  \
    }                                                                                    \
    _Pragma("unroll") for (int kk = 0; kk < 2; ++kk)                                     \
        _Pragma("unroll") for (int mi = 0; mi < 2; ++mi)                                 \
            _Pragma("unroll") for (int ni = 0; ni < 2; ++ni)                             \
                acc[mi][ni] = __builtin_amdgcn_mfma_f32_16x16x32_bf16(af[mi][kk],        \
                                                                     bf[ni][kk],        \
                                                                     acc[mi][ni], 0, 0, 0); \
  }

  STAGE6(0, 0);
  int buf = 0;
  for (int s = 0; s < 7; ++s) {
    STAGE6(buf ^ 1, s + 1);
    asm volatile("s_waitcnt vmcnt(4)" ::: "memory");
    __builtin_amdgcn_s_barrier();
    asm volatile("" ::: "memory");
    COMPUTE6(buf);
    asm volatile("" ::: "memory");
    __builtin_amdgcn_s_barrier();
    buf ^= 1;
  }
  asm volatile("s_waitcnt vmcnt(0)" ::: "memory");
  __builtin_amdgcn_s_barrier();
  asm volatile("" ::: "memory");
  COMPUTE6(buf);
#undef STAGE6
#undef COMPUTE6

#pragma unroll
  for (int mi = 0; mi < 2; ++mi) {
    int row = kt * 64 + wr * 32 + mi * 16 + (l >> 4) * 4;
#pragma unroll
    for (int ni = 0; ni < 2; ++ni) {
      int col = dt * 64 + wc * 32 + ni * 16 + (l & 15);
#pragma unroll
      for (int r = 0; r < 4; ++r)
        vpart[((size_t)(ms * 8 + b) * 128 + row + r) * 256 + col] = acc[mi][ni][r];
    }
  }
}

// ---------------- K7: combine 8 partials + bias-part - S*centroid, intra-normalize ----------------
__global__ void k7_intranorm(const float* __restrict__ vpart, const float* __restrict__ colsumW,
                             const float* __restrict__ b_inp, const float* __restrict__ cent,
                             float* __restrict__ out, float* __restrict__ ss1) {
  int k = blockIdx.x;
  int b = blockIdx.y;
  int d = threadIdx.x;
  float S = 0.f, bp = 0.f;
#pragma unroll
  for (int g = 0; g < 8; ++g) {
    float cw = colsumW[b * 1024 + g * 128 + k];
    S += cw;
    bp = fmaf(b_inp[g * 256 + d], cw, bp);
  }
  size_t off = ((size_t)b * 128 + k) * 256 + d;
  float v = bp - S * cent[(size_t)k * 256 + d];
#pragma unroll
  for (int i = 0; i < 8; ++i) v += vpart[off + (size_t)i * 262144];
  float ss = v * v;
#pragma unroll
  for (int m = 1; m < 64; m <<= 1) ss += __shfl_xor(ss, m, 64);
  __shared__ float red[4];
  int lane = d & 63, wv = d >> 6;
  if (lane == 0) red[wv] = ss;
  __syncthreads();
  float tot = red[0] + red[1] + red[2] + red[3];
  float rinv = 1.0f / fmaxf(sqrtf(tot), EPSN);
  out[off] = v * rinv;
  if (d == 0) ss1[b * 128 + k] = tot * rinv * rinv;
}

// ---------------- K8: final global L2 norm ----------------
__global__ void k8_finalnorm(const float* __restrict__ ss1, float* __restrict__ out) {
  int b = blockIdx.x;
  int t = threadIdx.x;
  __shared__ float red[256];
  red[t] = (t < 128) ? ss1[b * 128 + t] : 0.f;
  __syncthreads();
  for (int o = 128; o > 0; o >>= 1) {
    if (t < o) red[t] += red[t + o];
    __syncthreads();
  }
  float rinv = 1.0f / fmaxf(sqrtf(red[0]), EPSN);
  float* op = out + (size_t)b * 32768;
  for (int i = t; i < 32768; i += 256) op[i] *= rinv;
}

extern "C" void kernel_launch(void* const* d_in, const int* in_sizes, int n_in,
                              void* d_out, int out_size, void* d_ws, size_t ws_size,
                              hipStream_t stream) {
  const float* x     = (const float*)d_in[0];
  const float* W_inp = (const float*)d_in[1];
  const float* b_inp = (const float*)d_in[2];
  const float* W_g   = (const float*)d_in[3];
  const float* b_g   = (const float*)d_in[4];
  const float* W_gk  = (const float*)d_in[5];
  // b_gk (d_in[6]) cancels in the token-axis softmax — unused.
  const float* cent  = (const float*)d_in[7];
  float* out = (float*)d_out;
  float* ws = (float*)d_ws;

  // workspace layout (float offsets), total 12,887,104 floats = 51.5 MB
  float* ssq8    = ws + 0;         // 32768
  float* colsumW = ws + 32768;     // 8192
  float* ss1     = ws + 40960;     // 1024
  float* bWg     = ws + 41984;     // 64
  ushort_t* xnb  = (ushort_t*)(ws + 42048);        // [4096][1024] bf16 (2097152 fl)
  ushort_t* wbT  = xnb;                            // alias (xnb dead after gemm256)
  ushort_t* stackedA = (ushort_t*)(ws + 2139200);  // [3328][1024] bf16 (1703936 fl)
  ushort_t* WibT = (ushort_t*)(ws + 3843136);      // [1024][2048] bf16 (1048576 fl)
  ushort_t* Wgkx = (ushort_t*)(ws + 4891712);      // [1152][2048] bf16 (1179648 fl)
  float* vpart   = ws + 3843136;   // 2097152 fl, aliases WibT+Wgkx (dead after gemm0)
  ushort_t* Wc4b = (ushort_t*)(ws + 6071360);      // [4][1152][1024] bf16, dead after kpackC
  ushort_t* Cstacked = (ushort_t*)(ws + 6071360);  // [3328][4096] bf16 (6815744 fl), over Wc4b
  ushort_t* YcT      = Cstacked;                   // rows 0-2047
  ushort_t* logitsTb = Cstacked + (size_t)2048 * 4096;  // rows 2048-3199

  // fused prep: Wgkx pack + gate + bWg + Wib/WibT dual + pad + k0 ssq partials
  kpack2<<<3464, 256, 0, stream>>>(W_inp, W_gk, W_g, b_inp, b_g,
                                   (__hip_bfloat16*)stackedA, (__hip_bfloat16*)Wgkx, WibT, bWg,
                                   x, ssq8);
  // fused: gemm0 split-K x4 (bf16 partials, blocks 0-287) || k1 transpose (288-799)
  g0k1<<<800, 512, 0, stream>>>(Wgkx, WibT, Wc4b, x, ssq8, (__hip_bfloat16*)xnb);
  // pack: stackedA rows 2048-3199 = bf16(sum_s Wc4b[s])
  kpackC<<<576, 256, 0, stream>>>(Wc4b, stackedA + (size_t)2048 * 1024);
  // big stacked GEMM (256^2, 8-phase, 1 barrier/phase, vmcnt(2)): Cstacked = stackedA @ xnb^T
  gemm256_8ph<<<dim3(16, 13), 512, 0, stream>>>(stackedA, xnb, Cstacked, 1024, 4096);
  k5_softmax<<<2048, 256, 0, stream>>>(logitsTb, bWg, colsumW, wbT);
  k6_vlad_mfma<<<dim3(8, 8, 8), 256, 0, stream>>>(wbT, YcT, vpart);
  k7_intranorm<<<dim3(128, 8), 256, 0, stream>>>(vpart, colsumW, b_inp, cent, out, ss1);
  k8_finalnorm<<<8, 256, 0, stream>>>(ss1, out);
}